// Round 1
// 604.479 us; speedup vs baseline: 1.1548x; 1.1548x over previous
//
#include <hip/hip_runtime.h>
#include <hip/hip_bf16.h>

// Hybrid decoder block, MFMA everywhere GEMM-shaped, channels-last internals.
// row convention: r = z*4096 + n, n = y*64+x.
#define NTHREADS 256

typedef __attribute__((ext_vector_type(8))) short bs8_t;   // 8 bf16 (4 VGPRs)
typedef __attribute__((ext_vector_type(4))) float f4_t;    // 4 fp32 acc

__device__ __forceinline__ float bf2f(__hip_bfloat16 v) { return __bfloat162float(v); }
__device__ __forceinline__ __hip_bfloat16 f2bf(float v) { return __float2bfloat16(v); }
__device__ __forceinline__ float b2f_lo(unsigned int p) { return __uint_as_float(p << 16); }
__device__ __forceinline__ float b2f_hi(unsigned int p) { return __uint_as_float(p & 0xffff0000u); }
__device__ __forceinline__ float sigm(float x) { return 1.f / (1.f + __expf(-x)); }
__device__ __forceinline__ float leaky(float x) { return x > 0.f ? x : 0.01f * x; }
__device__ __forceinline__ float sane(float x) { return fminf(fmaxf(x, -1e9f), 1e9f); }
__device__ __forceinline__ unsigned packbf(float a, float b) {
  union { __hip_bfloat16 h[2]; unsigned u; } cv;
  cv.h[0] = f2bf(a); cv.h[1] = f2bf(b);
  return cv.u;
}
__device__ __forceinline__ float ldf(const void* p, long i, int f) {
  return f ? ((const float*)p)[i] : bf2f(((const __hip_bfloat16*)p)[i]);
}
// single-instruction 2^x (v_exp_f32); gfx9 trans ops are HW-interlocked.
__device__ __forceinline__ float exp2_fast(float x) {
  float r;
  asm("v_exp_f32 %0, %1" : "=v"(r) : "v"(x));
  return r;
}

// ---------------- dtype detector ----------------
__global__ void k_detect(const void* xp, int* flag) {
  __shared__ int cnt[NTHREADS];
  const __hip_bfloat16* h = (const __hip_bfloat16*)xp;
  int t = threadIdx.x;
  int c = 0;
  for (int j = 0; j < 8; j++) {
    float v = fabsf(bf2f(h[(t * 8 + j) * 2]));
    if (v > 1e-12f && v < 1e12f) c++;
  }
  cnt[t] = c;
  __syncthreads();
  for (int s = 128; s > 0; s >>= 1) {
    if (t < s) cnt[t] += cnt[t + s];
    __syncthreads();
  }
  if (t == 0) *flag = (cnt[0] > 1433) ? 0 : 1;
}

// generic converter: out[i] = bf16(in[i])
__global__ void k_prepcvt(const void* __restrict__ in, __hip_bfloat16* __restrict__ out,
                          int n, const int* __restrict__ flagp) {
  int f = *flagp;
  int gid = blockIdx.x * NTHREADS + threadIdx.x;
  if (gid < n) out[gid] = f2bf(ldf(in, gid, f));
}

// ---------------- pad1: x (ci-first) -> P1[z'(34)][y'(66)][x'(66)][32] bf16 ----------------
__global__ __launch_bounds__(NTHREADS) void k_pad1(const void* __restrict__ x,
                                                   __hip_bfloat16* __restrict__ P1,
                                                   const int* __restrict__ flagp) {
  __shared__ float tile[64 * 33];
  int f = *flagp;
  int zp = blockIdx.x / 66, yp = blockIdx.x % 66;
  long rowbase = ((long)zp * 66 + yp) * 66 * 32;
  int t = threadIdx.x;
  if (zp == 0 || zp == 33 || yp == 0 || yp == 65) {
    for (int i = t; i < 2112; i += NTHREADS) P1[rowbase + i] = f2bf(0.f);
    return;
  }
  int z = zp - 1, y = yp - 1;
#pragma unroll
  for (int j = 0; j < 8; j++) {
    int idx = t + j * NTHREADS;
    int ci = idx >> 6, xx = idx & 63;
    tile[xx * 33 + ci] = ldf(x, (long)(ci * 32 + z) * 4096 + y * 64 + xx, f);
  }
  __syncthreads();
#pragma unroll
  for (int j = 0; j < 8; j++) {
    int idx = t + j * NTHREADS;
    int xx = idx >> 5, ci = idx & 31;
    P1[rowbase + (xx + 1) * 32 + ci] = f2bf(tile[xx * 33 + ci]);
  }
  if (t < 32) P1[rowbase + t] = f2bf(0.f);
  else if (t < 64) P1[rowbase + 65 * 32 + (t - 32)] = f2bf(0.f);
}

// ---------------- weight reorg: cw (co,ci,2,3,3) -> W[s][co][ci] bf16 ----------------
__global__ void k_prepw(const void* __restrict__ cw, __hip_bfloat16* __restrict__ W,
                        int CI, const int* __restrict__ flagp) {
  int f = *flagp;
  int gid = blockIdx.x * NTHREADS + threadIdx.x;
  int s = gid / (64 * CI);
  int rem = gid % (64 * CI);
  int co = rem / CI, ci = rem % CI;
  W[gid] = f2bf(ldf(cw, (long)(co * CI + ci) * 18 + s, f));
}

// ---------------- MFMA implicit-GEMM conv + fused per-channel stats ----------------
template <int CI, int CIP>
__global__ __launch_bounds__(NTHREADS) void k_gemm_conv(const __hip_bfloat16* __restrict__ Pb,
                                                        const __hip_bfloat16* __restrict__ Wb,
                                                        __hip_bfloat16* __restrict__ out,
                                                        float* __restrict__ gacc) {
  __shared__ unsigned short Wl[3 * 64 * CIP];
  __shared__ float sred[256], qred[256];
  const unsigned short* P = (const unsigned short*)Pb;
  const unsigned short* W = (const unsigned short*)Wb;
  int t = threadIdx.x;
  int wv = t >> 6, lane = t & 63;
  int m = lane & 15, quad = lane >> 4;
  int zo = blockIdx.x >> 4;
  int y  = ((blockIdx.x & 15) << 2) + wv;
  f4_t zero4 = {0.f, 0.f, 0.f, 0.f};
  f4_t acc[4][4];
#pragma unroll
  for (int mt = 0; mt < 4; mt++)
#pragma unroll
    for (int nt = 0; nt < 4; nt++) acc[mt][nt] = zero4;

  for (int kz = 0; kz < 2; kz++) {
    for (int ky = 0; ky < 3; ky++) {
      __syncthreads();
      int s0 = (kz * 3 + ky) * 3;
      const unsigned short* wsrc = W + (long)s0 * 64 * CI;
      for (int i = t; i < 3 * 64 * CI; i += NTHREADS) {
        int kx = i / (64 * CI), rem = i % (64 * CI);
        int co = rem / CI, ci = rem % CI;
        Wl[(kx * 64 + co) * CIP + ci] = wsrc[i];
      }
      __syncthreads();
      int pz = zo + kz, py = y + ky;
      const unsigned short* prow = P + ((long)(pz * 66 + py) * 66) * CI;
#pragma unroll
      for (int kx = 0; kx < 3; kx++) {
#pragma unroll
        for (int ch = 0; ch < CI / 32; ch++) {
          int kof = kx * CI + ch * 32 + quad * 8;
          bs8_t a0 = *(const bs8_t*)(prow + (0 * 16 + m) * CI + kof);
          bs8_t a1 = *(const bs8_t*)(prow + (1 * 16 + m) * CI + kof);
          bs8_t a2 = *(const bs8_t*)(prow + (2 * 16 + m) * CI + kof);
          bs8_t a3 = *(const bs8_t*)(prow + (3 * 16 + m) * CI + kof);
#pragma unroll
          for (int nt = 0; nt < 4; nt++) {
            bs8_t b = *(const bs8_t*)&Wl[(kx * 64 + nt * 16 + m) * CIP + ch * 32 + quad * 8];
            acc[0][nt] = __builtin_amdgcn_mfma_f32_16x16x32_bf16(a0, b, acc[0][nt], 0, 0, 0);
            acc[1][nt] = __builtin_amdgcn_mfma_f32_16x16x32_bf16(a1, b, acc[1][nt], 0, 0, 0);
            acc[2][nt] = __builtin_amdgcn_mfma_f32_16x16x32_bf16(a2, b, acc[2][nt], 0, 0, 0);
            acc[3][nt] = __builtin_amdgcn_mfma_f32_16x16x32_bf16(a3, b, acc[3][nt], 0, 0, 0);
          }
        }
      }
    }
  }
  long obase = ((long)(zo * 64 + y) * 64) * 64;
  float psum[4], pq[4];
#pragma unroll
  for (int nt = 0; nt < 4; nt++) {
    int co = nt * 16 + m;
    float s = 0.f, q = 0.f;
#pragma unroll
    for (int mt = 0; mt < 4; mt++)
#pragma unroll
      for (int rg = 0; rg < 4; rg++) {
        float v = acc[mt][nt][rg];
        int xx = mt * 16 + quad * 4 + rg;
        out[obase + xx * 64 + co] = f2bf(v);
        s += v;
        q += v * v;
      }
    psum[nt] = s;
    pq[nt] = q;
  }
#pragma unroll
  for (int nt = 0; nt < 4; nt++) {
    psum[nt] += __shfl_xor(psum[nt], 16, 64);
    psum[nt] += __shfl_xor(psum[nt], 32, 64);
    pq[nt]   += __shfl_xor(pq[nt], 16, 64);
    pq[nt]   += __shfl_xor(pq[nt], 32, 64);
  }
  if (quad == 0) {
#pragma unroll
    for (int nt = 0; nt < 4; nt++) {
      sred[wv * 64 + nt * 16 + m] = psum[nt];
      qred[wv * 64 + nt * 16 + m] = pq[nt];
    }
  }
  __syncthreads();
  if (t < 64) {
    atomicAdd(&gacc[t], sred[t] + sred[64 + t] + sred[128 + t] + sred[192 + t]);
    atomicAdd(&gacc[64 + t], qred[t] + qred[64 + t] + qred[128 + t] + qred[192 + t]);
  }
}

__global__ void k_finalize(const float* __restrict__ acc, const void* __restrict__ g,
                           const void* __restrict__ b, float* __restrict__ ss, float invN,
                           const int* __restrict__ flagp) {
  int f = *flagp;
  int t = threadIdx.x;  // 64
  float mean = acc[t] * invN;
  float var  = acc[64 + t] * invN - mean * mean;
  float rstd = rsqrtf(fmaxf(var, 0.f) + 1e-5f);
  float sc   = ldf(g, t, f) * rstd;
  ss[t]      = sc;
  ss[64 + t] = ldf(b, t, f) - mean * sc;
}

// ---------------- normpad: c1raw -> norm+leaky -> P2[35][66][66][64] ----------------
__global__ __launch_bounds__(NTHREADS) void k_normpad(const __hip_bfloat16* __restrict__ in,
                                                      const float* __restrict__ ss,
                                                      __hip_bfloat16* __restrict__ P2) {
  int zp = blockIdx.x / 66, yp = blockIdx.x % 66;
  long rowbase = ((long)zp * 66 + yp) * 66 * 64;
  int t = threadIdx.x;
  if (zp == 0 || zp == 34 || yp == 0 || yp == 65) {
    for (int i = t; i < 4224; i += NTHREADS) P2[rowbase + i] = f2bf(0.f);
    return;
  }
  int z = zp - 1, y = yp - 1;
#pragma unroll
  for (int j = 0; j < 16; j++) {
    int idx = t + j * NTHREADS;
    int xx = idx >> 6, co = idx & 63;
    float v = bf2f(in[((long)(z * 64 + y) * 64 + xx) * 64 + co]) * ss[co] + ss[64 + co];
    P2[rowbase + (xx + 1) * 64 + co] = f2bf(leaky(v));
  }
  if (t < 64) P2[rowbase + t] = f2bf(0.f);
  else if (t < 128) P2[rowbase + 65 * 64 + (t - 64)] = f2bf(0.f);
}

// ---------------- hslice: c2raw -> norm+leaky -> hcl + residual d_out[c][r] ----------------
__global__ __launch_bounds__(NTHREADS) void k_hslice_cl(const __hip_bfloat16* __restrict__ in,
                                                        const float* __restrict__ ss,
                                                        __hip_bfloat16* __restrict__ hcl,
                                                        void* __restrict__ resid,
                                                        const int* __restrict__ flagp) {
  __shared__ float tile[64 * 65];
  int f = *flagp;
  int z = blockIdx.x >> 6, y = blockIdx.x & 63;
  long r0 = (long)z * 4096 + y * 64;
  int t = threadIdx.x;
#pragma unroll
  for (int j = 0; j < 16; j++) {
    int idx = t + j * NTHREADS;
    int xx = idx >> 6, co = idx & 63;
    float v = leaky(bf2f(in[(r0 + xx) * 64 + co]) * ss[co] + ss[64 + co]);
    hcl[(r0 + xx) * 64 + co] = f2bf(v);
    tile[xx * 65 + co] = v;
  }
  __syncthreads();
#pragma unroll
  for (int j = 0; j < 16; j++) {
    int idx = t + j * NTHREADS;
    int co = idx >> 6, xx = idx & 63;
    long off = (long)co * 131072 + r0 + xx;
    if (f) ((float*)resid)[off] = tile[xx * 65 + co];
    else   ((__hip_bfloat16*)resid)[off] = f2bf(tile[xx * 65 + co]);
  }
}

// ---------------- dw3x3 + pw1x1 (MFMA pointwise) + inr stats ----------------
__global__ __launch_bounds__(NTHREADS) void k_dwpw_mfma(const __hip_bfloat16* __restrict__ hcl,
                                                        const void* __restrict__ dwb,
                                                        const __hip_bfloat16* __restrict__ pwbb,
                                                        __hip_bfloat16* __restrict__ out,
                                                        float* __restrict__ acc,
                                                        const int* __restrict__ flagp) {
  __shared__ unsigned short hl[3 * 64 * 64];
  __shared__ unsigned short dwt[64 * 72];
  __shared__ unsigned short pwl[64 * 72];
  __shared__ float dwl[576];
  __shared__ float sred[256], qred[256];
  int f = *flagp;
  int t = threadIdx.x;
  int z = blockIdx.x >> 6, y = blockIdx.x & 63;
  for (int i = t; i < 576; i += NTHREADS) dwl[i] = ldf(dwb, i, f);
  {
    const unsigned short* ps = (const unsigned short*)pwbb;
    for (int i = t; i < 4096; i += NTHREADS) pwl[(i >> 6) * 72 + (i & 63)] = ps[i];
  }
  const unsigned short* hsrc = (const unsigned short*)hcl;
  for (int i = t; i < 12288; i += NTHREADS) {
    int dy = i / 4096, rem = i & 4095;
    int ry = y - 1 + dy;
    hl[i] = ((unsigned)ry < 64u) ? hsrc[((long)z * 4096 + ry * 64) * 64 + rem] : (unsigned short)0;
  }
  __syncthreads();
  const unsigned* hl32 = (const unsigned*)hl;
  unsigned* dwt32 = (unsigned*)dwt;
#pragma unroll
  for (int j = 0; j < 8; j++) {
    int idx = t + j * NTHREADS;
    int xx = idx >> 5, cp = idx & 31;
    float a0 = 0.f, a1 = 0.f;
#pragma unroll
    for (int dy = 0; dy < 3; dy++)
#pragma unroll
      for (int dx = 0; dx < 3; dx++) {
        int xv = xx - 1 + dx;
        if ((unsigned)xv < 64u) {
          unsigned hv = hl32[(dy * 64 + xv) * 32 + cp];
          a0 = fmaf(b2f_lo(hv), dwl[(cp * 2) * 9 + dy * 3 + dx], a0);
          a1 = fmaf(b2f_hi(hv), dwl[(cp * 2 + 1) * 9 + dy * 3 + dx], a1);
        }
      }
    dwt32[xx * 36 + cp] = packbf(a0, a1);
  }
  __syncthreads();
  int wv = t >> 6, lane = t & 63;
  int m = lane & 15, quad = lane >> 4;
  f4_t zero4 = {0.f, 0.f, 0.f, 0.f};
  f4_t acc4[4];
#pragma unroll
  for (int nt = 0; nt < 4; nt++) acc4[nt] = zero4;
#pragma unroll
  for (int ch = 0; ch < 2; ch++) {
    bs8_t a = *(const bs8_t*)&dwt[(wv * 16 + m) * 72 + ch * 32 + quad * 8];
#pragma unroll
    for (int nt = 0; nt < 4; nt++) {
      bs8_t b = *(const bs8_t*)&pwl[(nt * 16 + m) * 72 + ch * 32 + quad * 8];
      acc4[nt] = __builtin_amdgcn_mfma_f32_16x16x32_bf16(a, b, acc4[nt], 0, 0, 0);
    }
  }
  long obase = ((long)z * 4096 + y * 64) * 64;
  float psum[4], pq[4];
#pragma unroll
  for (int nt = 0; nt < 4; nt++) {
    float s = 0.f, q = 0.f;
#pragma unroll
    for (int rg = 0; rg < 4; rg++) {
      float v = acc4[nt][rg];
      int xx = wv * 16 + quad * 4 + rg;
      out[obase + xx * 64 + nt * 16 + m] = f2bf(v);
      s += v;
      q += v * v;
    }
    psum[nt] = s;
    pq[nt] = q;
  }
#pragma unroll
  for (int nt = 0; nt < 4; nt++) {
    psum[nt] += __shfl_xor(psum[nt], 16, 64);
    psum[nt] += __shfl_xor(psum[nt], 32, 64);
    pq[nt]   += __shfl_xor(pq[nt], 16, 64);
    pq[nt]   += __shfl_xor(pq[nt], 32, 64);
  }
  if (quad == 0) {
#pragma unroll
    for (int nt = 0; nt < 4; nt++) {
      sred[wv * 64 + nt * 16 + m] = psum[nt];
      qred[wv * 64 + nt * 16 + m] = pq[nt];
    }
  }
  __syncthreads();
  if (t < 64) {
    atomicAdd(&acc[t], sred[t] + sred[64 + t] + sred[128 + t] + sred[192 + t]);
    atomicAdd(&acc[64 + t], qred[t] + qred[64 + t] + qred[128 + t] + qred[192 + t]);
  }
}

// ---------------- x2 = h + silu(norm(pre2)); LayerNorm C=64 -> seq bf16 ----------------
__global__ __launch_bounds__(NTHREADS) void k_x2ln_cl(const __hip_bfloat16* __restrict__ hcl,
                                                      const __hip_bfloat16* __restrict__ p2,
                                                      const float* __restrict__ ssr,
                                                      const void* __restrict__ lng,
                                                      const void* __restrict__ lnb,
                                                      __hip_bfloat16* __restrict__ out,
                                                      const int* __restrict__ flagp) {
  __shared__ float sc[64], sh[64], sg[64], sb[64];
  int f = *flagp;
  int t = threadIdx.x;
  if (t < 64) {
    sc[t] = ssr[t];
    sh[t] = ssr[64 + t];
    sg[t] = ldf(lng, t, f);
    sb[t] = ldf(lnb, t, f);
  }
  __syncthreads();
  long r = (long)blockIdx.x * NTHREADS + t;
  const uint4* hp = (const uint4*)(hcl + r * 64);
  const uint4* pp = (const uint4*)(p2 + r * 64);
  float v[64];
  float s1 = 0.f;
#pragma unroll
  for (int q = 0; q < 8; q++) {
    uint4 hu = hp[q], pu = pp[q];
    float hv[8] = {b2f_lo(hu.x), b2f_hi(hu.x), b2f_lo(hu.y), b2f_hi(hu.y),
                   b2f_lo(hu.z), b2f_hi(hu.z), b2f_lo(hu.w), b2f_hi(hu.w)};
    float pv[8] = {b2f_lo(pu.x), b2f_hi(pu.x), b2f_lo(pu.y), b2f_hi(pu.y),
                   b2f_lo(pu.z), b2f_hi(pu.z), b2f_lo(pu.w), b2f_hi(pu.w)};
#pragma unroll
    for (int i = 0; i < 8; i++) {
      int c = q * 8 + i;
      float pn = sc[c] * pv[i] + sh[c];
      float x2 = hv[i] + pn * sigm(pn);
      v[c] = x2;
      s1 += x2;
    }
  }
  float m = s1 * (1.f / 64.f);
  float s2 = 0.f;
#pragma unroll
  for (int c = 0; c < 64; c++) {
    float d = v[c] - m;
    s2 += d * d;
  }
  float rstd = rsqrtf(s2 * (1.f / 64.f) + 1e-5f);
  uint4* o4 = (uint4*)(out + r * 64);
#pragma unroll
  for (int q = 0; q < 8; q++) {
    int c = q * 8;
    uint4 o;
    o.x = packbf((v[c + 0] - m) * rstd * sg[c + 0] + sb[c + 0],
                 (v[c + 1] - m) * rstd * sg[c + 1] + sb[c + 1]);
    o.y = packbf((v[c + 2] - m) * rstd * sg[c + 2] + sb[c + 2],
                 (v[c + 3] - m) * rstd * sg[c + 3] + sb[c + 3]);
    o.z = packbf((v[c + 4] - m) * rstd * sg[c + 4] + sb[c + 4],
                 (v[c + 5] - m) * rstd * sg[c + 5] + sb[c + 5]);
    o.w = packbf((v[c + 6] - m) * rstd * sg[c + 6] + sb[c + 6],
                 (v[c + 7] - m) * rstd * sg[c + 7] + sb[c + 7]);
    o4[q] = o;
  }
}

// ---------------- in_proj MFMA ----------------
__global__ __launch_bounds__(NTHREADS) void k_inproj_mfma(const __hip_bfloat16* __restrict__ seq,
                                                          const __hip_bfloat16* __restrict__ Wbf,
                                                          __hip_bfloat16* __restrict__ x_in,
                                                          __hip_bfloat16* __restrict__ zg) {
  __shared__ unsigned short Wl[256 * 72];
  const unsigned short* ws = (const unsigned short*)Wbf;
  int t = threadIdx.x;
  for (int i = t; i < 16384; i += NTHREADS) Wl[(i >> 6) * 72 + (i & 63)] = ws[i];
  __syncthreads();
  int wv = t >> 6, lane = t & 63;
  int m = lane & 15, quad = lane >> 4;
  long m0 = (long)blockIdx.x * 64;
  int n0 = wv * 64;
  f4_t zero4 = {0.f, 0.f, 0.f, 0.f};
  f4_t acc[4][4];
#pragma unroll
  for (int mt = 0; mt < 4; mt++)
#pragma unroll
    for (int nt = 0; nt < 4; nt++) acc[mt][nt] = zero4;
  const unsigned short* sp = (const unsigned short*)seq;
#pragma unroll
  for (int ch = 0; ch < 2; ch++) {
    int kof = ch * 32 + quad * 8;
    bs8_t a0 = *(const bs8_t*)(sp + (m0 + 0 * 16 + m) * 64 + kof);
    bs8_t a1 = *(const bs8_t*)(sp + (m0 + 1 * 16 + m) * 64 + kof);
    bs8_t a2 = *(const bs8_t*)(sp + (m0 + 2 * 16 + m) * 64 + kof);
    bs8_t a3 = *(const bs8_t*)(sp + (m0 + 3 * 16 + m) * 64 + kof);
#pragma unroll
    for (int nt = 0; nt < 4; nt++) {
      bs8_t b = *(const bs8_t*)&Wl[(n0 + nt * 16 + m) * 72 + kof];
      acc[0][nt] = __builtin_amdgcn_mfma_f32_16x16x32_bf16(a0, b, acc[0][nt], 0, 0, 0);
      acc[1][nt] = __builtin_amdgcn_mfma_f32_16x16x32_bf16(a1, b, acc[1][nt], 0, 0, 0);
      acc[2][nt] = __builtin_amdgcn_mfma_f32_16x16x32_bf16(a2, b, acc[2][nt], 0, 0, 0);
      acc[3][nt] = __builtin_amdgcn_mfma_f32_16x16x32_bf16(a3, b, acc[3][nt], 0, 0, 0);
    }
  }
  __hip_bfloat16* obuf = (n0 < 128) ? x_in : zg;
  int cbase = (n0 < 128) ? n0 : (n0 - 128);
#pragma unroll
  for (int mt = 0; mt < 4; mt++)
#pragma unroll
    for (int nt = 0; nt < 4; nt++) {
      int col = cbase + nt * 16 + m;
#pragma unroll
      for (int rg = 0; rg < 4; rg++) {
        long row = m0 + mt * 16 + quad * 4 + rg;
        obuf[row * 128 + col] = f2bf(acc[mt][nt][rg]);
      }
    }
}

// ---------------- causal depthwise conv1d, in place ----------------
__global__ __launch_bounds__(NTHREADS) void k_conv1d_ip(__hip_bfloat16* xio,
                                                        const void* __restrict__ wb,
                                                        const void* __restrict__ bb,
                                                        const int* __restrict__ flagp) {
  int f = *flagp;
  int gid = blockIdx.x * NTHREADS + threadIdx.x;
  int d = gid & 127, nl = gid >> 7;
  float w0 = ldf(wb, d * 4 + 0, f), w1 = ldf(wb, d * 4 + 1, f);
  float w2 = ldf(wb, d * 4 + 2, f), w3 = ldf(wb, d * 4 + 3, f);
  float bias = ldf(bb, d, f);
  float h0 = 0.f, h1 = 0.f, h2 = 0.f;
  size_t off = (size_t)nl * 128 + d;
  const size_t stride = 4096u * 128u;
  for (int z = 0; z < 32; z++) {
    float xv = bf2f(xio[off]);
    float a = bias;
    a = fmaf(h0, w0, a);
    a = fmaf(h1, w1, a);
    a = fmaf(h2, w2, a);
    a = fmaf(xv, w3, a);
    xio[off] = f2bf(a * sigm(a));
    h0 = h1; h1 = h2; h2 = xv;
    off += stride;
  }
}

// ---------------- x_proj MFMA: (131072,128) x (36->48 pad,128)^T -> xdbl (131072,36) ----------------
__global__ __launch_bounds__(NTHREADS) void k_xproj_mfma(const __hip_bfloat16* __restrict__ A,
                                                         const __hip_bfloat16* __restrict__ Wbf,
                                                         __hip_bfloat16* __restrict__ out) {
  __shared__ unsigned short Wl[48 * 136];
  const unsigned short* ws = (const unsigned short*)Wbf;   // (36,128) row-major
  int t = threadIdx.x;
  for (int i = t; i < 48 * 128; i += NTHREADS) {
    int j = i >> 7, k = i & 127;
    Wl[j * 136 + k] = (j < 36) ? ws[j * 128 + k] : (unsigned short)0;
  }
  __syncthreads();
  int wv = t >> 6, lane = t & 63;
  int m = lane & 15, quad = lane >> 4;
  long m0 = (long)blockIdx.x * 256 + wv * 64;
  f4_t zero4 = {0.f, 0.f, 0.f, 0.f};
  f4_t acc[4][3];
#pragma unroll
  for (int mt = 0; mt < 4; mt++)
#pragma unroll
    for (int nt = 0; nt < 3; nt++) acc[mt][nt] = zero4;
  const unsigned short* ap = (const unsigned short*)A;
#pragma unroll
  for (int ch = 0; ch < 4; ch++) {
    int kof = ch * 32 + quad * 8;
    bs8_t a0 = *(const bs8_t*)(ap + (m0 + 0 * 16 + m) * 128 + kof);
    bs8_t a1 = *(const bs8_t*)(ap + (m0 + 1 * 16 + m) * 128 + kof);
    bs8_t a2 = *(const bs8_t*)(ap + (m0 + 2 * 16 + m) * 128 + kof);
    bs8_t a3 = *(const bs8_t*)(ap + (m0 + 3 * 16 + m) * 128 + kof);
#pragma unroll
    for (int nt = 0; nt < 3; nt++) {
      bs8_t b = *(const bs8_t*)&Wl[(nt * 16 + m) * 136 + kof];
      acc[0][nt] = __builtin_amdgcn_mfma_f32_16x16x32_bf16(a0, b, acc[0][nt], 0, 0, 0);
      acc[1][nt] = __builtin_amdgcn_mfma_f32_16x16x32_bf16(a1, b, acc[1][nt], 0, 0, 0);
      acc[2][nt] = __builtin_amdgcn_mfma_f32_16x16x32_bf16(a2, b, acc[2][nt], 0, 0, 0);
      acc[3][nt] = __builtin_amdgcn_mfma_f32_16x16x32_bf16(a3, b, acc[3][nt], 0, 0, 0);
    }
  }
#pragma unroll
  for (int mt = 0; mt < 4; mt++)
#pragma unroll
    for (int nt = 0; nt < 3; nt++) {
      int col = nt * 16 + m;
      if (col < 36) {
#pragma unroll
        for (int rg = 0; rg < 4; rg++) {
          long row = m0 + mt * 16 + quad * 4 + rg;
          out[row * 36 + col] = f2bf(acc[mt][nt][rg]);
        }
      }
    }
}

// ---------------- selective scan ----------------
// 9x dwordx2 row loads, A prescaled by log2e and pinned in VGPRs, raw v_exp_f32,
// cheap softplus. One thread per (n,d); 16 states in registers.
__global__ __launch_bounds__(NTHREADS) void k_scan(const __hip_bfloat16* __restrict__ xdbl,
                                                   __hip_bfloat16* __restrict__ uy,
                                                   const __hip_bfloat16* __restrict__ zg,
                                                   const void* __restrict__ dtw,
                                                   const void* __restrict__ dtb,
                                                   const void* __restrict__ Alog,
                                                   const void* __restrict__ Dp,
                                                   const int* __restrict__ flagp) {
  int f = *flagp;
  int gid = blockIdx.x * NTHREADS + threadIdx.x;
  int d = gid & 127, n = gid >> 7;
  // A2[s] = -exp(A_log[d][s]) * log2(e): exp(dt*A) == exp2(dt*A2)
  float A2[16];
#pragma unroll
  for (int s = 0; s < 16; s++)
    A2[s] = -__expf(fminf(ldf(Alog, d * 16 + s, f), 60.f)) * 1.44269504088896f;
#pragma unroll
  for (int s = 0; s < 16; s++) asm("" : "+v"(A2[s]));  // pin in arch VGPRs; forbid remat/AGPR
  float W0 = ldf(dtw, d * 4 + 0, f), W1 = ldf(dtw, d * 4 + 1, f);
  float W2 = ldf(dtw, d * 4 + 2, f), W3 = ldf(dtw, d * 4 + 3, f);
  float bias = ldf(dtb, d, f);
  float Dv = ldf(Dp, d, f);
  float st[16];
#pragma unroll
  for (int s = 0; s < 16; s++) st[s] = 0.f;
  for (int z = 0; z < 32; z++) {
    size_t r = (size_t)(z << 12) | n;
    // row = 36 bf16 = 72 B, always 8B-aligned -> 9 dwordx2 loads
    const uint2* bq = (const uint2*)(xdbl + r * 36);
    uint2 g0 = bq[0], g1 = bq[1], g2 = bq[2], g3 = bq[3], g4 = bq[4];
    uint2 g5 = bq[5], g6 = bq[6], g7 = bq[7], g8 = bq[8];
    float u = sane(bf2f(uy[r * 128 + d]));
    float zv = sane(bf2f(zg[r * 128 + d]));
    float v = bias;
    v = fmaf(b2f_lo(g0.x), W0, v);
    v = fmaf(b2f_hi(g0.x), W1, v);
    v = fmaf(b2f_lo(g0.y), W2, v);
    v = fmaf(b2f_hi(g0.y), W3, v);
    // softplus: log1pf -> __logf(1+e^v); error only where e^v < 1e-7 (dt ~ 0)
    float dtv = v > 20.f ? v : __logf(1.f + __expf(v));
    dtv = fminf(fmaxf(dtv, 0.f), 60.f);
    float du = dtv * u;
    // elems: dt=0..3 (g0), B=4..19 (g1..g4), C=20..35 (g5..g8)
    uint wB[8] = {g1.x, g1.y, g2.x, g2.y, g3.x, g3.y, g4.x, g4.y};
    uint wC[8] = {g5.x, g5.y, g6.x, g6.y, g7.x, g7.y, g8.x, g8.y};
    float y = 0.f;
#pragma unroll
    for (int s = 0; s < 16; s++) {
      float Bv = (s & 1) ? b2f_hi(wB[s >> 1]) : b2f_lo(wB[s >> 1]);
      float Cv = (s & 1) ? b2f_hi(wC[s >> 1]) : b2f_lo(wC[s >> 1]);
      float e = exp2_fast(dtv * A2[s]);
      st[s] = fmaf(e, st[s], du * Bv);
      y = fmaf(st[s], Cv, y);
    }
    y = sane((y + Dv * u) * (zv * sigm(zv)));
    uy[r * 128 + d] = f2bf(y);
  }
}

// ---------------- W_comb = proj_w @ out_proj_w -> bf16 [o][d] ----------------
__global__ void k_wcomb(const void* __restrict__ pw, const void* __restrict__ opw,
                        __hip_bfloat16* __restrict__ wc, const int* __restrict__ flagp) {
  int f = *flagp;
  int gid = blockIdx.x * NTHREADS + threadIdx.x;
  int d = gid & 127, o = gid >> 7;
  float a = 0.f;
#pragma unroll
  for (int j = 0; j < 64; j++) a = fmaf(ldf(pw, o * 64 + j, f), ldf(opw, j * 128 + d, f), a);
  wc[(size_t)o * 128 + d] = f2bf(a);
}

// ---------------- out_proj+proj MFMA + fused pn stats ----------------
__global__ __launch_bounds__(NTHREADS) void k_outproj_mfma(const __hip_bfloat16* __restrict__ A,
                                                           const __hip_bfloat16* __restrict__ Wcb,
                                                           const void* __restrict__ bias,
                                                           __hip_bfloat16* __restrict__ out,
                                                           float* __restrict__ gacc,
                                                           const int* __restrict__ flagp) {
  __shared__ unsigned short Wl[64 * 136];
  __shared__ float bl[64];
  __shared__ float sred[256], qred[256];
  int f = *flagp;
  int t = threadIdx.x;
  const unsigned short* ws = (const unsigned short*)Wcb;
  for (int i = t; i < 8192; i += NTHREADS) Wl[(i >> 7) * 136 + (i & 127)] = ws[i];
  if (t < 64) bl[t] = ldf(bias, t, f);
  __syncthreads();
  int wv = t >> 6, lane = t & 63;
  int m = lane & 15, quad = lane >> 4;
  long m0 = (long)blockIdx.x * 256 + wv * 64;
  f4_t zero4 = {0.f, 0.f, 0.f, 0.f};
  f4_t acc[4][4];
#pragma unroll
  for (int mt = 0; mt < 4; mt++)
#pragma unroll
    for (int nt = 0; nt < 4; nt++) acc[mt][nt] = zero4;
  const unsigned short* ap = (const unsigned short*)A;
#pragma unroll
  for (int ch = 0; ch < 4; ch++) {
    int kof = ch * 32 + quad * 8;
    bs8_t a0 = *(const bs8_t*)(ap + (m0 + 0 * 16 + m) * 128 + kof);
    bs8_t a1 = *(const bs8_t*)(ap + (m0 + 1 * 16 + m) * 128 + kof);
    bs8_t a2 = *(const bs8_t*)(ap + (m0 + 2 * 16 + m) * 128 + kof);
    bs8_t a3 = *(const bs8_t*)(ap + (m0 + 3 * 16 + m) * 128 + kof);
#pragma unroll
    for (int nt = 0; nt < 4; nt++) {
      bs8_t b = *(const bs8_t*)&Wl[(nt * 16 + m) * 136 + kof];
      acc[0][nt] = __builtin_amdgcn_mfma_f32_16x16x32_bf16(a0, b, acc[0][nt], 0, 0, 0);
      acc[1][nt] = __builtin_amdgcn_mfma_f32_16x16x32_bf16(a1, b, acc[1][nt], 0, 0, 0);
      acc[2][nt] = __builtin_amdgcn_mfma_f32_16x16x32_bf16(a2, b, acc[2][nt], 0, 0, 0);
      acc[3][nt] = __builtin_amdgcn_mfma_f32_16x16x32_bf16(a3, b, acc[3][nt], 0, 0, 0);
    }
  }
  float psum[4], pq[4];
#pragma unroll
  for (int nt = 0; nt < 4; nt++) {
    int co = nt * 16 + m;
    float s = 0.f, q = 0.f;
#pragma unroll
    for (int mt = 0; mt < 4; mt++)
#pragma unroll
      for (int rg = 0; rg < 4; rg++) {
        float v = sane(acc[mt][nt][rg] + bl[co]);
        long row = m0 + mt * 16 + quad * 4 + rg;
        out[row * 64 + co] = f2bf(v);
        s += v;
        q += v * v;
      }
    psum[nt] = s;
    pq[nt] = q;
  }
#pragma unroll
  for (int nt = 0; nt < 4; nt++) {
    psum[nt] += __shfl_xor(psum[nt], 16, 64);
    psum[nt] += __shfl_xor(psum[nt], 32, 64);
    pq[nt]   += __shfl_xor(pq[nt], 16, 64);
    pq[nt]   += __shfl_xor(pq[nt], 32, 64);
  }
  if (quad == 0) {
#pragma unroll
    for (int nt = 0; nt < 4; nt++) {
      sred[wv * 64 + nt * 16 + m] = psum[nt];
      qred[wv * 64 + nt * 16 + m] = pq[nt];
    }
  }
  __syncthreads();
  if (t < 64) {
    atomicAdd(&gacc[t], sred[t] + sred[64 + t] + sred[128 + t] + sred[192 + t]);
    atomicAdd(&gacc[64 + t], qred[t] + qred[64 + t] + qred[128 + t] + qred[192 + t]);
  }
}

// ---------------- final ----------------
__global__ __launch_bounds__(NTHREADS) void k_final(const __hip_bfloat16* __restrict__ s2,
                                                    void* __restrict__ io,
                                                    const float* __restrict__ ss,
                                                    const int* __restrict__ flagp) {
  __shared__ float tile[64 * 65];
  __shared__ float sc[64], sh[64];
  int f = *flagp;
  int t = threadIdx.x;
  if (t < 64) {
    sc[t] = ss[t];
    sh[t] = ss[64 + t];
  }
  int z = blockIdx.x >> 6, n0 = (blockIdx.x & 63) << 6;
  size_t base = ((size_t)z * 4096 + n0) * 64;
  __syncthreads();
#pragma unroll
  for (int jj = 0; jj < 16; jj++) {
    int id = t + jj * NTHREADS;
    int i = id >> 6, c = id & 63;
    float v = sane(bf2f(s2[base + id]));
    tile[i * 65 + c] = sc[c] * v + sh[c];
  }
  __syncthreads();
#pragma unroll
  for (int jj = 0; jj < 16; jj++) {
    int id = t + jj * NTHREADS;
    int c = id >> 6, nl = id & 63;
    size_t off = (size_t)c * 131072 + (size_t)z * 4096 + n0 + nl;
    if (f) {
      float* o = (float*)io;
      o[off] = sane(o[off] + tile[nl * 65 + c]);
    } else {
      __hip_bfloat16* o = (__hip_bfloat16*)io;
      o[off] = f2bf(sane(bf2f(o[off]) + tile[nl * 65 + c]));
    }
  }
}

// ---------------- launch ----------------
extern "C" void kernel_launch(void* const* d_in, const int* in_sizes, int n_in,
                              void* d_out, int out_size, void* d_ws, size_t ws_size,
                              hipStream_t stream) {
  (void)in_sizes; (void)n_in; (void)out_size; (void)ws_size;
  const void* x        = d_in[0];
  const void* c1_w     = d_in[1];
  const void* in1_g    = d_in[2];
  const void* in1_b    = d_in[3];
  const void* c2_w     = d_in[4];
  const void* in2_g    = d_in[5];
  const void* in2_b    = d_in[6];
  const void* dw_w     = d_in[7];
  const void* pw_w     = d_in[8];
  const void* inr_g    = d_in[9];
  const void* inr_b    = d_in[10];
  const void* ln_g     = d_in[11];
  const void* ln_b     = d_in[12];
  const void* in_proj_w= d_in[13];
  const void* conv1d_w = d_in[14];
  const void* conv1d_b = d_in[15];
  const void* x_proj_w = d_in[16];
  const void* dt_proj_w= d_in[17];
  const void* dt_proj_b= d_in[18];
  const void* A_log    = d_in[19];
  const void* D_p      = d_in[20];
  const void* out_proj_w=d_in[21];
  const void* proj_w   = d_in[22];
  const void* proj_b   = d_in[23];
  const void* pn_g     = d_in[24];
  const void* pn_b     = d_in[25];

  char* wb = (char*)d_ws;
  // Byte layout, TOTAL ~= 85.3 MB (< 90.3 MB proven mapped in R7).
  // R0 [0, 33,554,432): P1(9.5M) -> P2(19.5M) -> zg(33.5M) -> s2(16.8M)
  __hip_bfloat16* P1   = (__hip_bfloat16*)wb;
  __hip_bfloat16* P2   = (__hip_bfloat16*)wb;
  __hip_bfloat16* zgb  = (__hip_bfloat16*)wb;
  __hip_bfloat16* s2   = (__hip_bfloat16*)wb;
  // R1 [33,554,432, 67,108,864): c1raw(17.3M) -> c2raw(17.8M) | pre2(16.8M) -> x_in(33.5M)
  __hip_bfloat16* c1raw = (__hip_bfloat16*)(wb + 33554432);
  __hip_bfloat16* c2raw = (__hip_bfloat16*)(wb + 33554432);
  __hip_bfloat16* pre2  = (__hip_bfloat16*)(wb + 33554432);
  __hip_bfloat16* x_in  = (__hip_bfloat16*)(wb + 33554432);
  // hcl [51,380,224, 68,157,440)
  __hip_bfloat16* hcl   = (__hip_bfloat16*)(wb + 51380224);
  // seq [68,157,440, 84,934,656); xdbl aliases seq after inproj
  __hip_bfloat16* seq   = (__hip_bfloat16*)(wb + 68157440);
  __hip_bfloat16* xdbl  = (__hip_bfloat16*)(wb + 68157440);
  // weights [84,934,656 ...)
  __hip_bfloat16* W1b   = (__hip_bfloat16*)(wb + 84934656);             // 73,728 B
  __hip_bfloat16* W2b   = (__hip_bfloat16*)(wb + 85008384);             // 147,456 B
  __hip_bfloat16* inwb  = (__hip_bfloat16*)(wb + 85155840);             // 32,768 B
  __hip_bfloat16* wcombb= (__hip_bfloat16*)(wb + 85188608);             // 16,384 B
  __hip_bfloat16* pwbb  = (__hip_bfloat16*)(wb + 85204992);             // 8,192 B
  __hip_bfloat16* xpwb  = (__hip_bfloat16*)(wb + 85213184);             // 9,216 B
  float*          fst   = (float*)(wb + 85222400);

  float* acc_in1 = fst;
  float* acc_in2 = fst + 128;
  float* acc_inr = fst + 256;
  float* acc_pn  = fst + 384;
  float* ss_in1  = fst + 512;
  float* ss_in2  = fst + 640;
  float* ss_inr  = fst + 768;
  float* ss_pn   = fst + 896;
  int*   flagp   = (int*)(fst + 1024);

  hipMemsetAsync(fst, 0, 512 * sizeof(float), stream);

  k_detect<<<1, NTHREADS, 0, stream>>>(x, flagp);
  k_pad1<<<34 * 66, NTHREADS, 0, stream>>>(x, P1, flagp);
  k_prepw<<<144, NTHREADS, 0, stream>>>(c1_w, W1b, 32, flagp);
  k_prepw<<<288, NTHREADS, 0, stream>>>(c2_w, W2b, 64, flagp);
  k_prepcvt<<<64, NTHREADS, 0, stream>>>(in_proj_w, inwb, 16384, flagp);
  k_prepcvt<<<16, NTHREADS, 0, stream>>>(pw_w, pwbb, 4096, flagp);
  k_prepcvt<<<18, NTHREADS, 0, stream>>>(x_proj_w, xpwb, 4608, flagp);
  k_wcomb<<<32, NTHREADS, 0, stream>>>(proj_w, out_proj_w, wcombb, flagp);

  k_gemm_conv<32, 40><<<33 * 16, NTHREADS, 0, stream>>>(P1, W1b, c1raw, acc_in1);
  k_finalize<<<1, 64, 0, stream>>>(acc_in1, in1_g, in1_b, ss_in1, 1.0f / 135168.0f, flagp);
  k_normpad<<<35 * 66, NTHREADS, 0, stream>>>(c1raw, ss_in1, P2);

  k_gemm_conv<64, 88><<<34 * 16, NTHREADS, 0, stream>>>(P2, W2b, c2raw, acc_in2);
  k_finalize<<<1, 64, 0, stream>>>(acc_in2, in2_g, in2_b, ss_in2, 1.0f / 139264.0f, flagp);
  k_hslice_cl<<<2048, NTHREADS, 0, stream>>>(c2raw, ss_in2, hcl, d_out, flagp);

  k_dwpw_mfma<<<2048, NTHREADS, 0, stream>>>(hcl, dw_w, pwbb, pre2, acc_inr, flagp);
  k_finalize<<<1, 64, 0, stream>>>(acc_inr, inr_g, inr_b, ss_inr, 1.0f / 131072.0f, flagp);
  k_x2ln_cl<<<512, NTHREADS, 0, stream>>>(hcl, pre2, ss_inr, ln_g, ln_b, seq, flagp);

  k_inproj_mfma<<<2048, NTHREADS, 0, stream>>>(seq, inwb, x_in, zgb);
  k_conv1d_ip<<<2048, NTHREADS, 0, stream>>>(x_in, conv1d_w, conv1d_b, flagp);
  k_xproj_mfma<<<512, NTHREADS, 0, stream>>>(x_in, xpwb, xdbl);
  k_scan<<<2048, NTHREADS, 0, stream>>>(xdbl, x_in, zgb, dt_proj_w, dt_proj_b, A_log, D_p, flagp);
  k_outproj_mfma<<<512, NTHREADS, 0, stream>>>(x_in, wcombb, proj_b, s2, acc_pn, flagp);

  k_finalize<<<1, 64, 0, stream>>>(acc_pn, pn_g, pn_b, ss_pn, 1.0f / 131072.0f, flagp);
  k_final<<<2048, NTHREADS, 0, stream>>>(s2, d_out, ss_pn, flagp);
}

// Round 4
// 595.611 us; speedup vs baseline: 1.1720x; 1.0149x over previous
//
#include <hip/hip_runtime.h>
#include <hip/hip_bf16.h>

// Hybrid decoder block, MFMA everywhere GEMM-shaped, channels-last internals.
// row convention: r = z*4096 + n, n = y*64+x.
#define NTHREADS 256

typedef __attribute__((ext_vector_type(8))) short bs8_t;   // 8 bf16 (4 VGPRs)
typedef __attribute__((ext_vector_type(4))) float f4_t;    // 4 fp32 acc

__device__ __forceinline__ float bf2f(__hip_bfloat16 v) { return __bfloat162float(v); }
__device__ __forceinline__ __hip_bfloat16 f2bf(float v) { return __float2bfloat16(v); }
__device__ __forceinline__ float b2f_lo(unsigned int p) { return __uint_as_float(p << 16); }
__device__ __forceinline__ float b2f_hi(unsigned int p) { return __uint_as_float(p & 0xffff0000u); }
__device__ __forceinline__ float sigm(float x) { return 1.f / (1.f + __expf(-x)); }
__device__ __forceinline__ float leaky(float x) { return x > 0.f ? x : 0.01f * x; }
__device__ __forceinline__ float sane(float x) { return fminf(fmaxf(x, -1e9f), 1e9f); }
__device__ __forceinline__ unsigned packbf(float a, float b) {
  union { __hip_bfloat16 h[2]; unsigned u; } cv;
  cv.h[0] = f2bf(a); cv.h[1] = f2bf(b);
  return cv.u;
}
__device__ __forceinline__ float ldf(const void* p, long i, int f) {
  return f ? ((const float*)p)[i] : bf2f(((const __hip_bfloat16*)p)[i]);
}
// single-instruction 2^x (v_exp_f32); gfx9 trans ops are HW-interlocked.
__device__ __forceinline__ float exp2_fast(float x) {
  float r;
  asm("v_exp_f32 %0, %1" : "=v"(r) : "v"(x));
  return r;
}

// ---------------- dtype detector ----------------
__global__ void k_detect(const void* xp, int* flag) {
  __shared__ int cnt[NTHREADS];
  const __hip_bfloat16* h = (const __hip_bfloat16*)xp;
  int t = threadIdx.x;
  int c = 0;
  for (int j = 0; j < 8; j++) {
    float v = fabsf(bf2f(h[(t * 8 + j) * 2]));
    if (v > 1e-12f && v < 1e12f) c++;
  }
  cnt[t] = c;
  __syncthreads();
  for (int s = 128; s > 0; s >>= 1) {
    if (t < s) cnt[t] += cnt[t + s];
    __syncthreads();
  }
  if (t == 0) *flag = (cnt[0] > 1433) ? 0 : 1;
}

// generic converter: out[i] = bf16(in[i])
__global__ void k_prepcvt(const void* __restrict__ in, __hip_bfloat16* __restrict__ out,
                          int n, const int* __restrict__ flagp) {
  int f = *flagp;
  int gid = blockIdx.x * NTHREADS + threadIdx.x;
  if (gid < n) out[gid] = f2bf(ldf(in, gid, f));
}

// ---------------- pad1: x (ci-first) -> P1[z'(34)][y'(66)][x'(66)][32] bf16 ----------------
__global__ __launch_bounds__(NTHREADS) void k_pad1(const void* __restrict__ x,
                                                   __hip_bfloat16* __restrict__ P1,
                                                   const int* __restrict__ flagp) {
  __shared__ float tile[64 * 33];
  int f = *flagp;
  int zp = blockIdx.x / 66, yp = blockIdx.x % 66;
  long rowbase = ((long)zp * 66 + yp) * 66 * 32;
  int t = threadIdx.x;
  if (zp == 0 || zp == 33 || yp == 0 || yp == 65) {
    for (int i = t; i < 2112; i += NTHREADS) P1[rowbase + i] = f2bf(0.f);
    return;
  }
  int z = zp - 1, y = yp - 1;
#pragma unroll
  for (int j = 0; j < 8; j++) {
    int idx = t + j * NTHREADS;
    int ci = idx >> 6, xx = idx & 63;
    tile[xx * 33 + ci] = ldf(x, (long)(ci * 32 + z) * 4096 + y * 64 + xx, f);
  }
  __syncthreads();
#pragma unroll
  for (int j = 0; j < 8; j++) {
    int idx = t + j * NTHREADS;
    int xx = idx >> 5, ci = idx & 31;
    P1[rowbase + (xx + 1) * 32 + ci] = f2bf(tile[xx * 33 + ci]);
  }
  if (t < 32) P1[rowbase + t] = f2bf(0.f);
  else if (t < 64) P1[rowbase + 65 * 32 + (t - 32)] = f2bf(0.f);
}

// ---------------- weight reorg: cw (co,ci,2,3,3) -> W[s][co][ci] bf16 ----------------
__global__ void k_prepw(const void* __restrict__ cw, __hip_bfloat16* __restrict__ W,
                        int CI, const int* __restrict__ flagp) {
  int f = *flagp;
  int gid = blockIdx.x * NTHREADS + threadIdx.x;
  int s = gid / (64 * CI);
  int rem = gid % (64 * CI);
  int co = rem / CI, ci = rem % CI;
  W[gid] = f2bf(ldf(cw, (long)(co * CI + ci) * 18 + s, f));
}

// ---------------- MFMA implicit-GEMM conv + fused per-channel stats ----------------
template <int CI, int CIP>
__global__ __launch_bounds__(NTHREADS) void k_gemm_conv(const __hip_bfloat16* __restrict__ Pb,
                                                        const __hip_bfloat16* __restrict__ Wb,
                                                        __hip_bfloat16* __restrict__ out,
                                                        float* __restrict__ gacc) {
  __shared__ unsigned short Wl[3 * 64 * CIP];
  __shared__ float sred[256], qred[256];
  const unsigned short* P = (const unsigned short*)Pb;
  const unsigned short* W = (const unsigned short*)Wb;
  int t = threadIdx.x;
  int wv = t >> 6, lane = t & 63;
  int m = lane & 15, quad = lane >> 4;
  int zo = blockIdx.x >> 4;
  int y  = ((blockIdx.x & 15) << 2) + wv;
  f4_t zero4 = {0.f, 0.f, 0.f, 0.f};
  f4_t acc[4][4];
#pragma unroll
  for (int mt = 0; mt < 4; mt++)
#pragma unroll
    for (int nt = 0; nt < 4; nt++) acc[mt][nt] = zero4;

  for (int kz = 0; kz < 2; kz++) {
    for (int ky = 0; ky < 3; ky++) {
      __syncthreads();
      int s0 = (kz * 3 + ky) * 3;
      const unsigned short* wsrc = W + (long)s0 * 64 * CI;
      for (int i = t; i < 3 * 64 * CI; i += NTHREADS) {
        int kx = i / (64 * CI), rem = i % (64 * CI);
        int co = rem / CI, ci = rem % CI;
        Wl[(kx * 64 + co) * CIP + ci] = wsrc[i];
      }
      __syncthreads();
      int pz = zo + kz, py = y + ky;
      const unsigned short* prow = P + ((long)(pz * 66 + py) * 66) * CI;
#pragma unroll
      for (int kx = 0; kx < 3; kx++) {
#pragma unroll
        for (int ch = 0; ch < CI / 32; ch++) {
          int kof = kx * CI + ch * 32 + quad * 8;
          bs8_t a0 = *(const bs8_t*)(prow + (0 * 16 + m) * CI + kof);
          bs8_t a1 = *(const bs8_t*)(prow + (1 * 16 + m) * CI + kof);
          bs8_t a2 = *(const bs8_t*)(prow + (2 * 16 + m) * CI + kof);
          bs8_t a3 = *(const bs8_t*)(prow + (3 * 16 + m) * CI + kof);
#pragma unroll
          for (int nt = 0; nt < 4; nt++) {
            bs8_t b = *(const bs8_t*)&Wl[(kx * 64 + nt * 16 + m) * CIP + ch * 32 + quad * 8];
            acc[0][nt] = __builtin_amdgcn_mfma_f32_16x16x32_bf16(a0, b, acc[0][nt], 0, 0, 0);
            acc[1][nt] = __builtin_amdgcn_mfma_f32_16x16x32_bf16(a1, b, acc[1][nt], 0, 0, 0);
            acc[2][nt] = __builtin_amdgcn_mfma_f32_16x16x32_bf16(a2, b, acc[2][nt], 0, 0, 0);
            acc[3][nt] = __builtin_amdgcn_mfma_f32_16x16x32_bf16(a3, b, acc[3][nt], 0, 0, 0);
          }
        }
      }
    }
  }
  long obase = ((long)(zo * 64 + y) * 64) * 64;
  float psum[4], pq[4];
#pragma unroll
  for (int nt = 0; nt < 4; nt++) {
    int co = nt * 16 + m;
    float s = 0.f, q = 0.f;
#pragma unroll
    for (int mt = 0; mt < 4; mt++)
#pragma unroll
      for (int rg = 0; rg < 4; rg++) {
        float v = acc[mt][nt][rg];
        int xx = mt * 16 + quad * 4 + rg;
        out[obase + xx * 64 + co] = f2bf(v);
        s += v;
        q += v * v;
      }
    psum[nt] = s;
    pq[nt] = q;
  }
#pragma unroll
  for (int nt = 0; nt < 4; nt++) {
    psum[nt] += __shfl_xor(psum[nt], 16, 64);
    psum[nt] += __shfl_xor(psum[nt], 32, 64);
    pq[nt]   += __shfl_xor(pq[nt], 16, 64);
    pq[nt]   += __shfl_xor(pq[nt], 32, 64);
  }
  if (quad == 0) {
#pragma unroll
    for (int nt = 0; nt < 4; nt++) {
      sred[wv * 64 + nt * 16 + m] = psum[nt];
      qred[wv * 64 + nt * 16 + m] = pq[nt];
    }
  }
  __syncthreads();
  if (t < 64) {
    atomicAdd(&gacc[t], sred[t] + sred[64 + t] + sred[128 + t] + sred[192 + t]);
    atomicAdd(&gacc[64 + t], qred[t] + qred[64 + t] + qred[128 + t] + qred[192 + t]);
  }
}

__global__ void k_finalize(const float* __restrict__ acc, const void* __restrict__ g,
                           const void* __restrict__ b, float* __restrict__ ss, float invN,
                           const int* __restrict__ flagp) {
  int f = *flagp;
  int t = threadIdx.x;  // 64
  float mean = acc[t] * invN;
  float var  = acc[64 + t] * invN - mean * mean;
  float rstd = rsqrtf(fmaxf(var, 0.f) + 1e-5f);
  float sc   = ldf(g, t, f) * rstd;
  ss[t]      = sc;
  ss[64 + t] = ldf(b, t, f) - mean * sc;
}

// ---------------- normpad: c1raw -> norm+leaky -> P2[35][66][66][64] ----------------
__global__ __launch_bounds__(NTHREADS) void k_normpad(const __hip_bfloat16* __restrict__ in,
                                                      const float* __restrict__ ss,
                                                      __hip_bfloat16* __restrict__ P2) {
  int zp = blockIdx.x / 66, yp = blockIdx.x % 66;
  long rowbase = ((long)zp * 66 + yp) * 66 * 64;
  int t = threadIdx.x;
  if (zp == 0 || zp == 34 || yp == 0 || yp == 65) {
    for (int i = t; i < 4224; i += NTHREADS) P2[rowbase + i] = f2bf(0.f);
    return;
  }
  int z = zp - 1, y = yp - 1;
#pragma unroll
  for (int j = 0; j < 16; j++) {
    int idx = t + j * NTHREADS;
    int xx = idx >> 6, co = idx & 63;
    float v = bf2f(in[((long)(z * 64 + y) * 64 + xx) * 64 + co]) * ss[co] + ss[64 + co];
    P2[rowbase + (xx + 1) * 64 + co] = f2bf(leaky(v));
  }
  if (t < 64) P2[rowbase + t] = f2bf(0.f);
  else if (t < 128) P2[rowbase + 65 * 64 + (t - 64)] = f2bf(0.f);
}

// ---------------- hslice: c2raw -> norm+leaky -> hcl + residual d_out[c][r] ----------------
__global__ __launch_bounds__(NTHREADS) void k_hslice_cl(const __hip_bfloat16* __restrict__ in,
                                                        const float* __restrict__ ss,
                                                        __hip_bfloat16* __restrict__ hcl,
                                                        void* __restrict__ resid,
                                                        const int* __restrict__ flagp) {
  __shared__ float tile[64 * 65];
  int f = *flagp;
  int z = blockIdx.x >> 6, y = blockIdx.x & 63;
  long r0 = (long)z * 4096 + y * 64;
  int t = threadIdx.x;
#pragma unroll
  for (int j = 0; j < 16; j++) {
    int idx = t + j * NTHREADS;
    int xx = idx >> 6, co = idx & 63;
    float v = leaky(bf2f(in[(r0 + xx) * 64 + co]) * ss[co] + ss[64 + co]);
    hcl[(r0 + xx) * 64 + co] = f2bf(v);
    tile[xx * 65 + co] = v;
  }
  __syncthreads();
#pragma unroll
  for (int j = 0; j < 16; j++) {
    int idx = t + j * NTHREADS;
    int co = idx >> 6, xx = idx & 63;
    long off = (long)co * 131072 + r0 + xx;
    if (f) ((float*)resid)[off] = tile[xx * 65 + co];
    else   ((__hip_bfloat16*)resid)[off] = f2bf(tile[xx * 65 + co]);
  }
}

// ---------------- dw3x3 + pw1x1 (MFMA pointwise) + inr stats ----------------
__global__ __launch_bounds__(NTHREADS) void k_dwpw_mfma(const __hip_bfloat16* __restrict__ hcl,
                                                        const void* __restrict__ dwb,
                                                        const __hip_bfloat16* __restrict__ pwbb,
                                                        __hip_bfloat16* __restrict__ out,
                                                        float* __restrict__ acc,
                                                        const int* __restrict__ flagp) {
  __shared__ unsigned short hl[3 * 64 * 64];
  __shared__ unsigned short dwt[64 * 72];
  __shared__ unsigned short pwl[64 * 72];
  __shared__ float dwl[576];
  __shared__ float sred[256], qred[256];
  int f = *flagp;
  int t = threadIdx.x;
  int z = blockIdx.x >> 6, y = blockIdx.x & 63;
  for (int i = t; i < 576; i += NTHREADS) dwl[i] = ldf(dwb, i, f);
  {
    const unsigned short* ps = (const unsigned short*)pwbb;
    for (int i = t; i < 4096; i += NTHREADS) pwl[(i >> 6) * 72 + (i & 63)] = ps[i];
  }
  const unsigned short* hsrc = (const unsigned short*)hcl;
  for (int i = t; i < 12288; i += NTHREADS) {
    int dy = i / 4096, rem = i & 4095;
    int ry = y - 1 + dy;
    hl[i] = ((unsigned)ry < 64u) ? hsrc[((long)z * 4096 + ry * 64) * 64 + rem] : (unsigned short)0;
  }
  __syncthreads();
  const unsigned* hl32 = (const unsigned*)hl;
  unsigned* dwt32 = (unsigned*)dwt;
#pragma unroll
  for (int j = 0; j < 8; j++) {
    int idx = t + j * NTHREADS;
    int xx = idx >> 5, cp = idx & 31;
    float a0 = 0.f, a1 = 0.f;
#pragma unroll
    for (int dy = 0; dy < 3; dy++)
#pragma unroll
      for (int dx = 0; dx < 3; dx++) {
        int xv = xx - 1 + dx;
        if ((unsigned)xv < 64u) {
          unsigned hv = hl32[(dy * 64 + xv) * 32 + cp];
          a0 = fmaf(b2f_lo(hv), dwl[(cp * 2) * 9 + dy * 3 + dx], a0);
          a1 = fmaf(b2f_hi(hv), dwl[(cp * 2 + 1) * 9 + dy * 3 + dx], a1);
        }
      }
    dwt32[xx * 36 + cp] = packbf(a0, a1);
  }
  __syncthreads();
  int wv = t >> 6, lane = t & 63;
  int m = lane & 15, quad = lane >> 4;
  f4_t zero4 = {0.f, 0.f, 0.f, 0.f};
  f4_t acc4[4];
#pragma unroll
  for (int nt = 0; nt < 4; nt++) acc4[nt] = zero4;
#pragma unroll
  for (int ch = 0; ch < 2; ch++) {
    bs8_t a = *(const bs8_t*)&dwt[(wv * 16 + m) * 72 + ch * 32 + quad * 8];
#pragma unroll
    for (int nt = 0; nt < 4; nt++) {
      bs8_t b = *(const bs8_t*)&pwl[(nt * 16 + m) * 72 + ch * 32 + quad * 8];
      acc4[nt] = __builtin_amdgcn_mfma_f32_16x16x32_bf16(a, b, acc4[nt], 0, 0, 0);
    }
  }
  long obase = ((long)z * 4096 + y * 64) * 64;
  float psum[4], pq[4];
#pragma unroll
  for (int nt = 0; nt < 4; nt++) {
    float s = 0.f, q = 0.f;
#pragma unroll
    for (int rg = 0; rg < 4; rg++) {
      float v = acc4[nt][rg];
      int xx = wv * 16 + quad * 4 + rg;
      out[obase + xx * 64 + nt * 16 + m] = f2bf(v);
      s += v;
      q += v * v;
    }
    psum[nt] = s;
    pq[nt] = q;
  }
#pragma unroll
  for (int nt = 0; nt < 4; nt++) {
    psum[nt] += __shfl_xor(psum[nt], 16, 64);
    psum[nt] += __shfl_xor(psum[nt], 32, 64);
    pq[nt]   += __shfl_xor(pq[nt], 16, 64);
    pq[nt]   += __shfl_xor(pq[nt], 32, 64);
  }
  if (quad == 0) {
#pragma unroll
    for (int nt = 0; nt < 4; nt++) {
      sred[wv * 64 + nt * 16 + m] = psum[nt];
      qred[wv * 64 + nt * 16 + m] = pq[nt];
    }
  }
  __syncthreads();
  if (t < 64) {
    atomicAdd(&acc[t], sred[t] + sred[64 + t] + sred[128 + t] + sred[192 + t]);
    atomicAdd(&acc[64 + t], qred[t] + qred[64 + t] + qred[128 + t] + qred[192 + t]);
  }
}

// ---------------- x2 = h + silu(norm(pre2)); LayerNorm C=64 -> seq bf16 ----------------
__global__ __launch_bounds__(NTHREADS) void k_x2ln_cl(const __hip_bfloat16* __restrict__ hcl,
                                                      const __hip_bfloat16* __restrict__ p2,
                                                      const float* __restrict__ ssr,
                                                      const void* __restrict__ lng,
                                                      const void* __restrict__ lnb,
                                                      __hip_bfloat16* __restrict__ out,
                                                      const int* __restrict__ flagp) {
  __shared__ float sc[64], sh[64], sg[64], sb[64];
  int f = *flagp;
  int t = threadIdx.x;
  if (t < 64) {
    sc[t] = ssr[t];
    sh[t] = ssr[64 + t];
    sg[t] = ldf(lng, t, f);
    sb[t] = ldf(lnb, t, f);
  }
  __syncthreads();
  long r = (long)blockIdx.x * NTHREADS + t;
  const uint4* hp = (const uint4*)(hcl + r * 64);
  const uint4* pp = (const uint4*)(p2 + r * 64);
  float v[64];
  float s1 = 0.f;
#pragma unroll
  for (int q = 0; q < 8; q++) {
    uint4 hu = hp[q], pu = pp[q];
    float hv[8] = {b2f_lo(hu.x), b2f_hi(hu.x), b2f_lo(hu.y), b2f_hi(hu.y),
                   b2f_lo(hu.z), b2f_hi(hu.z), b2f_lo(hu.w), b2f_hi(hu.w)};
    float pv[8] = {b2f_lo(pu.x), b2f_hi(pu.x), b2f_lo(pu.y), b2f_hi(pu.y),
                   b2f_lo(pu.z), b2f_hi(pu.z), b2f_lo(pu.w), b2f_hi(pu.w)};
#pragma unroll
    for (int i = 0; i < 8; i++) {
      int c = q * 8 + i;
      float pn = sc[c] * pv[i] + sh[c];
      float x2 = hv[i] + pn * sigm(pn);
      v[c] = x2;
      s1 += x2;
    }
  }
  float m = s1 * (1.f / 64.f);
  float s2 = 0.f;
#pragma unroll
  for (int c = 0; c < 64; c++) {
    float d = v[c] - m;
    s2 += d * d;
  }
  float rstd = rsqrtf(s2 * (1.f / 64.f) + 1e-5f);
  uint4* o4 = (uint4*)(out + r * 64);
#pragma unroll
  for (int q = 0; q < 8; q++) {
    int c = q * 8;
    uint4 o;
    o.x = packbf((v[c + 0] - m) * rstd * sg[c + 0] + sb[c + 0],
                 (v[c + 1] - m) * rstd * sg[c + 1] + sb[c + 1]);
    o.y = packbf((v[c + 2] - m) * rstd * sg[c + 2] + sb[c + 2],
                 (v[c + 3] - m) * rstd * sg[c + 3] + sb[c + 3]);
    o.z = packbf((v[c + 4] - m) * rstd * sg[c + 4] + sb[c + 4],
                 (v[c + 5] - m) * rstd * sg[c + 5] + sb[c + 5]);
    o.w = packbf((v[c + 6] - m) * rstd * sg[c + 6] + sb[c + 6],
                 (v[c + 7] - m) * rstd * sg[c + 7] + sb[c + 7]);
    o4[q] = o;
  }
}

// ---------------- in_proj MFMA ----------------
__global__ __launch_bounds__(NTHREADS) void k_inproj_mfma(const __hip_bfloat16* __restrict__ seq,
                                                          const __hip_bfloat16* __restrict__ Wbf,
                                                          __hip_bfloat16* __restrict__ x_in,
                                                          __hip_bfloat16* __restrict__ zg) {
  __shared__ unsigned short Wl[256 * 72];
  const unsigned short* ws = (const unsigned short*)Wbf;
  int t = threadIdx.x;
  for (int i = t; i < 16384; i += NTHREADS) Wl[(i >> 6) * 72 + (i & 63)] = ws[i];
  __syncthreads();
  int wv = t >> 6, lane = t & 63;
  int m = lane & 15, quad = lane >> 4;
  long m0 = (long)blockIdx.x * 64;
  int n0 = wv * 64;
  f4_t zero4 = {0.f, 0.f, 0.f, 0.f};
  f4_t acc[4][4];
#pragma unroll
  for (int mt = 0; mt < 4; mt++)
#pragma unroll
    for (int nt = 0; nt < 4; nt++) acc[mt][nt] = zero4;
  const unsigned short* sp = (const unsigned short*)seq;
#pragma unroll
  for (int ch = 0; ch < 2; ch++) {
    int kof = ch * 32 + quad * 8;
    bs8_t a0 = *(const bs8_t*)(sp + (m0 + 0 * 16 + m) * 64 + kof);
    bs8_t a1 = *(const bs8_t*)(sp + (m0 + 1 * 16 + m) * 64 + kof);
    bs8_t a2 = *(const bs8_t*)(sp + (m0 + 2 * 16 + m) * 64 + kof);
    bs8_t a3 = *(const bs8_t*)(sp + (m0 + 3 * 16 + m) * 64 + kof);
#pragma unroll
    for (int nt = 0; nt < 4; nt++) {
      bs8_t b = *(const bs8_t*)&Wl[(n0 + nt * 16 + m) * 72 + kof];
      acc[0][nt] = __builtin_amdgcn_mfma_f32_16x16x32_bf16(a0, b, acc[0][nt], 0, 0, 0);
      acc[1][nt] = __builtin_amdgcn_mfma_f32_16x16x32_bf16(a1, b, acc[1][nt], 0, 0, 0);
      acc[2][nt] = __builtin_amdgcn_mfma_f32_16x16x32_bf16(a2, b, acc[2][nt], 0, 0, 0);
      acc[3][nt] = __builtin_amdgcn_mfma_f32_16x16x32_bf16(a3, b, acc[3][nt], 0, 0, 0);
    }
  }
  __hip_bfloat16* obuf = (n0 < 128) ? x_in : zg;
  int cbase = (n0 < 128) ? n0 : (n0 - 128);
#pragma unroll
  for (int mt = 0; mt < 4; mt++)
#pragma unroll
    for (int nt = 0; nt < 4; nt++) {
      int col = cbase + nt * 16 + m;
#pragma unroll
      for (int rg = 0; rg < 4; rg++) {
        long row = m0 + mt * 16 + quad * 4 + rg;
        obuf[row * 128 + col] = f2bf(acc[mt][nt][rg]);
      }
    }
}

// ---------------- causal depthwise conv1d, in place ----------------
__global__ __launch_bounds__(NTHREADS) void k_conv1d_ip(__hip_bfloat16* xio,
                                                        const void* __restrict__ wb,
                                                        const void* __restrict__ bb,
                                                        const int* __restrict__ flagp) {
  int f = *flagp;
  int gid = blockIdx.x * NTHREADS + threadIdx.x;
  int d = gid & 127, nl = gid >> 7;
  float w0 = ldf(wb, d * 4 + 0, f), w1 = ldf(wb, d * 4 + 1, f);
  float w2 = ldf(wb, d * 4 + 2, f), w3 = ldf(wb, d * 4 + 3, f);
  float bias = ldf(bb, d, f);
  float h0 = 0.f, h1 = 0.f, h2 = 0.f;
  size_t off = (size_t)nl * 128 + d;
  const size_t stride = 4096u * 128u;
  for (int z = 0; z < 32; z++) {
    float xv = bf2f(xio[off]);
    float a = bias;
    a = fmaf(h0, w0, a);
    a = fmaf(h1, w1, a);
    a = fmaf(h2, w2, a);
    a = fmaf(xv, w3, a);
    xio[off] = f2bf(a * sigm(a));
    h0 = h1; h1 = h2; h2 = xv;
    off += stride;
  }
}

// ---------------- x_proj MFMA: (131072,128) x (36->48 pad,128)^T ----------------
// outputs: dtin[r][4] f32 (cols 0..3) and BC[r][32] f32 (cols 4..35)
__global__ __launch_bounds__(NTHREADS) void k_xproj_mfma(const __hip_bfloat16* __restrict__ A,
                                                         const __hip_bfloat16* __restrict__ Wbf,
                                                         float* __restrict__ dtin,
                                                         float* __restrict__ BC) {
  __shared__ unsigned short Wl[48 * 136];
  const unsigned short* ws = (const unsigned short*)Wbf;   // (36,128) row-major
  int t = threadIdx.x;
  for (int i = t; i < 48 * 128; i += NTHREADS) {
    int j = i >> 7, k = i & 127;
    Wl[j * 136 + k] = (j < 36) ? ws[j * 128 + k] : (unsigned short)0;
  }
  __syncthreads();
  int wv = t >> 6, lane = t & 63;
  int m = lane & 15, quad = lane >> 4;
  long m0 = (long)blockIdx.x * 256 + wv * 64;
  f4_t zero4 = {0.f, 0.f, 0.f, 0.f};
  f4_t acc[4][3];
#pragma unroll
  for (int mt = 0; mt < 4; mt++)
#pragma unroll
    for (int nt = 0; nt < 3; nt++) acc[mt][nt] = zero4;
  const unsigned short* ap = (const unsigned short*)A;
#pragma unroll
  for (int ch = 0; ch < 4; ch++) {
    int kof = ch * 32 + quad * 8;
    bs8_t a0 = *(const bs8_t*)(ap + (m0 + 0 * 16 + m) * 128 + kof);
    bs8_t a1 = *(const bs8_t*)(ap + (m0 + 1 * 16 + m) * 128 + kof);
    bs8_t a2 = *(const bs8_t*)(ap + (m0 + 2 * 16 + m) * 128 + kof);
    bs8_t a3 = *(const bs8_t*)(ap + (m0 + 3 * 16 + m) * 128 + kof);
#pragma unroll
    for (int nt = 0; nt < 3; nt++) {
      bs8_t b = *(const bs8_t*)&Wl[(nt * 16 + m) * 136 + kof];
      acc[0][nt] = __builtin_amdgcn_mfma_f32_16x16x32_bf16(a0, b, acc[0][nt], 0, 0, 0);
      acc[1][nt] = __builtin_amdgcn_mfma_f32_16x16x32_bf16(a1, b, acc[1][nt], 0, 0, 0);
      acc[2][nt] = __builtin_amdgcn_mfma_f32_16x16x32_bf16(a2, b, acc[2][nt], 0, 0, 0);
      acc[3][nt] = __builtin_amdgcn_mfma_f32_16x16x32_bf16(a3, b, acc[3][nt], 0, 0, 0);
    }
  }
#pragma unroll
  for (int mt = 0; mt < 4; mt++)
#pragma unroll
    for (int nt = 0; nt < 3; nt++) {
      int col = nt * 16 + m;
#pragma unroll
      for (int rg = 0; rg < 4; rg++) {
        long row = m0 + mt * 16 + quad * 4 + rg;
        float v = acc[mt][nt][rg];
        if (col < 4) dtin[row * 4 + col] = v;
        else if (col < 36) BC[row * 32 + (col - 4)] = v;
      }
    }
}

// ---------------- selective scan ----------------
// f32 dt/B/C inputs (no bf16 unpack); geometric-A fast path detected at runtime:
// if A[d][s] == (s+1)*A[d][0] (the A_log = log(arange) structure), then
// exp(dt*A[s]) = e1^(s+1) with a single v_exp per step instead of 16.
// General fallback path kept for arbitrary A (e.g. bf16-rounded inputs).
__global__ __launch_bounds__(NTHREADS) void k_scan(const float* __restrict__ dtin,
                                                   const float* __restrict__ BC,
                                                   __hip_bfloat16* __restrict__ uy,
                                                   const __hip_bfloat16* __restrict__ zg,
                                                   const void* __restrict__ dtw,
                                                   const void* __restrict__ dtb,
                                                   const void* __restrict__ Alog,
                                                   const void* __restrict__ Dp,
                                                   const int* __restrict__ flagp) {
  int f = *flagp;
  int gid = blockIdx.x * NTHREADS + threadIdx.x;
  int d = gid & 127, n = gid >> 7;
  // A2[s] = -exp(A_log[d][s]) * log2(e): exp(dt*A) == exp2(dt*A2)
  float A2[16];
#pragma unroll
  for (int s = 0; s < 16; s++)
    A2[s] = -__expf(fminf(ldf(Alog, d * 16 + s, f), 60.f)) * 1.44269504088896f;
  float W0 = ldf(dtw, d * 4 + 0, f), W1 = ldf(dtw, d * 4 + 1, f);
  float W2 = ldf(dtw, d * 4 + 2, f), W3 = ldf(dtw, d * 4 + 3, f);
  float bias = ldf(dtb, d, f);
  float Dv = ldf(Dp, d, f);
  float a0 = A2[0];
  int geo = 1;
#pragma unroll
  for (int s = 1; s < 16; s++)
    geo &= (fabsf(A2[s] - (float)(s + 1) * a0) <= 1e-4f * fabsf(A2[s])) ? 1 : 0;
  geo = __all(geo);
  float st[16];
#pragma unroll
  for (int s = 0; s < 16; s++) st[s] = 0.f;
  if (geo) {
    for (int z = 0; z < 32; z++) {
      size_t r = (size_t)(z << 12) | n;
      const float4* bp = (const float4*)(BC + r * 32);
      float4 dt4 = *(const float4*)(dtin + r * 4);
      float4 b0 = bp[0], b1 = bp[1], b2 = bp[2], b3 = bp[3];
      float4 c0 = bp[4], c1 = bp[5], c2 = bp[6], c3 = bp[7];
      float u = sane(bf2f(uy[r * 128 + d]));
      float zv = sane(bf2f(zg[r * 128 + d]));
      float v = bias;
      v = fmaf(dt4.x, W0, v);
      v = fmaf(dt4.y, W1, v);
      v = fmaf(dt4.z, W2, v);
      v = fmaf(dt4.w, W3, v);
      float dtv = v > 20.f ? v : __logf(1.f + __expf(v));
      dtv = fminf(fmaxf(dtv, 0.f), 60.f);
      float du = dtv * u;
      float e1 = exp2_fast(dtv * a0);
      float B[16] = {b0.x, b0.y, b0.z, b0.w, b1.x, b1.y, b1.z, b1.w,
                     b2.x, b2.y, b2.z, b2.w, b3.x, b3.y, b3.z, b3.w};
      float C[16] = {c0.x, c0.y, c0.z, c0.w, c1.x, c1.y, c1.z, c1.w,
                     c2.x, c2.y, c2.z, c2.w, c3.x, c3.y, c3.z, c3.w};
      float es = e1;
      float y = 0.f;
#pragma unroll
      for (int s = 0; s < 16; s++) {
        st[s] = fmaf(es, st[s], du * B[s]);
        y = fmaf(st[s], C[s], y);
        es *= e1;
      }
      y = sane((y + Dv * u) * (zv * sigm(zv)));
      uy[r * 128 + d] = f2bf(y);
    }
  } else {
#pragma unroll
    for (int s = 0; s < 16; s++) asm("" : "+v"(A2[s]));  // pin; forbid remat/AGPR
    for (int z = 0; z < 32; z++) {
      size_t r = (size_t)(z << 12) | n;
      const float4* bp = (const float4*)(BC + r * 32);
      float4 dt4 = *(const float4*)(dtin + r * 4);
      float4 b0 = bp[0], b1 = bp[1], b2 = bp[2], b3 = bp[3];
      float4 c0 = bp[4], c1 = bp[5], c2 = bp[6], c3 = bp[7];
      float u = sane(bf2f(uy[r * 128 + d]));
      float zv = sane(bf2f(zg[r * 128 + d]));
      float v = bias;
      v = fmaf(dt4.x, W0, v);
      v = fmaf(dt4.y, W1, v);
      v = fmaf(dt4.z, W2, v);
      v = fmaf(dt4.w, W3, v);
      float dtv = v > 20.f ? v : __logf(1.f + __expf(v));
      dtv = fminf(fmaxf(dtv, 0.f), 60.f);
      float du = dtv * u;
      float B[16] = {b0.x, b0.y, b0.z, b0.w, b1.x, b1.y, b1.z, b1.w,
                     b2.x, b2.y, b2.z, b2.w, b3.x, b3.y, b3.z, b3.w};
      float C[16] = {c0.x, c0.y, c0.z, c0.w, c1.x, c1.y, c1.z, c1.w,
                     c2.x, c2.y, c2.z, c2.w, c3.x, c3.y, c3.z, c3.w};
      float y = 0.f;
#pragma unroll
      for (int s = 0; s < 16; s++) {
        float e = exp2_fast(dtv * A2[s]);
        st[s] = fmaf(e, st[s], du * B[s]);
        y = fmaf(st[s], C[s], y);
      }
      y = sane((y + Dv * u) * (zv * sigm(zv)));
      uy[r * 128 + d] = f2bf(y);
    }
  }
}

// ---------------- W_comb = proj_w @ out_proj_w -> bf16 [o][d] ----------------
__global__ void k_wcomb(const void* __restrict__ pw, const void* __restrict__ opw,
                        __hip_bfloat16* __restrict__ wc, const int* __restrict__ flagp) {
  int f = *flagp;
  int gid = blockIdx.x * NTHREADS + threadIdx.x;
  int d = gid & 127, o = gid >> 7;
  float a = 0.f;
#pragma unroll
  for (int j = 0; j < 64; j++) a = fmaf(ldf(pw, o * 64 + j, f), ldf(opw, j * 128 + d, f), a);
  wc[(size_t)o * 128 + d] = f2bf(a);
}

// ---------------- out_proj+proj MFMA + fused pn stats ----------------
__global__ __launch_bounds__(NTHREADS) void k_outproj_mfma(const __hip_bfloat16* __restrict__ A,
                                                           const __hip_bfloat16* __restrict__ Wcb,
                                                           const void* __restrict__ bias,
                                                           __hip_bfloat16* __restrict__ out,
                                                           float* __restrict__ gacc,
                                                           const int* __restrict__ flagp) {
  __shared__ unsigned short Wl[64 * 136];
  __shared__ float bl[64];
  __shared__ float sred[256], qred[256];
  int f = *flagp;
  int t = threadIdx.x;
  const unsigned short* ws = (const unsigned short*)Wcb;
  for (int i = t; i < 8192; i += NTHREADS) Wl[(i >> 7) * 136 + (i & 127)] = ws[i];
  if (t < 64) bl[t] = ldf(bias, t, f);
  __syncthreads();
  int wv = t >> 6, lane = t & 63;
  int m = lane & 15, quad = lane >> 4;
  long m0 = (long)blockIdx.x * 256 + wv * 64;
  f4_t zero4 = {0.f, 0.f, 0.f, 0.f};
  f4_t acc[4][4];
#pragma unroll
  for (int mt = 0; mt < 4; mt++)
#pragma unroll
    for (int nt = 0; nt < 4; nt++) acc[mt][nt] = zero4;
  const unsigned short* ap = (const unsigned short*)A;
#pragma unroll
  for (int ch = 0; ch < 4; ch++) {
    int kof = ch * 32 + quad * 8;
    bs8_t a0 = *(const bs8_t*)(ap + (m0 + 0 * 16 + m) * 128 + kof);
    bs8_t a1 = *(const bs8_t*)(ap + (m0 + 1 * 16 + m) * 128 + kof);
    bs8_t a2 = *(const bs8_t*)(ap + (m0 + 2 * 16 + m) * 128 + kof);
    bs8_t a3 = *(const bs8_t*)(ap + (m0 + 3 * 16 + m) * 128 + kof);
#pragma unroll
    for (int nt = 0; nt < 4; nt++) {
      bs8_t b = *(const bs8_t*)&Wl[(nt * 16 + m) * 136 + kof];
      acc[0][nt] = __builtin_amdgcn_mfma_f32_16x16x32_bf16(a0, b, acc[0][nt], 0, 0, 0);
      acc[1][nt] = __builtin_amdgcn_mfma_f32_16x16x32_bf16(a1, b, acc[1][nt], 0, 0, 0);
      acc[2][nt] = __builtin_amdgcn_mfma_f32_16x16x32_bf16(a2, b, acc[2][nt], 0, 0, 0);
      acc[3][nt] = __builtin_amdgcn_mfma_f32_16x16x32_bf16(a3, b, acc[3][nt], 0, 0, 0);
    }
  }
  float psum[4], pq[4];
#pragma unroll
  for (int nt = 0; nt < 4; nt++) {
    int co = nt * 16 + m;
    float s = 0.f, q = 0.f;
#pragma unroll
    for (int mt = 0; mt < 4; mt++)
#pragma unroll
      for (int rg = 0; rg < 4; rg++) {
        float v = sane(acc[mt][nt][rg] + bl[co]);
        long row = m0 + mt * 16 + quad * 4 + rg;
        out[row * 64 + co] = f2bf(v);
        s += v;
        q += v * v;
      }
    psum[nt] = s;
    pq[nt] = q;
  }
#pragma unroll
  for (int nt = 0; nt < 4; nt++) {
    psum[nt] += __shfl_xor(psum[nt], 16, 64);
    psum[nt] += __shfl_xor(psum[nt], 32, 64);
    pq[nt]   += __shfl_xor(pq[nt], 16, 64);
    pq[nt]   += __shfl_xor(pq[nt], 32, 64);
  }
  if (quad == 0) {
#pragma unroll
    for (int nt = 0; nt < 4; nt++) {
      sred[wv * 64 + nt * 16 + m] = psum[nt];
      qred[wv * 64 + nt * 16 + m] = pq[nt];
    }
  }
  __syncthreads();
  if (t < 64) {
    atomicAdd(&gacc[t], sred[t] + sred[64 + t] + sred[128 + t] + sred[192 + t]);
    atomicAdd(&gacc[64 + t], qred[t] + qred[64 + t] + qred[128 + t] + qred[192 + t]);
  }
}

// ---------------- final ----------------
__global__ __launch_bounds__(NTHREADS) void k_final(const __hip_bfloat16* __restrict__ s2,
                                                    void* __restrict__ io,
                                                    const float* __restrict__ ss,
                                                    const int* __restrict__ flagp) {
  __shared__ float tile[64 * 65];
  __shared__ float sc[64], sh[64];
  int f = *flagp;
  int t = threadIdx.x;
  if (t < 64) {
    sc[t] = ss[t];
    sh[t] = ss[64 + t];
  }
  int z = blockIdx.x >> 6, n0 = (blockIdx.x & 63) << 6;
  size_t base = ((size_t)z * 4096 + n0) * 64;
  __syncthreads();
#pragma unroll
  for (int jj = 0; jj < 16; jj++) {
    int id = t + jj * NTHREADS;
    int i = id >> 6, c = id & 63;
    float v = sane(bf2f(s2[base + id]));
    tile[i * 65 + c] = sc[c] * v + sh[c];
  }
  __syncthreads();
#pragma unroll
  for (int jj = 0; jj < 16; jj++) {
    int id = t + jj * NTHREADS;
    int c = id >> 6, nl = id & 63;
    size_t off = (size_t)c * 131072 + (size_t)z * 4096 + n0 + nl;
    if (f) {
      float* o = (float*)io;
      o[off] = sane(o[off] + tile[nl * 65 + c]);
    } else {
      __hip_bfloat16* o = (__hip_bfloat16*)io;
      o[off] = f2bf(sane(bf2f(o[off]) + tile[nl * 65 + c]));
    }
  }
}

// ---------------- launch ----------------
extern "C" void kernel_launch(void* const* d_in, const int* in_sizes, int n_in,
                              void* d_out, int out_size, void* d_ws, size_t ws_size,
                              hipStream_t stream) {
  (void)in_sizes; (void)n_in; (void)out_size; (void)ws_size;
  const void* x        = d_in[0];
  const void* c1_w     = d_in[1];
  const void* in1_g    = d_in[2];
  const void* in1_b    = d_in[3];
  const void* c2_w     = d_in[4];
  const void* in2_g    = d_in[5];
  const void* in2_b    = d_in[6];
  const void* dw_w     = d_in[7];
  const void* pw_w     = d_in[8];
  const void* inr_g    = d_in[9];
  const void* inr_b    = d_in[10];
  const void* ln_g     = d_in[11];
  const void* ln_b     = d_in[12];
  const void* in_proj_w= d_in[13];
  const void* conv1d_w = d_in[14];
  const void* conv1d_b = d_in[15];
  const void* x_proj_w = d_in[16];
  const void* dt_proj_w= d_in[17];
  const void* dt_proj_b= d_in[18];
  const void* A_log    = d_in[19];
  const void* D_p      = d_in[20];
  const void* out_proj_w=d_in[21];
  const void* proj_w   = d_in[22];
  const void* proj_b   = d_in[23];
  const void* pn_g     = d_in[24];
  const void* pn_b     = d_in[25];

  char* wb = (char*)d_ws;
  // Byte layout, TOTAL ~= 87.4 MB (< 90.3 MB proven mapped in R7).
  // R0 [0, 33,554,432): P1(9.5M) -> P2(19.5M) -> zg(33.5M) -> s2(16.8M)
  __hip_bfloat16* P1   = (__hip_bfloat16*)wb;
  __hip_bfloat16* P2   = (__hip_bfloat16*)wb;
  __hip_bfloat16* zgb  = (__hip_bfloat16*)wb;
  __hip_bfloat16* s2   = (__hip_bfloat16*)wb;
  // R1 [33,554,432, 67,108,864): c1raw(17.3M) -> c2raw(17.8M) | pre2(16.8M) -> x_in(33.5M)
  // NOTE: x_in spans [33,554,432, 67,108,864) and is LIVE until k_outproj — nothing
  // may alias inside that range while the scan pipeline runs.
  __hip_bfloat16* c1raw = (__hip_bfloat16*)(wb + 33554432);
  __hip_bfloat16* c2raw = (__hip_bfloat16*)(wb + 33554432);
  __hip_bfloat16* pre2  = (__hip_bfloat16*)(wb + 33554432);
  __hip_bfloat16* x_in  = (__hip_bfloat16*)(wb + 33554432);
  // hcl [51,380,224, 68,157,440) — dead after k_x2ln (overlaps x_in tail; x_in written later)
  __hip_bfloat16* hcl   = (__hip_bfloat16*)(wb + 51380224);
  // seq [68,157,440, 84,934,656); BC (f32, 16,777,216 B exactly) aliases it after inproj
  __hip_bfloat16* seq   = (__hip_bfloat16*)(wb + 68157440);
  float*          BCf   = (float*)(wb + 68157440);
  // weights [84,934,656 ...)
  __hip_bfloat16* W1b   = (__hip_bfloat16*)(wb + 84934656);             // 73,728 B
  __hip_bfloat16* W2b   = (__hip_bfloat16*)(wb + 85008384);             // 147,456 B
  __hip_bfloat16* inwb  = (__hip_bfloat16*)(wb + 85155840);             // 32,768 B
  __hip_bfloat16* wcombb= (__hip_bfloat16*)(wb + 85188608);             // 16,384 B
  __hip_bfloat16* pwbb  = (__hip_bfloat16*)(wb + 85204992);             // 8,192 B
  __hip_bfloat16* xpwb  = (__hip_bfloat16*)(wb + 85213184);             // 9,216 B
  float*          fst   = (float*)(wb + 85222400);                      // 4,112 B
  // dtin f32 [85,229,568, 87,326,720) — free tail, outside every live buffer
  float*          dtinf = (float*)(wb + 85229568);

  float* acc_in1 = fst;
  float* acc_in2 = fst + 128;
  float* acc_inr = fst + 256;
  float* acc_pn  = fst + 384;
  float* ss_in1  = fst + 512;
  float* ss_in2  = fst + 640;
  float* ss_inr  = fst + 768;
  float* ss_pn   = fst + 896;
  int*   flagp   = (int*)(fst + 1024);

  hipMemsetAsync(fst, 0, 512 * sizeof(float), stream);

  k_detect<<<1, NTHREADS, 0, stream>>>(x, flagp);
  k_pad1<<<34 * 66, NTHREADS, 0, stream>>>(x, P1, flagp);
  k_prepw<<<144, NTHREADS, 0, stream>>>(c1_w, W1b, 32, flagp);
  k_prepw<<<288, NTHREADS, 0, stream>>>(c2_w, W2b, 64, flagp);
  k_prepcvt<<<64, NTHREADS, 0, stream>>>(in_proj_w, inwb, 16384, flagp);
  k_prepcvt<<<16, NTHREADS, 0, stream>>>(pw_w, pwbb, 4096, flagp);
  k_prepcvt<<<18, NTHREADS, 0, stream>>>(x_proj_w, xpwb, 4608, flagp);
  k_wcomb<<<32, NTHREADS, 0, stream>>>(proj_w, out_proj_w, wcombb, flagp);

  k_gemm_conv<32, 40><<<33 * 16, NTHREADS, 0, stream>>>(P1, W1b, c1raw, acc_in1);
  k_finalize<<<1, 64, 0, stream>>>(acc_in1, in1_g, in1_b, ss_in1, 1.0f / 135168.0f, flagp);
  k_normpad<<<35 * 66, NTHREADS, 0, stream>>>(c1raw, ss_in1, P2);

  k_gemm_conv<64, 88><<<34 * 16, NTHREADS, 0, stream>>>(P2, W2b, c2raw, acc_in2);
  k_finalize<<<1, 64, 0, stream>>>(acc_in2, in2_g, in2_b, ss_in2, 1.0f / 139264.0f, flagp);
  k_hslice_cl<<<2048, NTHREADS, 0, stream>>>(c2raw, ss_in2, hcl, d_out, flagp);

  k_dwpw_mfma<<<2048, NTHREADS, 0, stream>>>(hcl, dw_w, pwbb, pre2, acc_inr, flagp);
  k_finalize<<<1, 64, 0, stream>>>(acc_inr, inr_g, inr_b, ss_inr, 1.0f / 131072.0f, flagp);
  k_x2ln_cl<<<512, NTHREADS, 0, stream>>>(hcl, pre2, ss_inr, ln_g, ln_b, seq, flagp);

  k_inproj_mfma<<<2048, NTHREADS, 0, stream>>>(seq, inwb, x_in, zgb);
  k_conv1d_ip<<<2048, NTHREADS, 0, stream>>>(x_in, conv1d_w, conv1d_b, flagp);
  k_xproj_mfma<<<512, NTHREADS, 0, stream>>>(x_in, xpwb, dtinf, BCf);
  k_scan<<<2048, NTHREADS, 0, stream>>>(dtinf, BCf, x_in, zgb, dt_proj_w, dt_proj_b, A_log, D_p, flagp);
  k_outproj_mfma<<<512, NTHREADS, 0, stream>>>(x_in, wcombb, proj_b, s2, acc_pn, flagp);

  k_finalize<<<1, 64, 0, stream>>>(acc_pn, pn_g, pn_b, ss_pn, 1.0f / 131072.0f, flagp);
  k_final<<<2048, NTHREADS, 0, stream>>>(s2, d_out, ss_pn, flagp);
}

// Round 5
// 580.972 us; speedup vs baseline: 1.2016x; 1.0252x over previous
//
#include <hip/hip_runtime.h>
#include <hip/hip_bf16.h>

// Hybrid decoder block, MFMA everywhere GEMM-shaped, channels-last internals.
// row convention: r = z*4096 + n, n = y*64+x.
#define NTHREADS 256

typedef __attribute__((ext_vector_type(8))) short bs8_t;   // 8 bf16 (4 VGPRs)
typedef __attribute__((ext_vector_type(4))) float f4_t;    // 4 fp32 acc

__device__ __forceinline__ float bf2f(__hip_bfloat16 v) { return __bfloat162float(v); }
__device__ __forceinline__ __hip_bfloat16 f2bf(float v) { return __float2bfloat16(v); }
__device__ __forceinline__ float b2f_lo(unsigned int p) { return __uint_as_float(p << 16); }
__device__ __forceinline__ float b2f_hi(unsigned int p) { return __uint_as_float(p & 0xffff0000u); }
__device__ __forceinline__ float sigm(float x) { return 1.f / (1.f + __expf(-x)); }
__device__ __forceinline__ float leaky(float x) { return x > 0.f ? x : 0.01f * x; }
__device__ __forceinline__ float sane(float x) { return fminf(fmaxf(x, -1e9f), 1e9f); }
__device__ __forceinline__ unsigned packbf(float a, float b) {
  union { __hip_bfloat16 h[2]; unsigned u; } cv;
  cv.h[0] = f2bf(a); cv.h[1] = f2bf(b);
  return cv.u;
}
__device__ __forceinline__ float ldf(const void* p, long i, int f) {
  return f ? ((const float*)p)[i] : bf2f(((const __hip_bfloat16*)p)[i]);
}
// single-instruction 2^x (v_exp_f32); gfx9 trans ops are HW-interlocked.
__device__ __forceinline__ float exp2_fast(float x) {
  float r;
  asm("v_exp_f32 %0, %1" : "=v"(r) : "v"(x));
  return r;
}

// ---------------- dtype detector ----------------
__global__ void k_detect(const void* xp, int* flag) {
  __shared__ int cnt[NTHREADS];
  const __hip_bfloat16* h = (const __hip_bfloat16*)xp;
  int t = threadIdx.x;
  int c = 0;
  for (int j = 0; j < 8; j++) {
    float v = fabsf(bf2f(h[(t * 8 + j) * 2]));
    if (v > 1e-12f && v < 1e12f) c++;
  }
  cnt[t] = c;
  __syncthreads();
  for (int s = 128; s > 0; s >>= 1) {
    if (t < s) cnt[t] += cnt[t + s];
    __syncthreads();
  }
  if (t == 0) *flag = (cnt[0] > 1433) ? 0 : 1;
}

// generic converter: out[i] = bf16(in[i])
__global__ void k_prepcvt(const void* __restrict__ in, __hip_bfloat16* __restrict__ out,
                          int n, const int* __restrict__ flagp) {
  int f = *flagp;
  int gid = blockIdx.x * NTHREADS + threadIdx.x;
  if (gid < n) out[gid] = f2bf(ldf(in, gid, f));
}

// ---------------- pad1: x (ci-first) -> P1[z'(34)][y'(66)][x'(66)][32] bf16 ----------------
__global__ __launch_bounds__(NTHREADS) void k_pad1(const void* __restrict__ x,
                                                   __hip_bfloat16* __restrict__ P1,
                                                   const int* __restrict__ flagp) {
  __shared__ float tile[64 * 33];
  int f = *flagp;
  int zp = blockIdx.x / 66, yp = blockIdx.x % 66;
  long rowbase = ((long)zp * 66 + yp) * 66 * 32;
  int t = threadIdx.x;
  if (zp == 0 || zp == 33 || yp == 0 || yp == 65) {
    for (int i = t; i < 2112; i += NTHREADS) P1[rowbase + i] = f2bf(0.f);
    return;
  }
  int z = zp - 1, y = yp - 1;
#pragma unroll
  for (int j = 0; j < 8; j++) {
    int idx = t + j * NTHREADS;
    int ci = idx >> 6, xx = idx & 63;
    tile[xx * 33 + ci] = ldf(x, (long)(ci * 32 + z) * 4096 + y * 64 + xx, f);
  }
  __syncthreads();
#pragma unroll
  for (int j = 0; j < 8; j++) {
    int idx = t + j * NTHREADS;
    int xx = idx >> 5, ci = idx & 31;
    P1[rowbase + (xx + 1) * 32 + ci] = f2bf(tile[xx * 33 + ci]);
  }
  if (t < 32) P1[rowbase + t] = f2bf(0.f);
  else if (t < 64) P1[rowbase + 65 * 32 + (t - 32)] = f2bf(0.f);
}

// ---------------- weight reorg: cw (co,ci,2,3,3) -> W[s][co][ci] bf16 ----------------
__global__ void k_prepw(const void* __restrict__ cw, __hip_bfloat16* __restrict__ W,
                        int CI, const int* __restrict__ flagp) {
  int f = *flagp;
  int gid = blockIdx.x * NTHREADS + threadIdx.x;
  int s = gid / (64 * CI);
  int rem = gid % (64 * CI);
  int co = rem / CI, ci = rem % CI;
  W[gid] = f2bf(ldf(cw, (long)(co * CI + ci) * 18 + s, f));
}

// ---------------- MFMA implicit-GEMM conv + fused per-channel stats ----------------
template <int CI, int CIP>
__global__ __launch_bounds__(NTHREADS) void k_gemm_conv(const __hip_bfloat16* __restrict__ Pb,
                                                        const __hip_bfloat16* __restrict__ Wb,
                                                        __hip_bfloat16* __restrict__ out,
                                                        float* __restrict__ gacc) {
  __shared__ unsigned short Wl[3 * 64 * CIP];
  __shared__ float sred[256], qred[256];
  const unsigned short* P = (const unsigned short*)Pb;
  const unsigned short* W = (const unsigned short*)Wb;
  int t = threadIdx.x;
  int wv = t >> 6, lane = t & 63;
  int m = lane & 15, quad = lane >> 4;
  int zo = blockIdx.x >> 4;
  int y  = ((blockIdx.x & 15) << 2) + wv;
  f4_t zero4 = {0.f, 0.f, 0.f, 0.f};
  f4_t acc[4][4];
#pragma unroll
  for (int mt = 0; mt < 4; mt++)
#pragma unroll
    for (int nt = 0; nt < 4; nt++) acc[mt][nt] = zero4;

  for (int kz = 0; kz < 2; kz++) {
    for (int ky = 0; ky < 3; ky++) {
      __syncthreads();
      int s0 = (kz * 3 + ky) * 3;
      const unsigned short* wsrc = W + (long)s0 * 64 * CI;
      for (int i = t; i < 3 * 64 * CI; i += NTHREADS) {
        int kx = i / (64 * CI), rem = i % (64 * CI);
        int co = rem / CI, ci = rem % CI;
        Wl[(kx * 64 + co) * CIP + ci] = wsrc[i];
      }
      __syncthreads();
      int pz = zo + kz, py = y + ky;
      const unsigned short* prow = P + ((long)(pz * 66 + py) * 66) * CI;
#pragma unroll
      for (int kx = 0; kx < 3; kx++) {
#pragma unroll
        for (int ch = 0; ch < CI / 32; ch++) {
          int kof = kx * CI + ch * 32 + quad * 8;
          bs8_t a0 = *(const bs8_t*)(prow + (0 * 16 + m) * CI + kof);
          bs8_t a1 = *(const bs8_t*)(prow + (1 * 16 + m) * CI + kof);
          bs8_t a2 = *(const bs8_t*)(prow + (2 * 16 + m) * CI + kof);
          bs8_t a3 = *(const bs8_t*)(prow + (3 * 16 + m) * CI + kof);
#pragma unroll
          for (int nt = 0; nt < 4; nt++) {
            bs8_t b = *(const bs8_t*)&Wl[(kx * 64 + nt * 16 + m) * CIP + ch * 32 + quad * 8];
            acc[0][nt] = __builtin_amdgcn_mfma_f32_16x16x32_bf16(a0, b, acc[0][nt], 0, 0, 0);
            acc[1][nt] = __builtin_amdgcn_mfma_f32_16x16x32_bf16(a1, b, acc[1][nt], 0, 0, 0);
            acc[2][nt] = __builtin_amdgcn_mfma_f32_16x16x32_bf16(a2, b, acc[2][nt], 0, 0, 0);
            acc[3][nt] = __builtin_amdgcn_mfma_f32_16x16x32_bf16(a3, b, acc[3][nt], 0, 0, 0);
          }
        }
      }
    }
  }
  long obase = ((long)(zo * 64 + y) * 64) * 64;
  float psum[4], pq[4];
#pragma unroll
  for (int nt = 0; nt < 4; nt++) {
    int co = nt * 16 + m;
    float s = 0.f, q = 0.f;
#pragma unroll
    for (int mt = 0; mt < 4; mt++)
#pragma unroll
      for (int rg = 0; rg < 4; rg++) {
        float v = acc[mt][nt][rg];
        int xx = mt * 16 + quad * 4 + rg;
        out[obase + xx * 64 + co] = f2bf(v);
        s += v;
        q += v * v;
      }
    psum[nt] = s;
    pq[nt] = q;
  }
#pragma unroll
  for (int nt = 0; nt < 4; nt++) {
    psum[nt] += __shfl_xor(psum[nt], 16, 64);
    psum[nt] += __shfl_xor(psum[nt], 32, 64);
    pq[nt]   += __shfl_xor(pq[nt], 16, 64);
    pq[nt]   += __shfl_xor(pq[nt], 32, 64);
  }
  if (quad == 0) {
#pragma unroll
    for (int nt = 0; nt < 4; nt++) {
      sred[wv * 64 + nt * 16 + m] = psum[nt];
      qred[wv * 64 + nt * 16 + m] = pq[nt];
    }
  }
  __syncthreads();
  if (t < 64) {
    atomicAdd(&gacc[t], sred[t] + sred[64 + t] + sred[128 + t] + sred[192 + t]);
    atomicAdd(&gacc[64 + t], qred[t] + qred[64 + t] + qred[128 + t] + qred[192 + t]);
  }
}

__global__ void k_finalize(const float* __restrict__ acc, const void* __restrict__ g,
                           const void* __restrict__ b, float* __restrict__ ss, float invN,
                           const int* __restrict__ flagp) {
  int f = *flagp;
  int t = threadIdx.x;  // 64
  float mean = acc[t] * invN;
  float var  = acc[64 + t] * invN - mean * mean;
  float rstd = rsqrtf(fmaxf(var, 0.f) + 1e-5f);
  float sc   = ldf(g, t, f) * rstd;
  ss[t]      = sc;
  ss[64 + t] = ldf(b, t, f) - mean * sc;
}

// ---------------- normpad: c1raw -> norm+leaky -> P2[35][66][66][64] ----------------
__global__ __launch_bounds__(NTHREADS) void k_normpad(const __hip_bfloat16* __restrict__ in,
                                                      const float* __restrict__ ss,
                                                      __hip_bfloat16* __restrict__ P2) {
  int zp = blockIdx.x / 66, yp = blockIdx.x % 66;
  long rowbase = ((long)zp * 66 + yp) * 66 * 64;
  int t = threadIdx.x;
  if (zp == 0 || zp == 34 || yp == 0 || yp == 65) {
    for (int i = t; i < 4224; i += NTHREADS) P2[rowbase + i] = f2bf(0.f);
    return;
  }
  int z = zp - 1, y = yp - 1;
#pragma unroll
  for (int j = 0; j < 16; j++) {
    int idx = t + j * NTHREADS;
    int xx = idx >> 6, co = idx & 63;
    float v = bf2f(in[((long)(z * 64 + y) * 64 + xx) * 64 + co]) * ss[co] + ss[64 + co];
    P2[rowbase + (xx + 1) * 64 + co] = f2bf(leaky(v));
  }
  if (t < 64) P2[rowbase + t] = f2bf(0.f);
  else if (t < 128) P2[rowbase + 65 * 64 + (t - 64)] = f2bf(0.f);
}

// ---------------- hslice: c2raw -> norm+leaky -> hcl + residual d_out[c][r] ----------------
__global__ __launch_bounds__(NTHREADS) void k_hslice_cl(const __hip_bfloat16* __restrict__ in,
                                                        const float* __restrict__ ss,
                                                        __hip_bfloat16* __restrict__ hcl,
                                                        void* __restrict__ resid,
                                                        const int* __restrict__ flagp) {
  __shared__ float tile[64 * 65];
  int f = *flagp;
  int z = blockIdx.x >> 6, y = blockIdx.x & 63;
  long r0 = (long)z * 4096 + y * 64;
  int t = threadIdx.x;
#pragma unroll
  for (int j = 0; j < 16; j++) {
    int idx = t + j * NTHREADS;
    int xx = idx >> 6, co = idx & 63;
    float v = leaky(bf2f(in[(r0 + xx) * 64 + co]) * ss[co] + ss[64 + co]);
    hcl[(r0 + xx) * 64 + co] = f2bf(v);
    tile[xx * 65 + co] = v;
  }
  __syncthreads();
#pragma unroll
  for (int j = 0; j < 16; j++) {
    int idx = t + j * NTHREADS;
    int co = idx >> 6, xx = idx & 63;
    long off = (long)co * 131072 + r0 + xx;
    if (f) ((float*)resid)[off] = tile[xx * 65 + co];
    else   ((__hip_bfloat16*)resid)[off] = f2bf(tile[xx * 65 + co]);
  }
}

// ---------------- dw3x3 + pw1x1 (MFMA pointwise) + inr stats ----------------
__global__ __launch_bounds__(NTHREADS) void k_dwpw_mfma(const __hip_bfloat16* __restrict__ hcl,
                                                        const void* __restrict__ dwb,
                                                        const __hip_bfloat16* __restrict__ pwbb,
                                                        __hip_bfloat16* __restrict__ out,
                                                        float* __restrict__ acc,
                                                        const int* __restrict__ flagp) {
  __shared__ unsigned short hl[3 * 64 * 64];
  __shared__ unsigned short dwt[64 * 72];
  __shared__ unsigned short pwl[64 * 72];
  __shared__ float dwl[576];
  __shared__ float sred[256], qred[256];
  int f = *flagp;
  int t = threadIdx.x;
  int z = blockIdx.x >> 6, y = blockIdx.x & 63;
  for (int i = t; i < 576; i += NTHREADS) dwl[i] = ldf(dwb, i, f);
  {
    const unsigned short* ps = (const unsigned short*)pwbb;
    for (int i = t; i < 4096; i += NTHREADS) pwl[(i >> 6) * 72 + (i & 63)] = ps[i];
  }
  const unsigned short* hsrc = (const unsigned short*)hcl;
  for (int i = t; i < 12288; i += NTHREADS) {
    int dy = i / 4096, rem = i & 4095;
    int ry = y - 1 + dy;
    hl[i] = ((unsigned)ry < 64u) ? hsrc[((long)z * 4096 + ry * 64) * 64 + rem] : (unsigned short)0;
  }
  __syncthreads();
  const unsigned* hl32 = (const unsigned*)hl;
  unsigned* dwt32 = (unsigned*)dwt;
#pragma unroll
  for (int j = 0; j < 8; j++) {
    int idx = t + j * NTHREADS;
    int xx = idx >> 5, cp = idx & 31;
    float a0 = 0.f, a1 = 0.f;
#pragma unroll
    for (int dy = 0; dy < 3; dy++)
#pragma unroll
      for (int dx = 0; dx < 3; dx++) {
        int xv = xx - 1 + dx;
        if ((unsigned)xv < 64u) {
          unsigned hv = hl32[(dy * 64 + xv) * 32 + cp];
          a0 = fmaf(b2f_lo(hv), dwl[(cp * 2) * 9 + dy * 3 + dx], a0);
          a1 = fmaf(b2f_hi(hv), dwl[(cp * 2 + 1) * 9 + dy * 3 + dx], a1);
        }
      }
    dwt32[xx * 36 + cp] = packbf(a0, a1);
  }
  __syncthreads();
  int wv = t >> 6, lane = t & 63;
  int m = lane & 15, quad = lane >> 4;
  f4_t zero4 = {0.f, 0.f, 0.f, 0.f};
  f4_t acc4[4];
#pragma unroll
  for (int nt = 0; nt < 4; nt++) acc4[nt] = zero4;
#pragma unroll
  for (int ch = 0; ch < 2; ch++) {
    bs8_t a = *(const bs8_t*)&dwt[(wv * 16 + m) * 72 + ch * 32 + quad * 8];
#pragma unroll
    for (int nt = 0; nt < 4; nt++) {
      bs8_t b = *(const bs8_t*)&pwl[(nt * 16 + m) * 72 + ch * 32 + quad * 8];
      acc4[nt] = __builtin_amdgcn_mfma_f32_16x16x32_bf16(a, b, acc4[nt], 0, 0, 0);
    }
  }
  long obase = ((long)z * 4096 + y * 64) * 64;
  float psum[4], pq[4];
#pragma unroll
  for (int nt = 0; nt < 4; nt++) {
    float s = 0.f, q = 0.f;
#pragma unroll
    for (int rg = 0; rg < 4; rg++) {
      float v = acc4[nt][rg];
      int xx = wv * 16 + quad * 4 + rg;
      out[obase + xx * 64 + nt * 16 + m] = f2bf(v);
      s += v;
      q += v * v;
    }
    psum[nt] = s;
    pq[nt] = q;
  }
#pragma unroll
  for (int nt = 0; nt < 4; nt++) {
    psum[nt] += __shfl_xor(psum[nt], 16, 64);
    psum[nt] += __shfl_xor(psum[nt], 32, 64);
    pq[nt]   += __shfl_xor(pq[nt], 16, 64);
    pq[nt]   += __shfl_xor(pq[nt], 32, 64);
  }
  if (quad == 0) {
#pragma unroll
    for (int nt = 0; nt < 4; nt++) {
      sred[wv * 64 + nt * 16 + m] = psum[nt];
      qred[wv * 64 + nt * 16 + m] = pq[nt];
    }
  }
  __syncthreads();
  if (t < 64) {
    atomicAdd(&acc[t], sred[t] + sred[64 + t] + sred[128 + t] + sred[192 + t]);
    atomicAdd(&acc[64 + t], qred[t] + qred[64 + t] + qred[128 + t] + qred[192 + t]);
  }
}

// ---------------- x2 = h + silu(norm(pre2)); LayerNorm C=64 -> seq bf16 ----------------
__global__ __launch_bounds__(NTHREADS) void k_x2ln_cl(const __hip_bfloat16* __restrict__ hcl,
                                                      const __hip_bfloat16* __restrict__ p2,
                                                      const float* __restrict__ ssr,
                                                      const void* __restrict__ lng,
                                                      const void* __restrict__ lnb,
                                                      __hip_bfloat16* __restrict__ out,
                                                      const int* __restrict__ flagp) {
  __shared__ float sc[64], sh[64], sg[64], sb[64];
  int f = *flagp;
  int t = threadIdx.x;
  if (t < 64) {
    sc[t] = ssr[t];
    sh[t] = ssr[64 + t];
    sg[t] = ldf(lng, t, f);
    sb[t] = ldf(lnb, t, f);
  }
  __syncthreads();
  long r = (long)blockIdx.x * NTHREADS + t;
  const uint4* hp = (const uint4*)(hcl + r * 64);
  const uint4* pp = (const uint4*)(p2 + r * 64);
  float v[64];
  float s1 = 0.f;
#pragma unroll
  for (int q = 0; q < 8; q++) {
    uint4 hu = hp[q], pu = pp[q];
    float hv[8] = {b2f_lo(hu.x), b2f_hi(hu.x), b2f_lo(hu.y), b2f_hi(hu.y),
                   b2f_lo(hu.z), b2f_hi(hu.z), b2f_lo(hu.w), b2f_hi(hu.w)};
    float pv[8] = {b2f_lo(pu.x), b2f_hi(pu.x), b2f_lo(pu.y), b2f_hi(pu.y),
                   b2f_lo(pu.z), b2f_hi(pu.z), b2f_lo(pu.w), b2f_hi(pu.w)};
#pragma unroll
    for (int i = 0; i < 8; i++) {
      int c = q * 8 + i;
      float pn = sc[c] * pv[i] + sh[c];
      float x2 = hv[i] + pn * sigm(pn);
      v[c] = x2;
      s1 += x2;
    }
  }
  float m = s1 * (1.f / 64.f);
  float s2 = 0.f;
#pragma unroll
  for (int c = 0; c < 64; c++) {
    float d = v[c] - m;
    s2 += d * d;
  }
  float rstd = rsqrtf(s2 * (1.f / 64.f) + 1e-5f);
  uint4* o4 = (uint4*)(out + r * 64);
#pragma unroll
  for (int q = 0; q < 8; q++) {
    int c = q * 8;
    uint4 o;
    o.x = packbf((v[c + 0] - m) * rstd * sg[c + 0] + sb[c + 0],
                 (v[c + 1] - m) * rstd * sg[c + 1] + sb[c + 1]);
    o.y = packbf((v[c + 2] - m) * rstd * sg[c + 2] + sb[c + 2],
                 (v[c + 3] - m) * rstd * sg[c + 3] + sb[c + 3]);
    o.z = packbf((v[c + 4] - m) * rstd * sg[c + 4] + sb[c + 4],
                 (v[c + 5] - m) * rstd * sg[c + 5] + sb[c + 5]);
    o.w = packbf((v[c + 6] - m) * rstd * sg[c + 6] + sb[c + 6],
                 (v[c + 7] - m) * rstd * sg[c + 7] + sb[c + 7]);
    o4[q] = o;
  }
}

// ---------------- in_proj MFMA ----------------
__global__ __launch_bounds__(NTHREADS) void k_inproj_mfma(const __hip_bfloat16* __restrict__ seq,
                                                          const __hip_bfloat16* __restrict__ Wbf,
                                                          __hip_bfloat16* __restrict__ x_in,
                                                          __hip_bfloat16* __restrict__ zg) {
  __shared__ unsigned short Wl[256 * 72];
  const unsigned short* ws = (const unsigned short*)Wbf;
  int t = threadIdx.x;
  for (int i = t; i < 16384; i += NTHREADS) Wl[(i >> 6) * 72 + (i & 63)] = ws[i];
  __syncthreads();
  int wv = t >> 6, lane = t & 63;
  int m = lane & 15, quad = lane >> 4;
  long m0 = (long)blockIdx.x * 64;
  int n0 = wv * 64;
  f4_t zero4 = {0.f, 0.f, 0.f, 0.f};
  f4_t acc[4][4];
#pragma unroll
  for (int mt = 0; mt < 4; mt++)
#pragma unroll
    for (int nt = 0; nt < 4; nt++) acc[mt][nt] = zero4;
  const unsigned short* sp = (const unsigned short*)seq;
#pragma unroll
  for (int ch = 0; ch < 2; ch++) {
    int kof = ch * 32 + quad * 8;
    bs8_t a0 = *(const bs8_t*)(sp + (m0 + 0 * 16 + m) * 64 + kof);
    bs8_t a1 = *(const bs8_t*)(sp + (m0 + 1 * 16 + m) * 64 + kof);
    bs8_t a2 = *(const bs8_t*)(sp + (m0 + 2 * 16 + m) * 64 + kof);
    bs8_t a3 = *(const bs8_t*)(sp + (m0 + 3 * 16 + m) * 64 + kof);
#pragma unroll
    for (int nt = 0; nt < 4; nt++) {
      bs8_t b = *(const bs8_t*)&Wl[(n0 + nt * 16 + m) * 72 + kof];
      acc[0][nt] = __builtin_amdgcn_mfma_f32_16x16x32_bf16(a0, b, acc[0][nt], 0, 0, 0);
      acc[1][nt] = __builtin_amdgcn_mfma_f32_16x16x32_bf16(a1, b, acc[1][nt], 0, 0, 0);
      acc[2][nt] = __builtin_amdgcn_mfma_f32_16x16x32_bf16(a2, b, acc[2][nt], 0, 0, 0);
      acc[3][nt] = __builtin_amdgcn_mfma_f32_16x16x32_bf16(a3, b, acc[3][nt], 0, 0, 0);
    }
  }
  __hip_bfloat16* obuf = (n0 < 128) ? x_in : zg;
  int cbase = (n0 < 128) ? n0 : (n0 - 128);
#pragma unroll
  for (int mt = 0; mt < 4; mt++)
#pragma unroll
    for (int nt = 0; nt < 4; nt++) {
      int col = cbase + nt * 16 + m;
#pragma unroll
      for (int rg = 0; rg < 4; rg++) {
        long row = m0 + mt * 16 + quad * 4 + rg;
        obuf[row * 128 + col] = f2bf(acc[mt][nt][rg]);
      }
    }
}

// ---------------- causal depthwise conv1d, in place ----------------
// All 32 z-values preloaded into registers (independent loads, one latency),
// compute fully in-registers, then 32 stores. Removes the serial
// load->compute->store->load z-chain that was latency-bound.
__global__ __launch_bounds__(NTHREADS) void k_conv1d_ip(__hip_bfloat16* xio,
                                                        const void* __restrict__ wb,
                                                        const void* __restrict__ bb,
                                                        const int* __restrict__ flagp) {
  int f = *flagp;
  int gid = blockIdx.x * NTHREADS + threadIdx.x;
  int d = gid & 127, nl = gid >> 7;
  float w0 = ldf(wb, d * 4 + 0, f), w1 = ldf(wb, d * 4 + 1, f);
  float w2 = ldf(wb, d * 4 + 2, f), w3 = ldf(wb, d * 4 + 3, f);
  float bias = ldf(bb, d, f);
  const size_t stride = 4096u * 128u;
  size_t off0 = (size_t)nl * 128 + d;
  float xv[32];
#pragma unroll
  for (int z = 0; z < 32; z++) xv[z] = bf2f(xio[off0 + (size_t)z * stride]);
  float h0 = 0.f, h1 = 0.f, h2 = 0.f;
#pragma unroll
  for (int z = 0; z < 32; z++) {
    float cur = xv[z];
    float a = bias;
    a = fmaf(h0, w0, a);
    a = fmaf(h1, w1, a);
    a = fmaf(h2, w2, a);
    a = fmaf(cur, w3, a);
    xv[z] = a * sigm(a);
    h0 = h1; h1 = h2; h2 = cur;
  }
#pragma unroll
  for (int z = 0; z < 32; z++) xio[off0 + (size_t)z * stride] = f2bf(xv[z]);
}

// ---------------- x_proj MFMA: (131072,128) x (36->48 pad,128)^T ----------------
// outputs: dtin[r][4] f32 (cols 0..3) and BC[r][32] f32 (cols 4..35)
__global__ __launch_bounds__(NTHREADS) void k_xproj_mfma(const __hip_bfloat16* __restrict__ A,
                                                         const __hip_bfloat16* __restrict__ Wbf,
                                                         float* __restrict__ dtin,
                                                         float* __restrict__ BC) {
  __shared__ unsigned short Wl[48 * 136];
  const unsigned short* ws = (const unsigned short*)Wbf;   // (36,128) row-major
  int t = threadIdx.x;
  for (int i = t; i < 48 * 128; i += NTHREADS) {
    int j = i >> 7, k = i & 127;
    Wl[j * 136 + k] = (j < 36) ? ws[j * 128 + k] : (unsigned short)0;
  }
  __syncthreads();
  int wv = t >> 6, lane = t & 63;
  int m = lane & 15, quad = lane >> 4;
  long m0 = (long)blockIdx.x * 256 + wv * 64;
  f4_t zero4 = {0.f, 0.f, 0.f, 0.f};
  f4_t acc[4][3];
#pragma unroll
  for (int mt = 0; mt < 4; mt++)
#pragma unroll
    for (int nt = 0; nt < 3; nt++) acc[mt][nt] = zero4;
  const unsigned short* ap = (const unsigned short*)A;
#pragma unroll
  for (int ch = 0; ch < 4; ch++) {
    int kof = ch * 32 + quad * 8;
    bs8_t a0 = *(const bs8_t*)(ap + (m0 + 0 * 16 + m) * 128 + kof);
    bs8_t a1 = *(const bs8_t*)(ap + (m0 + 1 * 16 + m) * 128 + kof);
    bs8_t a2 = *(const bs8_t*)(ap + (m0 + 2 * 16 + m) * 128 + kof);
    bs8_t a3 = *(const bs8_t*)(ap + (m0 + 3 * 16 + m) * 128 + kof);
#pragma unroll
    for (int nt = 0; nt < 3; nt++) {
      bs8_t b = *(const bs8_t*)&Wl[(nt * 16 + m) * 136 + kof];
      acc[0][nt] = __builtin_amdgcn_mfma_f32_16x16x32_bf16(a0, b, acc[0][nt], 0, 0, 0);
      acc[1][nt] = __builtin_amdgcn_mfma_f32_16x16x32_bf16(a1, b, acc[1][nt], 0, 0, 0);
      acc[2][nt] = __builtin_amdgcn_mfma_f32_16x16x32_bf16(a2, b, acc[2][nt], 0, 0, 0);
      acc[3][nt] = __builtin_amdgcn_mfma_f32_16x16x32_bf16(a3, b, acc[3][nt], 0, 0, 0);
    }
  }
#pragma unroll
  for (int mt = 0; mt < 4; mt++)
#pragma unroll
    for (int nt = 0; nt < 3; nt++) {
      int col = nt * 16 + m;
#pragma unroll
      for (int rg = 0; rg < 4; rg++) {
        long row = m0 + mt * 16 + quad * 4 + rg;
        float v = acc[mt][nt][rg];
        if (col < 4) dtin[row * 4 + col] = v;
        else if (col < 36) BC[row * 32 + (col - 4)] = v;
      }
    }
}

// ---------------- selective scan ----------------
// geo fast path: 1-deep software pipeline (prefetch z+1 into named regs before
// computing z), even/odd power chains (dep depth 15->8), 4-chain y reduction.
// General fallback path kept for arbitrary A.
__global__ __launch_bounds__(NTHREADS) void k_scan(const float* __restrict__ dtin,
                                                   const float* __restrict__ BC,
                                                   __hip_bfloat16* __restrict__ uy,
                                                   const __hip_bfloat16* __restrict__ zg,
                                                   const void* __restrict__ dtw,
                                                   const void* __restrict__ dtb,
                                                   const void* __restrict__ Alog,
                                                   const void* __restrict__ Dp,
                                                   const int* __restrict__ flagp) {
  int f = *flagp;
  int gid = blockIdx.x * NTHREADS + threadIdx.x;
  int d = gid & 127, n = gid >> 7;
  // A2[s] = -exp(A_log[d][s]) * log2(e): exp(dt*A) == exp2(dt*A2)
  float A2[16];
#pragma unroll
  for (int s = 0; s < 16; s++)
    A2[s] = -__expf(fminf(ldf(Alog, d * 16 + s, f), 60.f)) * 1.44269504088896f;
  float W0 = ldf(dtw, d * 4 + 0, f), W1 = ldf(dtw, d * 4 + 1, f);
  float W2 = ldf(dtw, d * 4 + 2, f), W3 = ldf(dtw, d * 4 + 3, f);
  float bias = ldf(dtb, d, f);
  float Dv = ldf(Dp, d, f);
  float a0 = A2[0];
  int geo = 1;
#pragma unroll
  for (int s = 1; s < 16; s++)
    geo &= (fabsf(A2[s] - (float)(s + 1) * a0) <= 1e-4f * fabsf(A2[s])) ? 1 : 0;
  geo = __all(geo);
  float st[16];
#pragma unroll
  for (int s = 0; s < 16; s++) st[s] = 0.f;
  if (geo) {
    const float4* bp0 = (const float4*)(BC + (size_t)n * 32);   // +z*32768 float4
    const float4* dp0 = (const float4*)(dtin + (size_t)n * 4);  // +z*4096  float4
    const __hip_bfloat16* up0 = uy + (size_t)n * 128 + d;       // +z*524288
    const __hip_bfloat16* zp0 = zg + (size_t)n * 128 + d;
    __hip_bfloat16* uq = uy + (size_t)n * 128 + d;
    const size_t ustep = 4096u * 128u;
    // prologue: loads for z=0
    float4 b0 = bp0[0], b1 = bp0[1], b2 = bp0[2], b3 = bp0[3];
    float4 c0 = bp0[4], c1 = bp0[5], c2 = bp0[6], c3 = bp0[7];
    float4 dt4 = dp0[0];
    float u  = sane(bf2f(*up0));
    float zv = sane(bf2f(*zp0));
#pragma unroll 2
    for (int z = 0; z < 32; z++) {
      // prefetch z+1 (z=31 re-reads z=31; values unused)
      int zn = (z < 31) ? z + 1 : 31;
      const float4* bpn = bp0 + (size_t)zn * 32768u;
      float4 nb0 = bpn[0], nb1 = bpn[1], nb2 = bpn[2], nb3 = bpn[3];
      float4 nc0 = bpn[4], nc1 = bpn[5], nc2 = bpn[6], nc3 = bpn[7];
      float4 ndt = dp0[(size_t)zn * 4096u];
      float nu  = sane(bf2f(up0[(size_t)zn * ustep]));
      float nzv = sane(bf2f(zp0[(size_t)zn * ustep]));
      // compute current z
      float v = bias;
      v = fmaf(dt4.x, W0, v);
      v = fmaf(dt4.y, W1, v);
      v = fmaf(dt4.z, W2, v);
      v = fmaf(dt4.w, W3, v);
      float dtv = v > 20.f ? v : __logf(1.f + __expf(v));
      dtv = fminf(fmaxf(dtv, 0.f), 60.f);
      float du = dtv * u;
      float e1 = exp2_fast(dtv * a0);
      float e2 = e1 * e1;
      float es[16];
      es[0] = e1; es[1] = e2;
#pragma unroll
      for (int s = 2; s < 16; s++) es[s] = es[s - 2] * e2;
      float B[16] = {b0.x, b0.y, b0.z, b0.w, b1.x, b1.y, b1.z, b1.w,
                     b2.x, b2.y, b2.z, b2.w, b3.x, b3.y, b3.z, b3.w};
      float C[16] = {c0.x, c0.y, c0.z, c0.w, c1.x, c1.y, c1.z, c1.w,
                     c2.x, c2.y, c2.z, c2.w, c3.x, c3.y, c3.z, c3.w};
#pragma unroll
      for (int s = 0; s < 16; s++) st[s] = fmaf(es[s], st[s], du * B[s]);
      float y0 = 0.f, y1 = 0.f, y2 = 0.f, y3 = 0.f;
#pragma unroll
      for (int s = 0; s < 16; s += 4) {
        y0 = fmaf(st[s + 0], C[s + 0], y0);
        y1 = fmaf(st[s + 1], C[s + 1], y1);
        y2 = fmaf(st[s + 2], C[s + 2], y2);
        y3 = fmaf(st[s + 3], C[s + 3], y3);
      }
      float y = (y0 + y1) + (y2 + y3);
      y = sane((y + Dv * u) * (zv * sigm(zv)));
      uq[(size_t)z * ustep] = f2bf(y);
      // rotate pipeline registers
      b0 = nb0; b1 = nb1; b2 = nb2; b3 = nb3;
      c0 = nc0; c1 = nc1; c2 = nc2; c3 = nc3;
      dt4 = ndt; u = nu; zv = nzv;
    }
  } else {
#pragma unroll
    for (int s = 0; s < 16; s++) asm("" : "+v"(A2[s]));  // pin; forbid remat/AGPR
    for (int z = 0; z < 32; z++) {
      size_t r = (size_t)z * 4096 + n;
      const float4* bp = (const float4*)(BC + r * 32);
      float4 dt4 = *(const float4*)(dtin + r * 4);
      float4 b0 = bp[0], b1 = bp[1], b2 = bp[2], b3 = bp[3];
      float4 c0 = bp[4], c1 = bp[5], c2 = bp[6], c3 = bp[7];
      float u = sane(bf2f(uy[r * 128 + d]));
      float zv = sane(bf2f(zg[r * 128 + d]));
      float v = bias;
      v = fmaf(dt4.x, W0, v);
      v = fmaf(dt4.y, W1, v);
      v = fmaf(dt4.z, W2, v);
      v = fmaf(dt4.w, W3, v);
      float dtv = v > 20.f ? v : __logf(1.f + __expf(v));
      dtv = fminf(fmaxf(dtv, 0.f), 60.f);
      float du = dtv * u;
      float B[16] = {b0.x, b0.y, b0.z, b0.w, b1.x, b1.y, b1.z, b1.w,
                     b2.x, b2.y, b2.z, b2.w, b3.x, b3.y, b3.z, b3.w};
      float C[16] = {c0.x, c0.y, c0.z, c0.w, c1.x, c1.y, c1.z, c1.w,
                     c2.x, c2.y, c2.z, c2.w, c3.x, c3.y, c3.z, c3.w};
      float y = 0.f;
#pragma unroll
      for (int s = 0; s < 16; s++) {
        float e = exp2_fast(dtv * A2[s]);
        st[s] = fmaf(e, st[s], du * B[s]);
        y = fmaf(st[s], C[s], y);
      }
      y = sane((y + Dv * u) * (zv * sigm(zv)));
      uy[r * 128 + d] = f2bf(y);
    }
  }
}

// ---------------- W_comb = proj_w @ out_proj_w -> bf16 [o][d] ----------------
__global__ void k_wcomb(const void* __restrict__ pw, const void* __restrict__ opw,
                        __hip_bfloat16* __restrict__ wc, const int* __restrict__ flagp) {
  int f = *flagp;
  int gid = blockIdx.x * NTHREADS + threadIdx.x;
  int d = gid & 127, o = gid >> 7;
  float a = 0.f;
#pragma unroll
  for (int j = 0; j < 64; j++) a = fmaf(ldf(pw, o * 64 + j, f), ldf(opw, j * 128 + d, f), a);
  wc[(size_t)o * 128 + d] = f2bf(a);
}

// ---------------- out_proj+proj MFMA + fused pn stats ----------------
__global__ __launch_bounds__(NTHREADS) void k_outproj_mfma(const __hip_bfloat16* __restrict__ A,
                                                           const __hip_bfloat16* __restrict__ Wcb,
                                                           const void* __restrict__ bias,
                                                           __hip_bfloat16* __restrict__ out,
                                                           float* __restrict__ gacc,
                                                           const int* __restrict__ flagp) {
  __shared__ unsigned short Wl[64 * 136];
  __shared__ float bl[64];
  __shared__ float sred[256], qred[256];
  int f = *flagp;
  int t = threadIdx.x;
  const unsigned short* ws = (const unsigned short*)Wcb;
  for (int i = t; i < 8192; i += NTHREADS) Wl[(i >> 7) * 136 + (i & 127)] = ws[i];
  if (t < 64) bl[t] = ldf(bias, t, f);
  __syncthreads();
  int wv = t >> 6, lane = t & 63;
  int m = lane & 15, quad = lane >> 4;
  long m0 = (long)blockIdx.x * 256 + wv * 64;
  f4_t zero4 = {0.f, 0.f, 0.f, 0.f};
  f4_t acc[4][4];
#pragma unroll
  for (int mt = 0; mt < 4; mt++)
#pragma unroll
    for (int nt = 0; nt < 4; nt++) acc[mt][nt] = zero4;
  const unsigned short* ap = (const unsigned short*)A;
#pragma unroll
  for (int ch = 0; ch < 4; ch++) {
    int kof = ch * 32 + quad * 8;
    bs8_t a0 = *(const bs8_t*)(ap + (m0 + 0 * 16 + m) * 128 + kof);
    bs8_t a1 = *(const bs8_t*)(ap + (m0 + 1 * 16 + m) * 128 + kof);
    bs8_t a2 = *(const bs8_t*)(ap + (m0 + 2 * 16 + m) * 128 + kof);
    bs8_t a3 = *(const bs8_t*)(ap + (m0 + 3 * 16 + m) * 128 + kof);
#pragma unroll
    for (int nt = 0; nt < 4; nt++) {
      bs8_t b = *(const bs8_t*)&Wl[(nt * 16 + m) * 136 + kof];
      acc[0][nt] = __builtin_amdgcn_mfma_f32_16x16x32_bf16(a0, b, acc[0][nt], 0, 0, 0);
      acc[1][nt] = __builtin_amdgcn_mfma_f32_16x16x32_bf16(a1, b, acc[1][nt], 0, 0, 0);
      acc[2][nt] = __builtin_amdgcn_mfma_f32_16x16x32_bf16(a2, b, acc[2][nt], 0, 0, 0);
      acc[3][nt] = __builtin_amdgcn_mfma_f32_16x16x32_bf16(a3, b, acc[3][nt], 0, 0, 0);
    }
  }
  float psum[4], pq[4];
#pragma unroll
  for (int nt = 0; nt < 4; nt++) {
    int co = nt * 16 + m;
    float s = 0.f, q = 0.f;
#pragma unroll
    for (int mt = 0; mt < 4; mt++)
#pragma unroll
      for (int rg = 0; rg < 4; rg++) {
        float v = sane(acc[mt][nt][rg] + bl[co]);
        long row = m0 + mt * 16 + quad * 4 + rg;
        out[row * 64 + co] = f2bf(v);
        s += v;
        q += v * v;
      }
    psum[nt] = s;
    pq[nt] = q;
  }
#pragma unroll
  for (int nt = 0; nt < 4; nt++) {
    psum[nt] += __shfl_xor(psum[nt], 16, 64);
    psum[nt] += __shfl_xor(psum[nt], 32, 64);
    pq[nt]   += __shfl_xor(pq[nt], 16, 64);
    pq[nt]   += __shfl_xor(pq[nt], 32, 64);
  }
  if (quad == 0) {
#pragma unroll
    for (int nt = 0; nt < 4; nt++) {
      sred[wv * 64 + nt * 16 + m] = psum[nt];
      qred[wv * 64 + nt * 16 + m] = pq[nt];
    }
  }
  __syncthreads();
  if (t < 64) {
    atomicAdd(&gacc[t], sred[t] + sred[64 + t] + sred[128 + t] + sred[192 + t]);
    atomicAdd(&gacc[64 + t], qred[t] + qred[64 + t] + qred[128 + t] + qred[192 + t]);
  }
}

// ---------------- final ----------------
__global__ __launch_bounds__(NTHREADS) void k_final(const __hip_bfloat16* __restrict__ s2,
                                                    void* __restrict__ io,
                                                    const float* __restrict__ ss,
                                                    const int* __restrict__ flagp) {
  __shared__ float tile[64 * 65];
  __shared__ float sc[64], sh[64];
  int f = *flagp;
  int t = threadIdx.x;
  if (t < 64) {
    sc[t] = ss[t];
    sh[t] = ss[64 + t];
  }
  int z = blockIdx.x >> 6, n0 = (blockIdx.x & 63) << 6;
  size_t base = ((size_t)z * 4096 + n0) * 64;
  __syncthreads();
#pragma unroll
  for (int jj = 0; jj < 16; jj++) {
    int id = t + jj * NTHREADS;
    int i = id >> 6, c = id & 63;
    float v = sane(bf2f(s2[base + id]));
    tile[i * 65 + c] = sc[c] * v + sh[c];
  }
  __syncthreads();
#pragma unroll
  for (int jj = 0; jj < 16; jj++) {
    int id = t + jj * NTHREADS;
    int c = id >> 6, nl = id & 63;
    size_t off = (size_t)c * 131072 + (size_t)z * 4096 + n0 + nl;
    if (f) {
      float* o = (float*)io;
      o[off] = sane(o[off] + tile[nl * 65 + c]);
    } else {
      __hip_bfloat16* o = (__hip_bfloat16*)io;
      o[off] = f2bf(sane(bf2f(o[off]) + tile[nl * 65 + c]));
    }
  }
}

// ---------------- launch ----------------
extern "C" void kernel_launch(void* const* d_in, const int* in_sizes, int n_in,
                              void* d_out, int out_size, void* d_ws, size_t ws_size,
                              hipStream_t stream) {
  (void)in_sizes; (void)n_in; (void)out_size; (void)ws_size;
  const void* x        = d_in[0];
  const void* c1_w     = d_in[1];
  const void* in1_g    = d_in[2];
  const void* in1_b    = d_in[3];
  const void* c2_w     = d_in[4];
  const void* in2_g    = d_in[5];
  const void* in2_b    = d_in[6];
  const void* dw_w     = d_in[7];
  const void* pw_w     = d_in[8];
  const void* inr_g    = d_in[9];
  const void* inr_b    = d_in[10];
  const void* ln_g     = d_in[11];
  const void* ln_b     = d_in[12];
  const void* in_proj_w= d_in[13];
  const void* conv1d_w = d_in[14];
  const void* conv1d_b = d_in[15];
  const void* x_proj_w = d_in[16];
  const void* dt_proj_w= d_in[17];
  const void* dt_proj_b= d_in[18];
  const void* A_log    = d_in[19];
  const void* D_p      = d_in[20];
  const void* out_proj_w=d_in[21];
  const void* proj_w   = d_in[22];
  const void* proj_b   = d_in[23];
  const void* pn_g     = d_in[24];
  const void* pn_b     = d_in[25];

  char* wb = (char*)d_ws;
  // Byte layout, TOTAL ~= 87.4 MB (< 90.3 MB proven mapped in R7).
  // R0 [0, 33,554,432): P1(9.5M) -> P2(19.5M) -> zg(33.5M) -> s2(16.8M)
  __hip_bfloat16* P1   = (__hip_bfloat16*)wb;
  __hip_bfloat16* P2   = (__hip_bfloat16*)wb;
  __hip_bfloat16* zgb  = (__hip_bfloat16*)wb;
  __hip_bfloat16* s2   = (__hip_bfloat16*)wb;
  // R1 [33,554,432, 67,108,864): c1raw(17.3M) -> c2raw(17.8M) | pre2(16.8M) -> x_in(33.5M)
  // NOTE: x_in spans [33,554,432, 67,108,864) and is LIVE until k_outproj — nothing
  // may alias inside that range while the scan pipeline runs.
  __hip_bfloat16* c1raw = (__hip_bfloat16*)(wb + 33554432);
  __hip_bfloat16* c2raw = (__hip_bfloat16*)(wb + 33554432);
  __hip_bfloat16* pre2  = (__hip_bfloat16*)(wb + 33554432);
  __hip_bfloat16* x_in  = (__hip_bfloat16*)(wb + 33554432);
  // hcl [51,380,224, 68,157,440) — dead after k_x2ln (overlaps x_in tail; x_in written later)
  __hip_bfloat16* hcl   = (__hip_bfloat16*)(wb + 51380224);
  // seq [68,157,440, 84,934,656); BC (f32, 16,777,216 B exactly) aliases it after inproj
  __hip_bfloat16* seq   = (__hip_bfloat16*)(wb + 68157440);
  float*          BCf   = (float*)(wb + 68157440);
  // weights [84,934,656 ...)
  __hip_bfloat16* W1b   = (__hip_bfloat16*)(wb + 84934656);             // 73,728 B
  __hip_bfloat16* W2b   = (__hip_bfloat16*)(wb + 85008384);             // 147,456 B
  __hip_bfloat16* inwb  = (__hip_bfloat16*)(wb + 85155840);             // 32,768 B
  __hip_bfloat16* wcombb= (__hip_bfloat16*)(wb + 85188608);             // 16,384 B
  __hip_bfloat16* pwbb  = (__hip_bfloat16*)(wb + 85204992);             // 8,192 B
  __hip_bfloat16* xpwb  = (__hip_bfloat16*)(wb + 85213184);             // 9,216 B
  float*          fst   = (float*)(wb + 85222400);                      // 4,112 B
  // dtin f32 [85,229,568, 87,326,720) — free tail, outside every live buffer
  float*          dtinf = (float*)(wb + 85229568);

  float* acc_in1 = fst;
  float* acc_in2 = fst + 128;
  float* acc_inr = fst + 256;
  float* acc_pn  = fst + 384;
  float* ss_in1  = fst + 512;
  float* ss_in2  = fst + 640;
  float* ss_inr  = fst + 768;
  float* ss_pn   = fst + 896;
  int*   flagp   = (int*)(fst + 1024);

  hipMemsetAsync(fst, 0, 512 * sizeof(float), stream);

  k_detect<<<1, NTHREADS, 0, stream>>>(x, flagp);
  k_pad1<<<34 * 66, NTHREADS, 0, stream>>>(x, P1, flagp);
  k_prepw<<<144, NTHREADS, 0, stream>>>(c1_w, W1b, 32, flagp);
  k_prepw<<<288, NTHREADS, 0, stream>>>(c2_w, W2b, 64, flagp);
  k_prepcvt<<<64, NTHREADS, 0, stream>>>(in_proj_w, inwb, 16384, flagp);
  k_prepcvt<<<16, NTHREADS, 0, stream>>>(pw_w, pwbb, 4096, flagp);
  k_prepcvt<<<18, NTHREADS, 0, stream>>>(x_proj_w, xpwb, 4608, flagp);
  k_wcomb<<<32, NTHREADS, 0, stream>>>(proj_w, out_proj_w, wcombb, flagp);

  k_gemm_conv<32, 40><<<33 * 16, NTHREADS, 0, stream>>>(P1, W1b, c1raw, acc_in1);
  k_finalize<<<1, 64, 0, stream>>>(acc_in1, in1_g, in1_b, ss_in1, 1.0f / 135168.0f, flagp);
  k_normpad<<<35 * 66, NTHREADS, 0, stream>>>(c1raw, ss_in1, P2);

  k_gemm_conv<64, 88><<<34 * 16, NTHREADS, 0, stream>>>(P2, W2b, c2raw, acc_in2);
  k_finalize<<<1, 64, 0, stream>>>(acc_in2, in2_g, in2_b, ss_in2, 1.0f / 139264.0f, flagp);
  k_hslice_cl<<<2048, NTHREADS, 0, stream>>>(c2raw, ss_in2, hcl, d_out, flagp);

  k_dwpw_mfma<<<2048, NTHREADS, 0, stream>>>(hcl, dw_w, pwbb, pre2, acc_inr, flagp);
  k_finalize<<<1, 64, 0, stream>>>(acc_inr, inr_g, inr_b, ss_inr, 1.0f / 131072.0f, flagp);
  k_x2ln_cl<<<512, NTHREADS, 0, stream>>>(hcl, pre2, ss_inr, ln_g, ln_b, seq, flagp);

  k_inproj_mfma<<<2048, NTHREADS, 0, stream>>>(seq, inwb, x_in, zgb);
  k_conv1d_ip<<<2048, NTHREADS, 0, stream>>>(x_in, conv1d_w, conv1d_b, flagp);
  k_xproj_mfma<<<512, NTHREADS, 0, stream>>>(x_in, xpwb, dtinf, BCf);
  k_scan<<<2048, NTHREADS, 0, stream>>>(dtinf, BCf, x_in, zgb, dt_proj_w, dt_proj_b, A_log, D_p, flagp);
  k_outproj_mfma<<<512, NTHREADS, 0, stream>>>(x_in, wcombb, proj_b, s2, acc_pn, flagp);

  k_finalize<<<1, 64, 0, stream>>>(acc_pn, pn_g, pn_b, ss_pn, 1.0f / 131072.0f, flagp);
  k_final<<<2048, NTHREADS, 0, stream>>>(s2, d_out, ss_pn, flagp);
}

// Round 6
// 555.195 us; speedup vs baseline: 1.2573x; 1.0464x over previous
//
#include <hip/hip_runtime.h>
#include <hip/hip_bf16.h>

// Hybrid decoder block, MFMA everywhere GEMM-shaped, channels-last internals.
// row convention: r = z*4096 + n, n = y*64+x.
#define NTHREADS 256

typedef __attribute__((ext_vector_type(8))) short bs8_t;   // 8 bf16 (4 VGPRs)
typedef __attribute__((ext_vector_type(4))) float f4_t;    // 4 fp32 acc

__device__ __forceinline__ float bf2f(__hip_bfloat16 v) { return __bfloat162float(v); }
__device__ __forceinline__ __hip_bfloat16 f2bf(float v) { return __float2bfloat16(v); }
__device__ __forceinline__ float b2f_lo(unsigned int p) { return __uint_as_float(p << 16); }
__device__ __forceinline__ float b2f_hi(unsigned int p) { return __uint_as_float(p & 0xffff0000u); }
__device__ __forceinline__ float sigm(float x) { return 1.f / (1.f + __expf(-x)); }
__device__ __forceinline__ float leaky(float x) { return x > 0.f ? x : 0.01f * x; }
__device__ __forceinline__ float sane(float x) { return fminf(fmaxf(x, -1e9f), 1e9f); }
__device__ __forceinline__ unsigned packbf(float a, float b) {
  union { __hip_bfloat16 h[2]; unsigned u; } cv;
  cv.h[0] = f2bf(a); cv.h[1] = f2bf(b);
  return cv.u;
}
__device__ __forceinline__ float ldf(const void* p, long i, int f) {
  return f ? ((const float*)p)[i] : bf2f(((const __hip_bfloat16*)p)[i]);
}
// single-instruction 2^x (v_exp_f32); gfx9 trans ops are HW-interlocked.
__device__ __forceinline__ float exp2_fast(float x) {
  float r;
  asm("v_exp_f32 %0, %1" : "=v"(r) : "v"(x));
  return r;
}

// ---------------- dtype detector ----------------
__global__ void k_detect(const void* xp, int* flag) {
  __shared__ int cnt[NTHREADS];
  const __hip_bfloat16* h = (const __hip_bfloat16*)xp;
  int t = threadIdx.x;
  int c = 0;
  for (int j = 0; j < 8; j++) {
    float v = fabsf(bf2f(h[(t * 8 + j) * 2]));
    if (v > 1e-12f && v < 1e12f) c++;
  }
  cnt[t] = c;
  __syncthreads();
  for (int s = 128; s > 0; s >>= 1) {
    if (t < s) cnt[t] += cnt[t + s];
    __syncthreads();
  }
  if (t == 0) *flag = (cnt[0] > 1433) ? 0 : 1;
}

// generic converter: out[i] = bf16(in[i])
__global__ void k_prepcvt(const void* __restrict__ in, __hip_bfloat16* __restrict__ out,
                          int n, const int* __restrict__ flagp) {
  int f = *flagp;
  int gid = blockIdx.x * NTHREADS + threadIdx.x;
  if (gid < n) out[gid] = f2bf(ldf(in, gid, f));
}

// ---------------- pad1: x (ci-first) -> P1[z'(34)][y'(66)][x'(66)][32] bf16 ----------------
__global__ __launch_bounds__(NTHREADS) void k_pad1(const void* __restrict__ x,
                                                   __hip_bfloat16* __restrict__ P1,
                                                   const int* __restrict__ flagp) {
  __shared__ float tile[64 * 33];
  int f = *flagp;
  int zp = blockIdx.x / 66, yp = blockIdx.x % 66;
  long rowbase = ((long)zp * 66 + yp) * 66 * 32;
  int t = threadIdx.x;
  if (zp == 0 || zp == 33 || yp == 0 || yp == 65) {
    for (int i = t; i < 2112; i += NTHREADS) P1[rowbase + i] = f2bf(0.f);
    return;
  }
  int z = zp - 1, y = yp - 1;
#pragma unroll
  for (int j = 0; j < 8; j++) {
    int idx = t + j * NTHREADS;
    int ci = idx >> 6, xx = idx & 63;
    tile[xx * 33 + ci] = ldf(x, (long)(ci * 32 + z) * 4096 + y * 64 + xx, f);
  }
  __syncthreads();
#pragma unroll
  for (int j = 0; j < 8; j++) {
    int idx = t + j * NTHREADS;
    int xx = idx >> 5, ci = idx & 31;
    P1[rowbase + (xx + 1) * 32 + ci] = f2bf(tile[xx * 33 + ci]);
  }
  if (t < 32) P1[rowbase + t] = f2bf(0.f);
  else if (t < 64) P1[rowbase + 65 * 32 + (t - 32)] = f2bf(0.f);
}

// ---------------- weight reorg: cw (co,ci,2,3,3) -> W[s][co][ci] bf16 ----------------
__global__ void k_prepw(const void* __restrict__ cw, __hip_bfloat16* __restrict__ W,
                        int CI, const int* __restrict__ flagp) {
  int f = *flagp;
  int gid = blockIdx.x * NTHREADS + threadIdx.x;
  int s = gid / (64 * CI);
  int rem = gid % (64 * CI);
  int co = rem / CI, ci = rem % CI;
  W[gid] = f2bf(ldf(cw, (long)(co * CI + ci) * 18 + s, f));
}

// ---------------- MFMA implicit-GEMM conv + fused per-channel stats ----------------
// x-split: each block computes a 32-wide x half (xb = 0 or 32) -> 2x blocks,
// occupancy 2.1 -> ~4.25 blocks/CU (LDS allows 4). acc shrinks 4x4 -> 2x4.
template <int CI, int CIP>
__global__ __launch_bounds__(NTHREADS) void k_gemm_conv(const __hip_bfloat16* __restrict__ Pb,
                                                        const __hip_bfloat16* __restrict__ Wb,
                                                        __hip_bfloat16* __restrict__ out,
                                                        float* __restrict__ gacc) {
  __shared__ unsigned short Wl[3 * 64 * CIP];
  __shared__ float sred[256], qred[256];
  const unsigned short* P = (const unsigned short*)Pb;
  const unsigned short* W = (const unsigned short*)Wb;
  int t = threadIdx.x;
  int wv = t >> 6, lane = t & 63;
  int m = lane & 15, quad = lane >> 4;
  int zo  = blockIdx.x >> 5;
  int rem = blockIdx.x & 31;
  int y   = ((rem >> 1) << 2) + wv;
  int xb  = (rem & 1) << 5;
  f4_t zero4 = {0.f, 0.f, 0.f, 0.f};
  f4_t acc[2][4];
#pragma unroll
  for (int mt = 0; mt < 2; mt++)
#pragma unroll
    for (int nt = 0; nt < 4; nt++) acc[mt][nt] = zero4;

  for (int kz = 0; kz < 2; kz++) {
    for (int ky = 0; ky < 3; ky++) {
      __syncthreads();
      int s0 = (kz * 3 + ky) * 3;
      const unsigned short* wsrc = W + (long)s0 * 64 * CI;
      for (int i = t; i < 3 * 64 * CI; i += NTHREADS) {
        int kx = i / (64 * CI), rem2 = i % (64 * CI);
        int co = rem2 / CI, ci = rem2 % CI;
        Wl[(kx * 64 + co) * CIP + ci] = wsrc[i];
      }
      __syncthreads();
      int pz = zo + kz, py = y + ky;
      const unsigned short* prow = P + ((long)(pz * 66 + py) * 66) * CI;
#pragma unroll
      for (int kx = 0; kx < 3; kx++) {
#pragma unroll
        for (int ch = 0; ch < CI / 32; ch++) {
          int kof = kx * CI + ch * 32 + quad * 8;
          bs8_t a0 = *(const bs8_t*)(prow + (xb + 0 * 16 + m) * CI + kof);
          bs8_t a1 = *(const bs8_t*)(prow + (xb + 1 * 16 + m) * CI + kof);
#pragma unroll
          for (int nt = 0; nt < 4; nt++) {
            bs8_t b = *(const bs8_t*)&Wl[(kx * 64 + nt * 16 + m) * CIP + ch * 32 + quad * 8];
            acc[0][nt] = __builtin_amdgcn_mfma_f32_16x16x32_bf16(a0, b, acc[0][nt], 0, 0, 0);
            acc[1][nt] = __builtin_amdgcn_mfma_f32_16x16x32_bf16(a1, b, acc[1][nt], 0, 0, 0);
          }
        }
      }
    }
  }
  long obase = ((long)(zo * 64 + y) * 64) * 64;
  float psum[4], pq[4];
#pragma unroll
  for (int nt = 0; nt < 4; nt++) {
    int co = nt * 16 + m;
    float s = 0.f, q = 0.f;
#pragma unroll
    for (int mt = 0; mt < 2; mt++)
#pragma unroll
      for (int rg = 0; rg < 4; rg++) {
        float v = acc[mt][nt][rg];
        int xx = xb + mt * 16 + quad * 4 + rg;
        out[obase + xx * 64 + co] = f2bf(v);
        s += v;
        q += v * v;
      }
    psum[nt] = s;
    pq[nt] = q;
  }
#pragma unroll
  for (int nt = 0; nt < 4; nt++) {
    psum[nt] += __shfl_xor(psum[nt], 16, 64);
    psum[nt] += __shfl_xor(psum[nt], 32, 64);
    pq[nt]   += __shfl_xor(pq[nt], 16, 64);
    pq[nt]   += __shfl_xor(pq[nt], 32, 64);
  }
  if (quad == 0) {
#pragma unroll
    for (int nt = 0; nt < 4; nt++) {
      sred[wv * 64 + nt * 16 + m] = psum[nt];
      qred[wv * 64 + nt * 16 + m] = pq[nt];
    }
  }
  __syncthreads();
  if (t < 64) {
    atomicAdd(&gacc[t], sred[t] + sred[64 + t] + sred[128 + t] + sred[192 + t]);
    atomicAdd(&gacc[64 + t], qred[t] + qred[64 + t] + qred[128 + t] + qred[192 + t]);
  }
}

__global__ void k_finalize(const float* __restrict__ acc, const void* __restrict__ g,
                           const void* __restrict__ b, float* __restrict__ ss, float invN,
                           const int* __restrict__ flagp) {
  int f = *flagp;
  int t = threadIdx.x;  // 64
  float mean = acc[t] * invN;
  float var  = acc[64 + t] * invN - mean * mean;
  float rstd = rsqrtf(fmaxf(var, 0.f) + 1e-5f);
  float sc   = ldf(g, t, f) * rstd;
  ss[t]      = sc;
  ss[64 + t] = ldf(b, t, f) - mean * sc;
}

// ---------------- normpad: c1raw -> norm+leaky -> P2[35][66][66][64] ----------------
__global__ __launch_bounds__(NTHREADS) void k_normpad(const __hip_bfloat16* __restrict__ in,
                                                      const float* __restrict__ ss,
                                                      __hip_bfloat16* __restrict__ P2) {
  int zp = blockIdx.x / 66, yp = blockIdx.x % 66;
  long rowbase = ((long)zp * 66 + yp) * 66 * 64;
  int t = threadIdx.x;
  if (zp == 0 || zp == 34 || yp == 0 || yp == 65) {
    for (int i = t; i < 4224; i += NTHREADS) P2[rowbase + i] = f2bf(0.f);
    return;
  }
  int z = zp - 1, y = yp - 1;
#pragma unroll
  for (int j = 0; j < 16; j++) {
    int idx = t + j * NTHREADS;
    int xx = idx >> 6, co = idx & 63;
    float v = bf2f(in[((long)(z * 64 + y) * 64 + xx) * 64 + co]) * ss[co] + ss[64 + co];
    P2[rowbase + (xx + 1) * 64 + co] = f2bf(leaky(v));
  }
  if (t < 64) P2[rowbase + t] = f2bf(0.f);
  else if (t < 128) P2[rowbase + 65 * 64 + (t - 64)] = f2bf(0.f);
}

// ---------------- hslice: c2raw -> norm+leaky -> hcl + residual d_out[c][r] ----------------
__global__ __launch_bounds__(NTHREADS) void k_hslice_cl(const __hip_bfloat16* __restrict__ in,
                                                        const float* __restrict__ ss,
                                                        __hip_bfloat16* __restrict__ hcl,
                                                        void* __restrict__ resid,
                                                        const int* __restrict__ flagp) {
  __shared__ float tile[64 * 65];
  int f = *flagp;
  int z = blockIdx.x >> 6, y = blockIdx.x & 63;
  long r0 = (long)z * 4096 + y * 64;
  int t = threadIdx.x;
#pragma unroll
  for (int j = 0; j < 16; j++) {
    int idx = t + j * NTHREADS;
    int xx = idx >> 6, co = idx & 63;
    float v = leaky(bf2f(in[(r0 + xx) * 64 + co]) * ss[co] + ss[64 + co]);
    hcl[(r0 + xx) * 64 + co] = f2bf(v);
    tile[xx * 65 + co] = v;
  }
  __syncthreads();
#pragma unroll
  for (int j = 0; j < 16; j++) {
    int idx = t + j * NTHREADS;
    int co = idx >> 6, xx = idx & 63;
    long off = (long)co * 131072 + r0 + xx;
    if (f) ((float*)resid)[off] = tile[xx * 65 + co];
    else   ((__hip_bfloat16*)resid)[off] = f2bf(tile[xx * 65 + co]);
  }
}

// ---------------- dw3x3 + pw1x1 (MFMA pointwise) + inr stats ----------------
__global__ __launch_bounds__(NTHREADS) void k_dwpw_mfma(const __hip_bfloat16* __restrict__ hcl,
                                                        const void* __restrict__ dwb,
                                                        const __hip_bfloat16* __restrict__ pwbb,
                                                        __hip_bfloat16* __restrict__ out,
                                                        float* __restrict__ acc,
                                                        const int* __restrict__ flagp) {
  __shared__ unsigned short hl[3 * 64 * 64];
  __shared__ unsigned short dwt[64 * 72];
  __shared__ unsigned short pwl[64 * 72];
  __shared__ float dwl[576];
  __shared__ float sred[256], qred[256];
  int f = *flagp;
  int t = threadIdx.x;
  int z = blockIdx.x >> 6, y = blockIdx.x & 63;
  for (int i = t; i < 576; i += NTHREADS) dwl[i] = ldf(dwb, i, f);
  {
    const unsigned short* ps = (const unsigned short*)pwbb;
    for (int i = t; i < 4096; i += NTHREADS) pwl[(i >> 6) * 72 + (i & 63)] = ps[i];
  }
  const unsigned short* hsrc = (const unsigned short*)hcl;
  for (int i = t; i < 12288; i += NTHREADS) {
    int dy = i / 4096, rem = i & 4095;
    int ry = y - 1 + dy;
    hl[i] = ((unsigned)ry < 64u) ? hsrc[((long)z * 4096 + ry * 64) * 64 + rem] : (unsigned short)0;
  }
  __syncthreads();
  const unsigned* hl32 = (const unsigned*)hl;
  unsigned* dwt32 = (unsigned*)dwt;
#pragma unroll
  for (int j = 0; j < 8; j++) {
    int idx = t + j * NTHREADS;
    int xx = idx >> 5, cp = idx & 31;
    float a0 = 0.f, a1 = 0.f;
#pragma unroll
    for (int dy = 0; dy < 3; dy++)
#pragma unroll
      for (int dx = 0; dx < 3; dx++) {
        int xv = xx - 1 + dx;
        if ((unsigned)xv < 64u) {
          unsigned hv = hl32[(dy * 64 + xv) * 32 + cp];
          a0 = fmaf(b2f_lo(hv), dwl[(cp * 2) * 9 + dy * 3 + dx], a0);
          a1 = fmaf(b2f_hi(hv), dwl[(cp * 2 + 1) * 9 + dy * 3 + dx], a1);
        }
      }
    dwt32[xx * 36 + cp] = packbf(a0, a1);
  }
  __syncthreads();
  int wv = t >> 6, lane = t & 63;
  int m = lane & 15, quad = lane >> 4;
  f4_t zero4 = {0.f, 0.f, 0.f, 0.f};
  f4_t acc4[4];
#pragma unroll
  for (int nt = 0; nt < 4; nt++) acc4[nt] = zero4;
#pragma unroll
  for (int ch = 0; ch < 2; ch++) {
    bs8_t a = *(const bs8_t*)&dwt[(wv * 16 + m) * 72 + ch * 32 + quad * 8];
#pragma unroll
    for (int nt = 0; nt < 4; nt++) {
      bs8_t b = *(const bs8_t*)&pwl[(nt * 16 + m) * 72 + ch * 32 + quad * 8];
      acc4[nt] = __builtin_amdgcn_mfma_f32_16x16x32_bf16(a, b, acc4[nt], 0, 0, 0);
    }
  }
  long obase = ((long)z * 4096 + y * 64) * 64;
  float psum[4], pq[4];
#pragma unroll
  for (int nt = 0; nt < 4; nt++) {
    float s = 0.f, q = 0.f;
#pragma unroll
    for (int rg = 0; rg < 4; rg++) {
      float v = acc4[nt][rg];
      int xx = wv * 16 + quad * 4 + rg;
      out[obase + xx * 64 + nt * 16 + m] = f2bf(v);
      s += v;
      q += v * v;
    }
    psum[nt] = s;
    pq[nt] = q;
  }
#pragma unroll
  for (int nt = 0; nt < 4; nt++) {
    psum[nt] += __shfl_xor(psum[nt], 16, 64);
    psum[nt] += __shfl_xor(psum[nt], 32, 64);
    pq[nt]   += __shfl_xor(pq[nt], 16, 64);
    pq[nt]   += __shfl_xor(pq[nt], 32, 64);
  }
  if (quad == 0) {
#pragma unroll
    for (int nt = 0; nt < 4; nt++) {
      sred[wv * 64 + nt * 16 + m] = psum[nt];
      qred[wv * 64 + nt * 16 + m] = pq[nt];
    }
  }
  __syncthreads();
  if (t < 64) {
    atomicAdd(&acc[t], sred[t] + sred[64 + t] + sred[128 + t] + sred[192 + t]);
    atomicAdd(&acc[64 + t], qred[t] + qred[64 + t] + qred[128 + t] + qred[192 + t]);
  }
}

// ---------------- x2 = h + silu(norm(pre2)); LayerNorm C=64 -> seq bf16 ----------------
__global__ __launch_bounds__(NTHREADS) void k_x2ln_cl(const __hip_bfloat16* __restrict__ hcl,
                                                      const __hip_bfloat16* __restrict__ p2,
                                                      const float* __restrict__ ssr,
                                                      const void* __restrict__ lng,
                                                      const void* __restrict__ lnb,
                                                      __hip_bfloat16* __restrict__ out,
                                                      const int* __restrict__ flagp) {
  __shared__ float sc[64], sh[64], sg[64], sb[64];
  int f = *flagp;
  int t = threadIdx.x;
  if (t < 64) {
    sc[t] = ssr[t];
    sh[t] = ssr[64 + t];
    sg[t] = ldf(lng, t, f);
    sb[t] = ldf(lnb, t, f);
  }
  __syncthreads();
  long r = (long)blockIdx.x * NTHREADS + t;
  const uint4* hp = (const uint4*)(hcl + r * 64);
  const uint4* pp = (const uint4*)(p2 + r * 64);
  float v[64];
  float s1 = 0.f;
#pragma unroll
  for (int q = 0; q < 8; q++) {
    uint4 hu = hp[q], pu = pp[q];
    float hv[8] = {b2f_lo(hu.x), b2f_hi(hu.x), b2f_lo(hu.y), b2f_hi(hu.y),
                   b2f_lo(hu.z), b2f_hi(hu.z), b2f_lo(hu.w), b2f_hi(hu.w)};
    float pv[8] = {b2f_lo(pu.x), b2f_hi(pu.x), b2f_lo(pu.y), b2f_hi(pu.y),
                   b2f_lo(pu.z), b2f_hi(pu.z), b2f_lo(pu.w), b2f_hi(pu.w)};
#pragma unroll
    for (int i = 0; i < 8; i++) {
      int c = q * 8 + i;
      float pn = sc[c] * pv[i] + sh[c];
      float x2 = hv[i] + pn * sigm(pn);
      v[c] = x2;
      s1 += x2;
    }
  }
  float m = s1 * (1.f / 64.f);
  float s2 = 0.f;
#pragma unroll
  for (int c = 0; c < 64; c++) {
    float d = v[c] - m;
    s2 += d * d;
  }
  float rstd = rsqrtf(s2 * (1.f / 64.f) + 1e-5f);
  uint4* o4 = (uint4*)(out + r * 64);
#pragma unroll
  for (int q = 0; q < 8; q++) {
    int c = q * 8;
    uint4 o;
    o.x = packbf((v[c + 0] - m) * rstd * sg[c + 0] + sb[c + 0],
                 (v[c + 1] - m) * rstd * sg[c + 1] + sb[c + 1]);
    o.y = packbf((v[c + 2] - m) * rstd * sg[c + 2] + sb[c + 2],
                 (v[c + 3] - m) * rstd * sg[c + 3] + sb[c + 3]);
    o.z = packbf((v[c + 4] - m) * rstd * sg[c + 4] + sb[c + 4],
                 (v[c + 5] - m) * rstd * sg[c + 5] + sb[c + 5]);
    o.w = packbf((v[c + 6] - m) * rstd * sg[c + 6] + sb[c + 6],
                 (v[c + 7] - m) * rstd * sg[c + 7] + sb[c + 7]);
    o4[q] = o;
  }
}

// ---------------- in_proj MFMA ----------------
__global__ __launch_bounds__(NTHREADS) void k_inproj_mfma(const __hip_bfloat16* __restrict__ seq,
                                                          const __hip_bfloat16* __restrict__ Wbf,
                                                          __hip_bfloat16* __restrict__ x_in,
                                                          __hip_bfloat16* __restrict__ zg) {
  __shared__ unsigned short Wl[256 * 72];
  const unsigned short* ws = (const unsigned short*)Wbf;
  int t = threadIdx.x;
  for (int i = t; i < 16384; i += NTHREADS) Wl[(i >> 6) * 72 + (i & 63)] = ws[i];
  __syncthreads();
  int wv = t >> 6, lane = t & 63;
  int m = lane & 15, quad = lane >> 4;
  long m0 = (long)blockIdx.x * 64;
  int n0 = wv * 64;
  f4_t zero4 = {0.f, 0.f, 0.f, 0.f};
  f4_t acc[4][4];
#pragma unroll
  for (int mt = 0; mt < 4; mt++)
#pragma unroll
    for (int nt = 0; nt < 4; nt++) acc[mt][nt] = zero4;
  const unsigned short* sp = (const unsigned short*)seq;
#pragma unroll
  for (int ch = 0; ch < 2; ch++) {
    int kof = ch * 32 + quad * 8;
    bs8_t a0 = *(const bs8_t*)(sp + (m0 + 0 * 16 + m) * 64 + kof);
    bs8_t a1 = *(const bs8_t*)(sp + (m0 + 1 * 16 + m) * 64 + kof);
    bs8_t a2 = *(const bs8_t*)(sp + (m0 + 2 * 16 + m) * 64 + kof);
    bs8_t a3 = *(const bs8_t*)(sp + (m0 + 3 * 16 + m) * 64 + kof);
#pragma unroll
    for (int nt = 0; nt < 4; nt++) {
      bs8_t b = *(const bs8_t*)&Wl[(n0 + nt * 16 + m) * 72 + kof];
      acc[0][nt] = __builtin_amdgcn_mfma_f32_16x16x32_bf16(a0, b, acc[0][nt], 0, 0, 0);
      acc[1][nt] = __builtin_amdgcn_mfma_f32_16x16x32_bf16(a1, b, acc[1][nt], 0, 0, 0);
      acc[2][nt] = __builtin_amdgcn_mfma_f32_16x16x32_bf16(a2, b, acc[2][nt], 0, 0, 0);
      acc[3][nt] = __builtin_amdgcn_mfma_f32_16x16x32_bf16(a3, b, acc[3][nt], 0, 0, 0);
    }
  }
  __hip_bfloat16* obuf = (n0 < 128) ? x_in : zg;
  int cbase = (n0 < 128) ? n0 : (n0 - 128);
#pragma unroll
  for (int mt = 0; mt < 4; mt++)
#pragma unroll
    for (int nt = 0; nt < 4; nt++) {
      int col = cbase + nt * 16 + m;
#pragma unroll
      for (int rg = 0; rg < 4; rg++) {
        long row = m0 + mt * 16 + quad * 4 + rg;
        obuf[row * 128 + col] = f2bf(acc[mt][nt][rg]);
      }
    }
}

// ---------------- causal depthwise conv1d, in place ----------------
// All 32 z-values preloaded into registers (independent loads, one latency),
// compute fully in-registers, then 32 stores.
__global__ __launch_bounds__(NTHREADS) void k_conv1d_ip(__hip_bfloat16* xio,
                                                        const void* __restrict__ wb,
                                                        const void* __restrict__ bb,
                                                        const int* __restrict__ flagp) {
  int f = *flagp;
  int gid = blockIdx.x * NTHREADS + threadIdx.x;
  int d = gid & 127, nl = gid >> 7;
  float w0 = ldf(wb, d * 4 + 0, f), w1 = ldf(wb, d * 4 + 1, f);
  float w2 = ldf(wb, d * 4 + 2, f), w3 = ldf(wb, d * 4 + 3, f);
  float bias = ldf(bb, d, f);
  const size_t stride = 4096u * 128u;
  size_t off0 = (size_t)nl * 128 + d;
  float xv[32];
#pragma unroll
  for (int z = 0; z < 32; z++) xv[z] = bf2f(xio[off0 + (size_t)z * stride]);
  float h0 = 0.f, h1 = 0.f, h2 = 0.f;
#pragma unroll
  for (int z = 0; z < 32; z++) {
    float cur = xv[z];
    float a = bias;
    a = fmaf(h0, w0, a);
    a = fmaf(h1, w1, a);
    a = fmaf(h2, w2, a);
    a = fmaf(cur, w3, a);
    xv[z] = a * sigm(a);
    h0 = h1; h1 = h2; h2 = cur;
  }
#pragma unroll
  for (int z = 0; z < 32; z++) xio[off0 + (size_t)z * stride] = f2bf(xv[z]);
}

// ---------------- x_proj MFMA: (131072,128) x (36->48 pad,128)^T ----------------
// outputs: dtin[r][4] f32 (cols 0..3) and BC[r][32] f32 (cols 4..35)
__global__ __launch_bounds__(NTHREADS) void k_xproj_mfma(const __hip_bfloat16* __restrict__ A,
                                                         const __hip_bfloat16* __restrict__ Wbf,
                                                         float* __restrict__ dtin,
                                                         float* __restrict__ BC) {
  __shared__ unsigned short Wl[48 * 136];
  const unsigned short* ws = (const unsigned short*)Wbf;   // (36,128) row-major
  int t = threadIdx.x;
  for (int i = t; i < 48 * 128; i += NTHREADS) {
    int j = i >> 7, k = i & 127;
    Wl[j * 136 + k] = (j < 36) ? ws[j * 128 + k] : (unsigned short)0;
  }
  __syncthreads();
  int wv = t >> 6, lane = t & 63;
  int m = lane & 15, quad = lane >> 4;
  long m0 = (long)blockIdx.x * 256 + wv * 64;
  f4_t zero4 = {0.f, 0.f, 0.f, 0.f};
  f4_t acc[4][3];
#pragma unroll
  for (int mt = 0; mt < 4; mt++)
#pragma unroll
    for (int nt = 0; nt < 3; nt++) acc[mt][nt] = zero4;
  const unsigned short* ap = (const unsigned short*)A;
#pragma unroll
  for (int ch = 0; ch < 4; ch++) {
    int kof = ch * 32 + quad * 8;
    bs8_t a0 = *(const bs8_t*)(ap + (m0 + 0 * 16 + m) * 128 + kof);
    bs8_t a1 = *(const bs8_t*)(ap + (m0 + 1 * 16 + m) * 128 + kof);
    bs8_t a2 = *(const bs8_t*)(ap + (m0 + 2 * 16 + m) * 128 + kof);
    bs8_t a3 = *(const bs8_t*)(ap + (m0 + 3 * 16 + m) * 128 + kof);
#pragma unroll
    for (int nt = 0; nt < 3; nt++) {
      bs8_t b = *(const bs8_t*)&Wl[(nt * 16 + m) * 136 + kof];
      acc[0][nt] = __builtin_amdgcn_mfma_f32_16x16x32_bf16(a0, b, acc[0][nt], 0, 0, 0);
      acc[1][nt] = __builtin_amdgcn_mfma_f32_16x16x32_bf16(a1, b, acc[1][nt], 0, 0, 0);
      acc[2][nt] = __builtin_amdgcn_mfma_f32_16x16x32_bf16(a2, b, acc[2][nt], 0, 0, 0);
      acc[3][nt] = __builtin_amdgcn_mfma_f32_16x16x32_bf16(a3, b, acc[3][nt], 0, 0, 0);
    }
  }
#pragma unroll
  for (int mt = 0; mt < 4; mt++)
#pragma unroll
    for (int nt = 0; nt < 3; nt++) {
      int col = nt * 16 + m;
#pragma unroll
      for (int rg = 0; rg < 4; rg++) {
        long row = m0 + mt * 16 + quad * 4 + rg;
        float v = acc[mt][nt][rg];
        if (col < 4) dtin[row * 4 + col] = v;
        else if (col < 36) BC[row * 32 + (col - 4)] = v;
      }
    }
}

// ---------------- selective scan ----------------
// geo fast path: BC/dt rows are WAVE-UNIFORM (n = gid>>7 is constant across a
// 64-lane wave) -> route through readfirstlane so the backend emits scalar
// (s_load) fetches: one fetch per wave instead of 64 redundant vector loads,
// operands consumed straight from SGPRs. u/zv stay per-lane (prefetched).
__global__ __launch_bounds__(NTHREADS) void k_scan(const float* __restrict__ dtin,
                                                   const float* __restrict__ BC,
                                                   __hip_bfloat16* __restrict__ uy,
                                                   const __hip_bfloat16* __restrict__ zg,
                                                   const void* __restrict__ dtw,
                                                   const void* __restrict__ dtb,
                                                   const void* __restrict__ Alog,
                                                   const void* __restrict__ Dp,
                                                   const int* __restrict__ flagp) {
  int f = *flagp;
  int gid = blockIdx.x * NTHREADS + threadIdx.x;
  int d = gid & 127, n = gid >> 7;
  // A2[s] = -exp(A_log[d][s]) * log2(e): exp(dt*A) == exp2(dt*A2)
  float A2[16];
#pragma unroll
  for (int s = 0; s < 16; s++)
    A2[s] = -__expf(fminf(ldf(Alog, d * 16 + s, f), 60.f)) * 1.44269504088896f;
  float W0 = ldf(dtw, d * 4 + 0, f), W1 = ldf(dtw, d * 4 + 1, f);
  float W2 = ldf(dtw, d * 4 + 2, f), W3 = ldf(dtw, d * 4 + 3, f);
  float bias = ldf(dtb, d, f);
  float Dv = ldf(Dp, d, f);
  float a0 = A2[0];
  int geo = 1;
#pragma unroll
  for (int s = 1; s < 16; s++)
    geo &= (fabsf(A2[s] - (float)(s + 1) * a0) <= 1e-4f * fabsf(A2[s])) ? 1 : 0;
  geo = __all(geo);
  float st[16];
#pragma unroll
  for (int s = 0; s < 16; s++) st[s] = 0.f;
  if (geo) {
    int nu_ = __builtin_amdgcn_readfirstlane(n);   // wave-uniform -> scalar addr
    const float4* bp0 = (const float4*)(BC + (size_t)nu_ * 32);
    const float4* dp0 = (const float4*)(dtin + (size_t)nu_ * 4);
    const __hip_bfloat16* up0 = uy + (size_t)n * 128 + d;
    const __hip_bfloat16* zp0 = zg + (size_t)n * 128 + d;
    __hip_bfloat16* uq = uy + (size_t)n * 128 + d;
    const size_t ustep = 4096u * 128u;
    // prologue: loads for z=0
    float4 b0 = bp0[0], b1 = bp0[1], b2 = bp0[2], b3 = bp0[3];
    float4 c0 = bp0[4], c1 = bp0[5], c2 = bp0[6], c3 = bp0[7];
    float4 dt4 = dp0[0];
    float u  = sane(bf2f(*up0));
    float zv = sane(bf2f(*zp0));
#pragma unroll 2
    for (int z = 0; z < 32; z++) {
      // prefetch z+1 (z=31 re-reads z=31; values unused)
      int zn = (z < 31) ? z + 1 : 31;
      const float4* bpn = bp0 + (size_t)zn * 32768u;
      float4 nb0 = bpn[0], nb1 = bpn[1], nb2 = bpn[2], nb3 = bpn[3];
      float4 nc0 = bpn[4], nc1 = bpn[5], nc2 = bpn[6], nc3 = bpn[7];
      float4 ndt = dp0[(size_t)zn * 4096u];
      float nu  = sane(bf2f(up0[(size_t)zn * ustep]));
      float nzv = sane(bf2f(zp0[(size_t)zn * ustep]));
      // compute current z
      float v = bias;
      v = fmaf(dt4.x, W0, v);
      v = fmaf(dt4.y, W1, v);
      v = fmaf(dt4.z, W2, v);
      v = fmaf(dt4.w, W3, v);
      float dtv = v > 20.f ? v : __logf(1.f + __expf(v));
      dtv = fminf(fmaxf(dtv, 0.f), 60.f);
      float du = dtv * u;
      float e1 = exp2_fast(dtv * a0);
      float e2 = e1 * e1;
      float es[16];
      es[0] = e1; es[1] = e2;
#pragma unroll
      for (int s = 2; s < 16; s++) es[s] = es[s - 2] * e2;
      float B[16] = {b0.x, b0.y, b0.z, b0.w, b1.x, b1.y, b1.z, b1.w,
                     b2.x, b2.y, b2.z, b2.w, b3.x, b3.y, b3.z, b3.w};
      float C[16] = {c0.x, c0.y, c0.z, c0.w, c1.x, c1.y, c1.z, c1.w,
                     c2.x, c2.y, c2.z, c2.w, c3.x, c3.y, c3.z, c3.w};
#pragma unroll
      for (int s = 0; s < 16; s++) st[s] = fmaf(es[s], st[s], du * B[s]);
      float y0 = 0.f, y1 = 0.f, y2 = 0.f, y3 = 0.f;
#pragma unroll
      for (int s = 0; s < 16; s += 4) {
        y0 = fmaf(st[s + 0], C[s + 0], y0);
        y1 = fmaf(st[s + 1], C[s + 1], y1);
        y2 = fmaf(st[s + 2], C[s + 2], y2);
        y3 = fmaf(st[s + 3], C[s + 3], y3);
      }
      float y = (y0 + y1) + (y2 + y3);
      y = sane((y + Dv * u) * (zv * sigm(zv)));
      uq[(size_t)z * ustep] = f2bf(y);
      // rotate pipeline registers (scalar copies on the SALU pipe if uniform)
      b0 = nb0; b1 = nb1; b2 = nb2; b3 = nb3;
      c0 = nc0; c1 = nc1; c2 = nc2; c3 = nc3;
      dt4 = ndt; u = nu; zv = nzv;
    }
  } else {
#pragma unroll
    for (int s = 0; s < 16; s++) asm("" : "+v"(A2[s]));  // pin; forbid remat/AGPR
    for (int z = 0; z < 32; z++) {
      size_t r = (size_t)z * 4096 + n;
      const float4* bp = (const float4*)(BC + r * 32);
      float4 dt4 = *(const float4*)(dtin + r * 4);
      float4 b0 = bp[0], b1 = bp[1], b2 = bp[2], b3 = bp[3];
      float4 c0 = bp[4], c1 = bp[5], c2 = bp[6], c3 = bp[7];
      float u = sane(bf2f(uy[r * 128 + d]));
      float zv = sane(bf2f(zg[r * 128 + d]));
      float v = bias;
      v = fmaf(dt4.x, W0, v);
      v = fmaf(dt4.y, W1, v);
      v = fmaf(dt4.z, W2, v);
      v = fmaf(dt4.w, W3, v);
      float dtv = v > 20.f ? v : __logf(1.f + __expf(v));
      dtv = fminf(fmaxf(dtv, 0.f), 60.f);
      float du = dtv * u;
      float B[16] = {b0.x, b0.y, b0.z, b0.w, b1.x, b1.y, b1.z, b1.w,
                     b2.x, b2.y, b2.z, b2.w, b3.x, b3.y, b3.z, b3.w};
      float C[16] = {c0.x, c0.y, c0.z, c0.w, c1.x, c1.y, c1.z, c1.w,
                     c2.x, c2.y, c2.z, c2.w, c3.x, c3.y, c3.z, c3.w};
      float y = 0.f;
#pragma unroll
      for (int s = 0; s < 16; s++) {
        float e = exp2_fast(dtv * A2[s]);
        st[s] = fmaf(e, st[s], du * B[s]);
        y = fmaf(st[s], C[s], y);
      }
      y = sane((y + Dv * u) * (zv * sigm(zv)));
      uy[r * 128 + d] = f2bf(y);
    }
  }
}

// ---------------- W_comb = proj_w @ out_proj_w -> bf16 [o][d] ----------------
__global__ void k_wcomb(const void* __restrict__ pw, const void* __restrict__ opw,
                        __hip_bfloat16* __restrict__ wc, const int* __restrict__ flagp) {
  int f = *flagp;
  int gid = blockIdx.x * NTHREADS + threadIdx.x;
  int d = gid & 127, o = gid >> 7;
  float a = 0.f;
#pragma unroll
  for (int j = 0; j < 64; j++) a = fmaf(ldf(pw, o * 64 + j, f), ldf(opw, j * 128 + d, f), a);
  wc[(size_t)o * 128 + d] = f2bf(a);
}

// ---------------- out_proj+proj MFMA + fused pn stats ----------------
__global__ __launch_bounds__(NTHREADS) void k_outproj_mfma(const __hip_bfloat16* __restrict__ A,
                                                           const __hip_bfloat16* __restrict__ Wcb,
                                                           const void* __restrict__ bias,
                                                           __hip_bfloat16* __restrict__ out,
                                                           float* __restrict__ gacc,
                                                           const int* __restrict__ flagp) {
  __shared__ unsigned short Wl[64 * 136];
  __shared__ float bl[64];
  __shared__ float sred[256], qred[256];
  int f = *flagp;
  int t = threadIdx.x;
  const unsigned short* ws = (const unsigned short*)Wcb;
  for (int i = t; i < 8192; i += NTHREADS) Wl[(i >> 7) * 136 + (i & 127)] = ws[i];
  if (t < 64) bl[t] = ldf(bias, t, f);
  __syncthreads();
  int wv = t >> 6, lane = t & 63;
  int m = lane & 15, quad = lane >> 4;
  long m0 = (long)blockIdx.x * 256 + wv * 64;
  f4_t zero4 = {0.f, 0.f, 0.f, 0.f};
  f4_t acc[4][4];
#pragma unroll
  for (int mt = 0; mt < 4; mt++)
#pragma unroll
    for (int nt = 0; nt < 4; nt++) acc[mt][nt] = zero4;
  const unsigned short* ap = (const unsigned short*)A;
#pragma unroll
  for (int ch = 0; ch < 4; ch++) {
    int kof = ch * 32 + quad * 8;
    bs8_t a0 = *(const bs8_t*)(ap + (m0 + 0 * 16 + m) * 128 + kof);
    bs8_t a1 = *(const bs8_t*)(ap + (m0 + 1 * 16 + m) * 128 + kof);
    bs8_t a2 = *(const bs8_t*)(ap + (m0 + 2 * 16 + m) * 128 + kof);
    bs8_t a3 = *(const bs8_t*)(ap + (m0 + 3 * 16 + m) * 128 + kof);
#pragma unroll
    for (int nt = 0; nt < 4; nt++) {
      bs8_t b = *(const bs8_t*)&Wl[(nt * 16 + m) * 136 + kof];
      acc[0][nt] = __builtin_amdgcn_mfma_f32_16x16x32_bf16(a0, b, acc[0][nt], 0, 0, 0);
      acc[1][nt] = __builtin_amdgcn_mfma_f32_16x16x32_bf16(a1, b, acc[1][nt], 0, 0, 0);
      acc[2][nt] = __builtin_amdgcn_mfma_f32_16x16x32_bf16(a2, b, acc[2][nt], 0, 0, 0);
      acc[3][nt] = __builtin_amdgcn_mfma_f32_16x16x32_bf16(a3, b, acc[3][nt], 0, 0, 0);
    }
  }
  float psum[4], pq[4];
#pragma unroll
  for (int nt = 0; nt < 4; nt++) {
    int co = nt * 16 + m;
    float s = 0.f, q = 0.f;
#pragma unroll
    for (int mt = 0; mt < 4; mt++)
#pragma unroll
      for (int rg = 0; rg < 4; rg++) {
        float v = sane(acc[mt][nt][rg] + bl[co]);
        long row = m0 + mt * 16 + quad * 4 + rg;
        out[row * 64 + co] = f2bf(v);
        s += v;
        q += v * v;
      }
    psum[nt] = s;
    pq[nt] = q;
  }
#pragma unroll
  for (int nt = 0; nt < 4; nt++) {
    psum[nt] += __shfl_xor(psum[nt], 16, 64);
    psum[nt] += __shfl_xor(psum[nt], 32, 64);
    pq[nt]   += __shfl_xor(pq[nt], 16, 64);
    pq[nt]   += __shfl_xor(pq[nt], 32, 64);
  }
  if (quad == 0) {
#pragma unroll
    for (int nt = 0; nt < 4; nt++) {
      sred[wv * 64 + nt * 16 + m] = psum[nt];
      qred[wv * 64 + nt * 16 + m] = pq[nt];
    }
  }
  __syncthreads();
  if (t < 64) {
    atomicAdd(&gacc[t], sred[t] + sred[64 + t] + sred[128 + t] + sred[192 + t]);
    atomicAdd(&gacc[64 + t], qred[t] + qred[64 + t] + qred[128 + t] + qred[192 + t]);
  }
}

// ---------------- final ----------------
__global__ __launch_bounds__(NTHREADS) void k_final(const __hip_bfloat16* __restrict__ s2,
                                                    void* __restrict__ io,
                                                    const float* __restrict__ ss,
                                                    const int* __restrict__ flagp) {
  __shared__ float tile[64 * 65];
  __shared__ float sc[64], sh[64];
  int f = *flagp;
  int t = threadIdx.x;
  if (t < 64) {
    sc[t] = ss[t];
    sh[t] = ss[64 + t];
  }
  int z = blockIdx.x >> 6, n0 = (blockIdx.x & 63) << 6;
  size_t base = ((size_t)z * 4096 + n0) * 64;
  __syncthreads();
#pragma unroll
  for (int jj = 0; jj < 16; jj++) {
    int id = t + jj * NTHREADS;
    int i = id >> 6, c = id & 63;
    float v = sane(bf2f(s2[base + id]));
    tile[i * 65 + c] = sc[c] * v + sh[c];
  }
  __syncthreads();
#pragma unroll
  for (int jj = 0; jj < 16; jj++) {
    int id = t + jj * NTHREADS;
    int c = id >> 6, nl = id & 63;
    size_t off = (size_t)c * 131072 + (size_t)z * 4096 + n0 + nl;
    if (f) {
      float* o = (float*)io;
      o[off] = sane(o[off] + tile[nl * 65 + c]);
    } else {
      __hip_bfloat16* o = (__hip_bfloat16*)io;
      o[off] = f2bf(sane(bf2f(o[off]) + tile[nl * 65 + c]));
    }
  }
}

// ---------------- launch ----------------
extern "C" void kernel_launch(void* const* d_in, const int* in_sizes, int n_in,
                              void* d_out, int out_size, void* d_ws, size_t ws_size,
                              hipStream_t stream) {
  (void)in_sizes; (void)n_in; (void)out_size; (void)ws_size;
  const void* x        = d_in[0];
  const void* c1_w     = d_in[1];
  const void* in1_g    = d_in[2];
  const void* in1_b    = d_in[3];
  const void* c2_w     = d_in[4];
  const void* in2_g    = d_in[5];
  const void* in2_b    = d_in[6];
  const void* dw_w     = d_in[7];
  const void* pw_w     = d_in[8];
  const void* inr_g    = d_in[9];
  const void* inr_b    = d_in[10];
  const void* ln_g     = d_in[11];
  const void* ln_b     = d_in[12];
  const void* in_proj_w= d_in[13];
  const void* conv1d_w = d_in[14];
  const void* conv1d_b = d_in[15];
  const void* x_proj_w = d_in[16];
  const void* dt_proj_w= d_in[17];
  const void* dt_proj_b= d_in[18];
  const void* A_log    = d_in[19];
  const void* D_p      = d_in[20];
  const void* out_proj_w=d_in[21];
  const void* proj_w   = d_in[22];
  const void* proj_b   = d_in[23];
  const void* pn_g     = d_in[24];
  const void* pn_b     = d_in[25];

  char* wb = (char*)d_ws;
  // Byte layout, TOTAL ~= 87.4 MB (< 90.3 MB proven mapped in R7).
  // R0 [0, 33,554,432): P1(9.5M) -> P2(19.5M) -> zg(33.5M) -> s2(16.8M)
  __hip_bfloat16* P1   = (__hip_bfloat16*)wb;
  __hip_bfloat16* P2   = (__hip_bfloat16*)wb;
  __hip_bfloat16* zgb  = (__hip_bfloat16*)wb;
  __hip_bfloat16* s2   = (__hip_bfloat16*)wb;
  // R1 [33,554,432, 67,108,864): c1raw(17.3M) -> c2raw(17.8M) | pre2(16.8M) -> x_in(33.5M)
  // NOTE: x_in spans [33,554,432, 67,108,864) and is LIVE until k_outproj — nothing
  // may alias inside that range while the scan pipeline runs.
  __hip_bfloat16* c1raw = (__hip_bfloat16*)(wb + 33554432);
  __hip_bfloat16* c2raw = (__hip_bfloat16*)(wb + 33554432);
  __hip_bfloat16* pre2  = (__hip_bfloat16*)(wb + 33554432);
  __hip_bfloat16* x_in  = (__hip_bfloat16*)(wb + 33554432);
  // hcl [51,380,224, 68,157,440) — dead after k_x2ln (overlaps x_in tail; x_in written later)
  __hip_bfloat16* hcl   = (__hip_bfloat16*)(wb + 51380224);
  // seq [68,157,440, 84,934,656); BC (f32, 16,777,216 B exactly) aliases it after inproj
  __hip_bfloat16* seq   = (__hip_bfloat16*)(wb + 68157440);
  float*          BCf   = (float*)(wb + 68157440);
  // weights [84,934,656 ...)
  __hip_bfloat16* W1b   = (__hip_bfloat16*)(wb + 84934656);             // 73,728 B
  __hip_bfloat16* W2b   = (__hip_bfloat16*)(wb + 85008384);             // 147,456 B
  __hip_bfloat16* inwb  = (__hip_bfloat16*)(wb + 85155840);             // 32,768 B
  __hip_bfloat16* wcombb= (__hip_bfloat16*)(wb + 85188608);             // 16,384 B
  __hip_bfloat16* pwbb  = (__hip_bfloat16*)(wb + 85204992);             // 8,192 B
  __hip_bfloat16* xpwb  = (__hip_bfloat16*)(wb + 85213184);             // 9,216 B
  float*          fst   = (float*)(wb + 85222400);                      // 4,112 B
  // dtin f32 [85,229,568, 87,326,720) — free tail, outside every live buffer
  float*          dtinf = (float*)(wb + 85229568);

  float* acc_in1 = fst;
  float* acc_in2 = fst + 128;
  float* acc_inr = fst + 256;
  float* acc_pn  = fst + 384;
  float* ss_in1  = fst + 512;
  float* ss_in2  = fst + 640;
  float* ss_inr  = fst + 768;
  float* ss_pn   = fst + 896;
  int*   flagp   = (int*)(fst + 1024);

  hipMemsetAsync(fst, 0, 512 * sizeof(float), stream);

  k_detect<<<1, NTHREADS, 0, stream>>>(x, flagp);
  k_pad1<<<34 * 66, NTHREADS, 0, stream>>>(x, P1, flagp);
  k_prepw<<<144, NTHREADS, 0, stream>>>(c1_w, W1b, 32, flagp);
  k_prepw<<<288, NTHREADS, 0, stream>>>(c2_w, W2b, 64, flagp);
  k_prepcvt<<<64, NTHREADS, 0, stream>>>(in_proj_w, inwb, 16384, flagp);
  k_prepcvt<<<16, NTHREADS, 0, stream>>>(pw_w, pwbb, 4096, flagp);
  k_prepcvt<<<18, NTHREADS, 0, stream>>>(x_proj_w, xpwb, 4608, flagp);
  k_wcomb<<<32, NTHREADS, 0, stream>>>(proj_w, out_proj_w, wcombb, flagp);

  k_gemm_conv<32, 40><<<33 * 32, NTHREADS, 0, stream>>>(P1, W1b, c1raw, acc_in1);
  k_finalize<<<1, 64, 0, stream>>>(acc_in1, in1_g, in1_b, ss_in1, 1.0f / 135168.0f, flagp);
  k_normpad<<<35 * 66, NTHREADS, 0, stream>>>(c1raw, ss_in1, P2);

  k_gemm_conv<64, 88><<<34 * 32, NTHREADS, 0, stream>>>(P2, W2b, c2raw, acc_in2);
  k_finalize<<<1, 64, 0, stream>>>(acc_in2, in2_g, in2_b, ss_in2, 1.0f / 139264.0f, flagp);
  k_hslice_cl<<<2048, NTHREADS, 0, stream>>>(c2raw, ss_in2, hcl, d_out, flagp);

  k_dwpw_mfma<<<2048, NTHREADS, 0, stream>>>(hcl, dw_w, pwbb, pre2, acc_inr, flagp);
  k_finalize<<<1, 64, 0, stream>>>(acc_inr, inr_g, inr_b, ss_inr, 1.0f / 131072.0f, flagp);
  k_x2ln_cl<<<512, NTHREADS, 0, stream>>>(hcl, pre2, ss_inr, ln_g, ln_b, seq, flagp);

  k_inproj_mfma<<<2048, NTHREADS, 0, stream>>>(seq, inwb, x_in, zgb);
  k_conv1d_ip<<<2048, NTHREADS, 0, stream>>>(x_in, conv1d_w, conv1d_b, flagp);
  k_xproj_mfma<<<512, NTHREADS, 0, stream>>>(x_in, xpwb, dtinf, BCf);
  k_scan<<<2048, NTHREADS, 0, stream>>>(dtinf, BCf, x_in, zgb, dt_proj_w, dt_proj_b, A_log, D_p, flagp);
  k_outproj_mfma<<<512, NTHREADS, 0, stream>>>(x_in, wcombb, proj_b, s2, acc_pn, flagp);

  k_finalize<<<1, 64, 0, stream>>>(acc_pn, pn_g, pn_b, ss_pn, 1.0f / 131072.0f, flagp);
  k_final<<<2048, NTHREADS, 0, stream>>>(s2, d_out, ss_pn, flagp);
}

// Round 7
// 528.878 us; speedup vs baseline: 1.3199x; 1.0498x over previous
//
#include <hip/hip_runtime.h>
#include <hip/hip_bf16.h>

// Hybrid decoder block, MFMA everywhere GEMM-shaped, channels-last internals.
// row convention: r = z*4096 + n, n = y*64+x.
#define NTHREADS 256

typedef __attribute__((ext_vector_type(8))) short bs8_t;   // 8 bf16 (4 VGPRs)
typedef __attribute__((ext_vector_type(4))) float f4_t;    // 4 fp32 acc

__device__ __forceinline__ float bf2f(__hip_bfloat16 v) { return __bfloat162float(v); }
__device__ __forceinline__ __hip_bfloat16 f2bf(float v) { return __float2bfloat16(v); }
__device__ __forceinline__ float b2f_lo(unsigned int p) { return __uint_as_float(p << 16); }
__device__ __forceinline__ float b2f_hi(unsigned int p) { return __uint_as_float(p & 0xffff0000u); }
__device__ __forceinline__ float sigm(float x) { return 1.f / (1.f + __expf(-x)); }
__device__ __forceinline__ float leaky(float x) { return x > 0.f ? x : 0.01f * x; }
__device__ __forceinline__ float sane(float x) { return fminf(fmaxf(x, -1e9f), 1e9f); }
__device__ __forceinline__ unsigned packbf(float a, float b) {
  union { __hip_bfloat16 h[2]; unsigned u; } cv;
  cv.h[0] = f2bf(a); cv.h[1] = f2bf(b);
  return cv.u;
}
__device__ __forceinline__ float ldf(const void* p, long i, int f) {
  return f ? ((const float*)p)[i] : bf2f(((const __hip_bfloat16*)p)[i]);
}
// single-instruction 2^x (v_exp_f32); gfx9 trans ops are HW-interlocked.
__device__ __forceinline__ float exp2_fast(float x) {
  float r;
  asm("v_exp_f32 %0, %1" : "=v"(r) : "v"(x));
  return r;
}

// ---------------- dtype detector ----------------
__global__ void k_detect(const void* xp, int* flag) {
  __shared__ int cnt[NTHREADS];
  const __hip_bfloat16* h = (const __hip_bfloat16*)xp;
  int t = threadIdx.x;
  int c = 0;
  for (int j = 0; j < 8; j++) {
    float v = fabsf(bf2f(h[(t * 8 + j) * 2]));
    if (v > 1e-12f && v < 1e12f) c++;
  }
  cnt[t] = c;
  __syncthreads();
  for (int s = 128; s > 0; s >>= 1) {
    if (t < s) cnt[t] += cnt[t + s];
    __syncthreads();
  }
  if (t == 0) *flag = (cnt[0] > 1433) ? 0 : 1;
}

// generic converter: out[i] = bf16(in[i])
__global__ void k_prepcvt(const void* __restrict__ in, __hip_bfloat16* __restrict__ out,
                          int n, const int* __restrict__ flagp) {
  int f = *flagp;
  int gid = blockIdx.x * NTHREADS + threadIdx.x;
  if (gid < n) out[gid] = f2bf(ldf(in, gid, f));
}

// ---------------- pad1: x (ci-first) -> P1[z'(34)][y'(66)][x'(66)][32] bf16 ----------------
__global__ __launch_bounds__(NTHREADS) void k_pad1(const void* __restrict__ x,
                                                   __hip_bfloat16* __restrict__ P1,
                                                   const int* __restrict__ flagp) {
  __shared__ float tile[64 * 33];
  int f = *flagp;
  int zp = blockIdx.x / 66, yp = blockIdx.x % 66;
  long rowbase = ((long)zp * 66 + yp) * 66 * 32;
  int t = threadIdx.x;
  if (zp == 0 || zp == 33 || yp == 0 || yp == 65) {
    for (int i = t; i < 2112; i += NTHREADS) P1[rowbase + i] = f2bf(0.f);
    return;
  }
  int z = zp - 1, y = yp - 1;
#pragma unroll
  for (int j = 0; j < 8; j++) {
    int idx = t + j * NTHREADS;
    int ci = idx >> 6, xx = idx & 63;
    tile[xx * 33 + ci] = ldf(x, (long)(ci * 32 + z) * 4096 + y * 64 + xx, f);
  }
  __syncthreads();
#pragma unroll
  for (int j = 0; j < 8; j++) {
    int idx = t + j * NTHREADS;
    int xx = idx >> 5, ci = idx & 31;
    P1[rowbase + (xx + 1) * 32 + ci] = f2bf(tile[xx * 33 + ci]);
  }
  if (t < 32) P1[rowbase + t] = f2bf(0.f);
  else if (t < 64) P1[rowbase + 65 * 32 + (t - 32)] = f2bf(0.f);
}

// ---------------- weight reorg: cw (co,ci,2,3,3) -> W[s][co][ci] bf16 ----------------
__global__ void k_prepw(const void* __restrict__ cw, __hip_bfloat16* __restrict__ W,
                        int CI, const int* __restrict__ flagp) {
  int f = *flagp;
  int gid = blockIdx.x * NTHREADS + threadIdx.x;
  int s = gid / (64 * CI);
  int rem = gid % (64 * CI);
  int co = rem / CI, ci = rem % CI;
  W[gid] = f2bf(ldf(cw, (long)(co * CI + ci) * 18 + s, f));
}

// ---------------- MFMA implicit-GEMM conv + fused per-channel stats ----------------
// x-split: each block computes a 32-wide x half (xb = 0 or 32) -> 2x blocks.
template <int CI, int CIP>
__global__ __launch_bounds__(NTHREADS) void k_gemm_conv(const __hip_bfloat16* __restrict__ Pb,
                                                        const __hip_bfloat16* __restrict__ Wb,
                                                        __hip_bfloat16* __restrict__ out,
                                                        float* __restrict__ gacc) {
  __shared__ unsigned short Wl[3 * 64 * CIP];
  __shared__ float sred[256], qred[256];
  const unsigned short* P = (const unsigned short*)Pb;
  const unsigned short* W = (const unsigned short*)Wb;
  int t = threadIdx.x;
  int wv = t >> 6, lane = t & 63;
  int m = lane & 15, quad = lane >> 4;
  int zo  = blockIdx.x >> 5;
  int rem = blockIdx.x & 31;
  int y   = ((rem >> 1) << 2) + wv;
  int xb  = (rem & 1) << 5;
  f4_t zero4 = {0.f, 0.f, 0.f, 0.f};
  f4_t acc[2][4];
#pragma unroll
  for (int mt = 0; mt < 2; mt++)
#pragma unroll
    for (int nt = 0; nt < 4; nt++) acc[mt][nt] = zero4;

  for (int kz = 0; kz < 2; kz++) {
    for (int ky = 0; ky < 3; ky++) {
      __syncthreads();
      int s0 = (kz * 3 + ky) * 3;
      const unsigned short* wsrc = W + (long)s0 * 64 * CI;
      for (int i = t; i < 3 * 64 * CI; i += NTHREADS) {
        int kx = i / (64 * CI), rem2 = i % (64 * CI);
        int co = rem2 / CI, ci = rem2 % CI;
        Wl[(kx * 64 + co) * CIP + ci] = wsrc[i];
      }
      __syncthreads();
      int pz = zo + kz, py = y + ky;
      const unsigned short* prow = P + ((long)(pz * 66 + py) * 66) * CI;
#pragma unroll
      for (int kx = 0; kx < 3; kx++) {
#pragma unroll
        for (int ch = 0; ch < CI / 32; ch++) {
          int kof = kx * CI + ch * 32 + quad * 8;
          bs8_t a0 = *(const bs8_t*)(prow + (xb + 0 * 16 + m) * CI + kof);
          bs8_t a1 = *(const bs8_t*)(prow + (xb + 1 * 16 + m) * CI + kof);
#pragma unroll
          for (int nt = 0; nt < 4; nt++) {
            bs8_t b = *(const bs8_t*)&Wl[(kx * 64 + nt * 16 + m) * CIP + ch * 32 + quad * 8];
            acc[0][nt] = __builtin_amdgcn_mfma_f32_16x16x32_bf16(a0, b, acc[0][nt], 0, 0, 0);
            acc[1][nt] = __builtin_amdgcn_mfma_f32_16x16x32_bf16(a1, b, acc[1][nt], 0, 0, 0);
          }
        }
      }
    }
  }
  long obase = ((long)(zo * 64 + y) * 64) * 64;
  float psum[4], pq[4];
#pragma unroll
  for (int nt = 0; nt < 4; nt++) {
    int co = nt * 16 + m;
    float s = 0.f, q = 0.f;
#pragma unroll
    for (int mt = 0; mt < 2; mt++)
#pragma unroll
      for (int rg = 0; rg < 4; rg++) {
        float v = acc[mt][nt][rg];
        int xx = xb + mt * 16 + quad * 4 + rg;
        out[obase + xx * 64 + co] = f2bf(v);
        s += v;
        q += v * v;
      }
    psum[nt] = s;
    pq[nt] = q;
  }
#pragma unroll
  for (int nt = 0; nt < 4; nt++) {
    psum[nt] += __shfl_xor(psum[nt], 16, 64);
    psum[nt] += __shfl_xor(psum[nt], 32, 64);
    pq[nt]   += __shfl_xor(pq[nt], 16, 64);
    pq[nt]   += __shfl_xor(pq[nt], 32, 64);
  }
  if (quad == 0) {
#pragma unroll
    for (int nt = 0; nt < 4; nt++) {
      sred[wv * 64 + nt * 16 + m] = psum[nt];
      qred[wv * 64 + nt * 16 + m] = pq[nt];
    }
  }
  __syncthreads();
  if (t < 64) {
    atomicAdd(&gacc[t], sred[t] + sred[64 + t] + sred[128 + t] + sred[192 + t]);
    atomicAdd(&gacc[64 + t], qred[t] + qred[64 + t] + qred[128 + t] + qred[192 + t]);
  }
}

__global__ void k_finalize(const float* __restrict__ acc, const void* __restrict__ g,
                           const void* __restrict__ b, float* __restrict__ ss, float invN,
                           const int* __restrict__ flagp) {
  int f = *flagp;
  int t = threadIdx.x;  // 64
  float mean = acc[t] * invN;
  float var  = acc[64 + t] * invN - mean * mean;
  float rstd = rsqrtf(fmaxf(var, 0.f) + 1e-5f);
  float sc   = ldf(g, t, f) * rstd;
  ss[t]      = sc;
  ss[64 + t] = ldf(b, t, f) - mean * sc;
}

// ---------------- normpad: c1raw -> norm+leaky -> P2[35][66][66][64] ----------------
__global__ __launch_bounds__(NTHREADS) void k_normpad(const __hip_bfloat16* __restrict__ in,
                                                      const float* __restrict__ ss,
                                                      __hip_bfloat16* __restrict__ P2) {
  int zp = blockIdx.x / 66, yp = blockIdx.x % 66;
  long rowbase = ((long)zp * 66 + yp) * 66 * 64;
  int t = threadIdx.x;
  if (zp == 0 || zp == 34 || yp == 0 || yp == 65) {
    for (int i = t; i < 4224; i += NTHREADS) P2[rowbase + i] = f2bf(0.f);
    return;
  }
  int z = zp - 1, y = yp - 1;
#pragma unroll
  for (int j = 0; j < 16; j++) {
    int idx = t + j * NTHREADS;
    int xx = idx >> 6, co = idx & 63;
    float v = bf2f(in[((long)(z * 64 + y) * 64 + xx) * 64 + co]) * ss[co] + ss[64 + co];
    P2[rowbase + (xx + 1) * 64 + co] = f2bf(leaky(v));
  }
  if (t < 64) P2[rowbase + t] = f2bf(0.f);
  else if (t < 128) P2[rowbase + 65 * 64 + (t - 64)] = f2bf(0.f);
}

// ---------------- hslice: c2raw -> norm+leaky -> hcl + residual d_out[c][r] ----------------
__global__ __launch_bounds__(NTHREADS) void k_hslice_cl(const __hip_bfloat16* __restrict__ in,
                                                        const float* __restrict__ ss,
                                                        __hip_bfloat16* __restrict__ hcl,
                                                        void* __restrict__ resid,
                                                        const int* __restrict__ flagp) {
  __shared__ float tile[64 * 65];
  int f = *flagp;
  int z = blockIdx.x >> 6, y = blockIdx.x & 63;
  long r0 = (long)z * 4096 + y * 64;
  int t = threadIdx.x;
#pragma unroll
  for (int j = 0; j < 16; j++) {
    int idx = t + j * NTHREADS;
    int xx = idx >> 6, co = idx & 63;
    float v = leaky(bf2f(in[(r0 + xx) * 64 + co]) * ss[co] + ss[64 + co]);
    hcl[(r0 + xx) * 64 + co] = f2bf(v);
    tile[xx * 65 + co] = v;
  }
  __syncthreads();
#pragma unroll
  for (int j = 0; j < 16; j++) {
    int idx = t + j * NTHREADS;
    int co = idx >> 6, xx = idx & 63;
    long off = (long)co * 131072 + r0 + xx;
    if (f) ((float*)resid)[off] = tile[xx * 65 + co];
    else   ((__hip_bfloat16*)resid)[off] = f2bf(tile[xx * 65 + co]);
  }
}

// ---------------- dw3x3 + pw1x1 (MFMA pointwise) + inr stats ----------------
// Staging vectorized to uint4 (16B): hl = 6 loads/thread (was 48 x 2B),
// pwl = 2 loads/thread (was 16 x 2B). Layouts unchanged.
__global__ __launch_bounds__(NTHREADS) void k_dwpw_mfma(const __hip_bfloat16* __restrict__ hcl,
                                                        const void* __restrict__ dwb,
                                                        const __hip_bfloat16* __restrict__ pwbb,
                                                        __hip_bfloat16* __restrict__ out,
                                                        float* __restrict__ acc,
                                                        const int* __restrict__ flagp) {
  __shared__ unsigned short hl[3 * 64 * 64];
  __shared__ unsigned short dwt[64 * 72];
  __shared__ unsigned short pwl[64 * 72];
  __shared__ float dwl[576];
  __shared__ float sred[256], qred[256];
  int f = *flagp;
  int t = threadIdx.x;
  int z = blockIdx.x >> 6, y = blockIdx.x & 63;
  for (int i = t; i < 576; i += NTHREADS) dwl[i] = ldf(dwb, i, f);
  {
    const uint4* ps4 = (const uint4*)pwbb;
#pragma unroll
    for (int j = 0; j < 2; j++) {
      int i = t + j * NTHREADS;          // i in [0,512): uint4 index, 8 ushorts
      int row = i >> 3, g = i & 7;
      *(uint4*)&pwl[row * 72 + g * 8] = ps4[i];
    }
  }
  {
    const unsigned short* hsrc = (const unsigned short*)hcl;
    uint4* hl4 = (uint4*)hl;
#pragma unroll
    for (int j = 0; j < 6; j++) {
      int i = t + j * NTHREADS;          // i in [0,1536): uint4 index
      int dy = i / 512, rem = i % 512;   // rem in uint4 units within the row-slab
      int ry = y - 1 + dy;
      uint4 v = make_uint4(0u, 0u, 0u, 0u);
      if ((unsigned)ry < 64u)
        v = *(const uint4*)(hsrc + ((long)z * 4096 + ry * 64) * 64 + rem * 8);
      hl4[i] = v;
    }
  }
  __syncthreads();
  const unsigned* hl32 = (const unsigned*)hl;
  unsigned* dwt32 = (unsigned*)dwt;
#pragma unroll
  for (int j = 0; j < 8; j++) {
    int idx = t + j * NTHREADS;
    int xx = idx >> 5, cp = idx & 31;
    float a0 = 0.f, a1 = 0.f;
#pragma unroll
    for (int dy = 0; dy < 3; dy++)
#pragma unroll
      for (int dx = 0; dx < 3; dx++) {
        int xv = xx - 1 + dx;
        if ((unsigned)xv < 64u) {
          unsigned hv = hl32[(dy * 64 + xv) * 32 + cp];
          a0 = fmaf(b2f_lo(hv), dwl[(cp * 2) * 9 + dy * 3 + dx], a0);
          a1 = fmaf(b2f_hi(hv), dwl[(cp * 2 + 1) * 9 + dy * 3 + dx], a1);
        }
      }
    dwt32[xx * 36 + cp] = packbf(a0, a1);
  }
  __syncthreads();
  int wv = t >> 6, lane = t & 63;
  int m = lane & 15, quad = lane >> 4;
  f4_t zero4 = {0.f, 0.f, 0.f, 0.f};
  f4_t acc4[4];
#pragma unroll
  for (int nt = 0; nt < 4; nt++) acc4[nt] = zero4;
#pragma unroll
  for (int ch = 0; ch < 2; ch++) {
    bs8_t a = *(const bs8_t*)&dwt[(wv * 16 + m) * 72 + ch * 32 + quad * 8];
#pragma unroll
    for (int nt = 0; nt < 4; nt++) {
      bs8_t b = *(const bs8_t*)&pwl[(nt * 16 + m) * 72 + ch * 32 + quad * 8];
      acc4[nt] = __builtin_amdgcn_mfma_f32_16x16x32_bf16(a, b, acc4[nt], 0, 0, 0);
    }
  }
  long obase = ((long)z * 4096 + y * 64) * 64;
  float psum[4], pq[4];
#pragma unroll
  for (int nt = 0; nt < 4; nt++) {
    float s = 0.f, q = 0.f;
#pragma unroll
    for (int rg = 0; rg < 4; rg++) {
      float v = acc4[nt][rg];
      int xx = wv * 16 + quad * 4 + rg;
      out[obase + xx * 64 + nt * 16 + m] = f2bf(v);
      s += v;
      q += v * v;
    }
    psum[nt] = s;
    pq[nt] = q;
  }
#pragma unroll
  for (int nt = 0; nt < 4; nt++) {
    psum[nt] += __shfl_xor(psum[nt], 16, 64);
    psum[nt] += __shfl_xor(psum[nt], 32, 64);
    pq[nt]   += __shfl_xor(pq[nt], 16, 64);
    pq[nt]   += __shfl_xor(pq[nt], 32, 64);
  }
  if (quad == 0) {
#pragma unroll
    for (int nt = 0; nt < 4; nt++) {
      sred[wv * 64 + nt * 16 + m] = psum[nt];
      qred[wv * 64 + nt * 16 + m] = pq[nt];
    }
  }
  __syncthreads();
  if (t < 64) {
    atomicAdd(&acc[t], sred[t] + sred[64 + t] + sred[128 + t] + sred[192 + t]);
    atomicAdd(&acc[64 + t], qred[t] + qred[64 + t] + qred[128 + t] + qred[192 + t]);
  }
}

// ---------------- x2 = h + silu(norm(pre2)); LayerNorm C=64 -> seq bf16 ----------------
__global__ __launch_bounds__(NTHREADS) void k_x2ln_cl(const __hip_bfloat16* __restrict__ hcl,
                                                      const __hip_bfloat16* __restrict__ p2,
                                                      const float* __restrict__ ssr,
                                                      const void* __restrict__ lng,
                                                      const void* __restrict__ lnb,
                                                      __hip_bfloat16* __restrict__ out,
                                                      const int* __restrict__ flagp) {
  __shared__ float sc[64], sh[64], sg[64], sb[64];
  int f = *flagp;
  int t = threadIdx.x;
  if (t < 64) {
    sc[t] = ssr[t];
    sh[t] = ssr[64 + t];
    sg[t] = ldf(lng, t, f);
    sb[t] = ldf(lnb, t, f);
  }
  __syncthreads();
  long r = (long)blockIdx.x * NTHREADS + t;
  const uint4* hp = (const uint4*)(hcl + r * 64);
  const uint4* pp = (const uint4*)(p2 + r * 64);
  float v[64];
  float s1 = 0.f;
#pragma unroll
  for (int q = 0; q < 8; q++) {
    uint4 hu = hp[q], pu = pp[q];
    float hv[8] = {b2f_lo(hu.x), b2f_hi(hu.x), b2f_lo(hu.y), b2f_hi(hu.y),
                   b2f_lo(hu.z), b2f_hi(hu.z), b2f_lo(hu.w), b2f_hi(hu.w)};
    float pv[8] = {b2f_lo(pu.x), b2f_hi(pu.x), b2f_lo(pu.y), b2f_hi(pu.y),
                   b2f_lo(pu.z), b2f_hi(pu.z), b2f_lo(pu.w), b2f_hi(pu.w)};
#pragma unroll
    for (int i = 0; i < 8; i++) {
      int c = q * 8 + i;
      float pn = sc[c] * pv[i] + sh[c];
      float x2 = hv[i] + pn * sigm(pn);
      v[c] = x2;
      s1 += x2;
    }
  }
  float m = s1 * (1.f / 64.f);
  float s2 = 0.f;
#pragma unroll
  for (int c = 0; c < 64; c++) {
    float d = v[c] - m;
    s2 += d * d;
  }
  float rstd = rsqrtf(s2 * (1.f / 64.f) + 1e-5f);
  uint4* o4 = (uint4*)(out + r * 64);
#pragma unroll
  for (int q = 0; q < 8; q++) {
    int c = q * 8;
    uint4 o;
    o.x = packbf((v[c + 0] - m) * rstd * sg[c + 0] + sb[c + 0],
                 (v[c + 1] - m) * rstd * sg[c + 1] + sb[c + 1]);
    o.y = packbf((v[c + 2] - m) * rstd * sg[c + 2] + sb[c + 2],
                 (v[c + 3] - m) * rstd * sg[c + 3] + sb[c + 3]);
    o.z = packbf((v[c + 4] - m) * rstd * sg[c + 4] + sb[c + 4],
                 (v[c + 5] - m) * rstd * sg[c + 5] + sb[c + 5]);
    o.w = packbf((v[c + 6] - m) * rstd * sg[c + 6] + sb[c + 6],
                 (v[c + 7] - m) * rstd * sg[c + 7] + sb[c + 7]);
    o4[q] = o;
  }
}

// ---------------- in_proj MFMA ----------------
__global__ __launch_bounds__(NTHREADS) void k_inproj_mfma(const __hip_bfloat16* __restrict__ seq,
                                                          const __hip_bfloat16* __restrict__ Wbf,
                                                          __hip_bfloat16* __restrict__ x_in,
                                                          __hip_bfloat16* __restrict__ zg) {
  __shared__ unsigned short Wl[256 * 72];
  const unsigned short* ws = (const unsigned short*)Wbf;
  int t = threadIdx.x;
  for (int i = t; i < 16384; i += NTHREADS) Wl[(i >> 6) * 72 + (i & 63)] = ws[i];
  __syncthreads();
  int wv = t >> 6, lane = t & 63;
  int m = lane & 15, quad = lane >> 4;
  long m0 = (long)blockIdx.x * 64;
  int n0 = wv * 64;
  f4_t zero4 = {0.f, 0.f, 0.f, 0.f};
  f4_t acc[4][4];
#pragma unroll
  for (int mt = 0; mt < 4; mt++)
#pragma unroll
    for (int nt = 0; nt < 4; nt++) acc[mt][nt] = zero4;
  const unsigned short* sp = (const unsigned short*)seq;
#pragma unroll
  for (int ch = 0; ch < 2; ch++) {
    int kof = ch * 32 + quad * 8;
    bs8_t a0 = *(const bs8_t*)(sp + (m0 + 0 * 16 + m) * 64 + kof);
    bs8_t a1 = *(const bs8_t*)(sp + (m0 + 1 * 16 + m) * 64 + kof);
    bs8_t a2 = *(const bs8_t*)(sp + (m0 + 2 * 16 + m) * 64 + kof);
    bs8_t a3 = *(const bs8_t*)(sp + (m0 + 3 * 16 + m) * 64 + kof);
#pragma unroll
    for (int nt = 0; nt < 4; nt++) {
      bs8_t b = *(const bs8_t*)&Wl[(n0 + nt * 16 + m) * 72 + kof];
      acc[0][nt] = __builtin_amdgcn_mfma_f32_16x16x32_bf16(a0, b, acc[0][nt], 0, 0, 0);
      acc[1][nt] = __builtin_amdgcn_mfma_f32_16x16x32_bf16(a1, b, acc[1][nt], 0, 0, 0);
      acc[2][nt] = __builtin_amdgcn_mfma_f32_16x16x32_bf16(a2, b, acc[2][nt], 0, 0, 0);
      acc[3][nt] = __builtin_amdgcn_mfma_f32_16x16x32_bf16(a3, b, acc[3][nt], 0, 0, 0);
    }
  }
  __hip_bfloat16* obuf = (n0 < 128) ? x_in : zg;
  int cbase = (n0 < 128) ? n0 : (n0 - 128);
#pragma unroll
  for (int mt = 0; mt < 4; mt++)
#pragma unroll
    for (int nt = 0; nt < 4; nt++) {
      int col = cbase + nt * 16 + m;
#pragma unroll
      for (int rg = 0; rg < 4; rg++) {
        long row = m0 + mt * 16 + quad * 4 + rg;
        obuf[row * 128 + col] = f2bf(acc[mt][nt][rg]);
      }
    }
}

// ---------------- causal depthwise conv1d, in place ----------------
__global__ __launch_bounds__(NTHREADS) void k_conv1d_ip(__hip_bfloat16* xio,
                                                        const void* __restrict__ wb,
                                                        const void* __restrict__ bb,
                                                        const int* __restrict__ flagp) {
  int f = *flagp;
  int gid = blockIdx.x * NTHREADS + threadIdx.x;
  int d = gid & 127, nl = gid >> 7;
  float w0 = ldf(wb, d * 4 + 0, f), w1 = ldf(wb, d * 4 + 1, f);
  float w2 = ldf(wb, d * 4 + 2, f), w3 = ldf(wb, d * 4 + 3, f);
  float bias = ldf(bb, d, f);
  const size_t stride = 4096u * 128u;
  size_t off0 = (size_t)nl * 128 + d;
  float xv[32];
#pragma unroll
  for (int z = 0; z < 32; z++) xv[z] = bf2f(xio[off0 + (size_t)z * stride]);
  float h0 = 0.f, h1 = 0.f, h2 = 0.f;
#pragma unroll
  for (int z = 0; z < 32; z++) {
    float cur = xv[z];
    float a = bias;
    a = fmaf(h0, w0, a);
    a = fmaf(h1, w1, a);
    a = fmaf(h2, w2, a);
    a = fmaf(cur, w3, a);
    xv[z] = a * sigm(a);
    h0 = h1; h1 = h2; h2 = cur;
  }
#pragma unroll
  for (int z = 0; z < 32; z++) xio[off0 + (size_t)z * stride] = f2bf(xv[z]);
}

// ---------------- x_proj MFMA: (131072,128) x (36->48 pad,128)^T ----------------
// outputs: dtin[r][4] f32 (cols 0..3) and BC[r][32] f32 (cols 4..35)
__global__ __launch_bounds__(NTHREADS) void k_xproj_mfma(const __hip_bfloat16* __restrict__ A,
                                                         const __hip_bfloat16* __restrict__ Wbf,
                                                         float* __restrict__ dtin,
                                                         float* __restrict__ BC) {
  __shared__ unsigned short Wl[48 * 136];
  const unsigned short* ws = (const unsigned short*)Wbf;   // (36,128) row-major
  int t = threadIdx.x;
  for (int i = t; i < 48 * 128; i += NTHREADS) {
    int j = i >> 7, k = i & 127;
    Wl[j * 136 + k] = (j < 36) ? ws[j * 128 + k] : (unsigned short)0;
  }
  __syncthreads();
  int wv = t >> 6, lane = t & 63;
  int m = lane & 15, quad = lane >> 4;
  long m0 = (long)blockIdx.x * 256 + wv * 64;
  f4_t zero4 = {0.f, 0.f, 0.f, 0.f};
  f4_t acc[4][3];
#pragma unroll
  for (int mt = 0; mt < 4; mt++)
#pragma unroll
    for (int nt = 0; nt < 3; nt++) acc[mt][nt] = zero4;
  const unsigned short* ap = (const unsigned short*)A;
#pragma unroll
  for (int ch = 0; ch < 4; ch++) {
    int kof = ch * 32 + quad * 8;
    bs8_t a0 = *(const bs8_t*)(ap + (m0 + 0 * 16 + m) * 128 + kof);
    bs8_t a1 = *(const bs8_t*)(ap + (m0 + 1 * 16 + m) * 128 + kof);
    bs8_t a2 = *(const bs8_t*)(ap + (m0 + 2 * 16 + m) * 128 + kof);
    bs8_t a3 = *(const bs8_t*)(ap + (m0 + 3 * 16 + m) * 128 + kof);
#pragma unroll
    for (int nt = 0; nt < 3; nt++) {
      bs8_t b = *(const bs8_t*)&Wl[(nt * 16 + m) * 136 + kof];
      acc[0][nt] = __builtin_amdgcn_mfma_f32_16x16x32_bf16(a0, b, acc[0][nt], 0, 0, 0);
      acc[1][nt] = __builtin_amdgcn_mfma_f32_16x16x32_bf16(a1, b, acc[1][nt], 0, 0, 0);
      acc[2][nt] = __builtin_amdgcn_mfma_f32_16x16x32_bf16(a2, b, acc[2][nt], 0, 0, 0);
      acc[3][nt] = __builtin_amdgcn_mfma_f32_16x16x32_bf16(a3, b, acc[3][nt], 0, 0, 0);
    }
  }
#pragma unroll
  for (int mt = 0; mt < 4; mt++)
#pragma unroll
    for (int nt = 0; nt < 3; nt++) {
      int col = nt * 16 + m;
#pragma unroll
      for (int rg = 0; rg < 4; rg++) {
        long row = m0 + mt * 16 + quad * 4 + rg;
        float v = acc[mt][nt][rg];
        if (col < 4) dtin[row * 4 + col] = v;
        else if (col < 36) BC[row * 32 + (col - 4)] = v;
      }
    }
}

// ---------------- selective scan ----------------
// geo fast path: BC/dt rows are WAVE-UNIFORM (n = gid>>7) -> readfirstlane
// routes them to scalar s_load; per-lane u/zv prefetched 1 deep.
__global__ __launch_bounds__(NTHREADS) void k_scan(const float* __restrict__ dtin,
                                                   const float* __restrict__ BC,
                                                   __hip_bfloat16* __restrict__ uy,
                                                   const __hip_bfloat16* __restrict__ zg,
                                                   const void* __restrict__ dtw,
                                                   const void* __restrict__ dtb,
                                                   const void* __restrict__ Alog,
                                                   const void* __restrict__ Dp,
                                                   const int* __restrict__ flagp) {
  int f = *flagp;
  int gid = blockIdx.x * NTHREADS + threadIdx.x;
  int d = gid & 127, n = gid >> 7;
  // A2[s] = -exp(A_log[d][s]) * log2(e): exp(dt*A) == exp2(dt*A2)
  float A2[16];
#pragma unroll
  for (int s = 0; s < 16; s++)
    A2[s] = -__expf(fminf(ldf(Alog, d * 16 + s, f), 60.f)) * 1.44269504088896f;
  float W0 = ldf(dtw, d * 4 + 0, f), W1 = ldf(dtw, d * 4 + 1, f);
  float W2 = ldf(dtw, d * 4 + 2, f), W3 = ldf(dtw, d * 4 + 3, f);
  float bias = ldf(dtb, d, f);
  float Dv = ldf(Dp, d, f);
  float a0 = A2[0];
  int geo = 1;
#pragma unroll
  for (int s = 1; s < 16; s++)
    geo &= (fabsf(A2[s] - (float)(s + 1) * a0) <= 1e-4f * fabsf(A2[s])) ? 1 : 0;
  geo = __all(geo);
  float st[16];
#pragma unroll
  for (int s = 0; s < 16; s++) st[s] = 0.f;
  if (geo) {
    int nu_ = __builtin_amdgcn_readfirstlane(n);   // wave-uniform -> scalar addr
    const float4* bp0 = (const float4*)(BC + (size_t)nu_ * 32);
    const float4* dp0 = (const float4*)(dtin + (size_t)nu_ * 4);
    const __hip_bfloat16* up0 = uy + (size_t)n * 128 + d;
    const __hip_bfloat16* zp0 = zg + (size_t)n * 128 + d;
    __hip_bfloat16* uq = uy + (size_t)n * 128 + d;
    const size_t ustep = 4096u * 128u;
    // prologue: loads for z=0
    float4 b0 = bp0[0], b1 = bp0[1], b2 = bp0[2], b3 = bp0[3];
    float4 c0 = bp0[4], c1 = bp0[5], c2 = bp0[6], c3 = bp0[7];
    float4 dt4 = dp0[0];
    float u  = sane(bf2f(*up0));
    float zv = sane(bf2f(*zp0));
#pragma unroll 2
    for (int z = 0; z < 32; z++) {
      // prefetch z+1 (z=31 re-reads z=31; values unused)
      int zn = (z < 31) ? z + 1 : 31;
      const float4* bpn = bp0 + (size_t)zn * 32768u;
      float4 nb0 = bpn[0], nb1 = bpn[1], nb2 = bpn[2], nb3 = bpn[3];
      float4 nc0 = bpn[4], nc1 = bpn[5], nc2 = bpn[6], nc3 = bpn[7];
      float4 ndt = dp0[(size_t)zn * 4096u];
      float nu  = sane(bf2f(up0[(size_t)zn * ustep]));
      float nzv = sane(bf2f(zp0[(size_t)zn * ustep]));
      // compute current z
      float v = bias;
      v = fmaf(dt4.x, W0, v);
      v = fmaf(dt4.y, W1, v);
      v = fmaf(dt4.z, W2, v);
      v = fmaf(dt4.w, W3, v);
      float dtv = v > 20.f ? v : __logf(1.f + __expf(v));
      dtv = fminf(fmaxf(dtv, 0.f), 60.f);
      float du = dtv * u;
      float e1 = exp2_fast(dtv * a0);
      float e2 = e1 * e1;
      float es[16];
      es[0] = e1; es[1] = e2;
#pragma unroll
      for (int s = 2; s < 16; s++) es[s] = es[s - 2] * e2;
      float B[16] = {b0.x, b0.y, b0.z, b0.w, b1.x, b1.y, b1.z, b1.w,
                     b2.x, b2.y, b2.z, b2.w, b3.x, b3.y, b3.z, b3.w};
      float C[16] = {c0.x, c0.y, c0.z, c0.w, c1.x, c1.y, c1.z, c1.w,
                     c2.x, c2.y, c2.z, c2.w, c3.x, c3.y, c3.z, c3.w};
#pragma unroll
      for (int s = 0; s < 16; s++) st[s] = fmaf(es[s], st[s], du * B[s]);
      float y0 = 0.f, y1 = 0.f, y2 = 0.f, y3 = 0.f;
#pragma unroll
      for (int s = 0; s < 16; s += 4) {
        y0 = fmaf(st[s + 0], C[s + 0], y0);
        y1 = fmaf(st[s + 1], C[s + 1], y1);
        y2 = fmaf(st[s + 2], C[s + 2], y2);
        y3 = fmaf(st[s + 3], C[s + 3], y3);
      }
      float y = (y0 + y1) + (y2 + y3);
      y = sane((y + Dv * u) * (zv * sigm(zv)));
      uq[(size_t)z * ustep] = f2bf(y);
      // rotate pipeline registers (scalar copies on the SALU pipe if uniform)
      b0 = nb0; b1 = nb1; b2 = nb2; b3 = nb3;
      c0 = nc0; c1 = nc1; c2 = nc2; c3 = nc3;
      dt4 = ndt; u = nu; zv = nzv;
    }
  } else {
#pragma unroll
    for (int s = 0; s < 16; s++) asm("" : "+v"(A2[s]));  // pin; forbid remat/AGPR
    for (int z = 0; z < 32; z++) {
      size_t r = (size_t)z * 4096 + n;
      const float4* bp = (const float4*)(BC + r * 32);
      float4 dt4 = *(const float4*)(dtin + r * 4);
      float4 b0 = bp[0], b1 = bp[1], b2 = bp[2], b3 = bp[3];
      float4 c0 = bp[4], c1 = bp[5], c2 = bp[6], c3 = bp[7];
      float u = sane(bf2f(uy[r * 128 + d]));
      float zv = sane(bf2f(zg[r * 128 + d]));
      float v = bias;
      v = fmaf(dt4.x, W0, v);
      v = fmaf(dt4.y, W1, v);
      v = fmaf(dt4.z, W2, v);
      v = fmaf(dt4.w, W3, v);
      float dtv = v > 20.f ? v : __logf(1.f + __expf(v));
      dtv = fminf(fmaxf(dtv, 0.f), 60.f);
      float du = dtv * u;
      float B[16] = {b0.x, b0.y, b0.z, b0.w, b1.x, b1.y, b1.z, b1.w,
                     b2.x, b2.y, b2.z, b2.w, b3.x, b3.y, b3.z, b3.w};
      float C[16] = {c0.x, c0.y, c0.z, c0.w, c1.x, c1.y, c1.z, c1.w,
                     c2.x, c2.y, c2.z, c2.w, c3.x, c3.y, c3.z, c3.w};
      float y = 0.f;
#pragma unroll
      for (int s = 0; s < 16; s++) {
        float e = exp2_fast(dtv * A2[s]);
        st[s] = fmaf(e, st[s], du * B[s]);
        y = fmaf(st[s], C[s], y);
      }
      y = sane((y + Dv * u) * (zv * sigm(zv)));
      uy[r * 128 + d] = f2bf(y);
    }
  }
}

// ---------------- W_comb = proj_w @ out_proj_w -> bf16 [o][d] ----------------
__global__ void k_wcomb(const void* __restrict__ pw, const void* __restrict__ opw,
                        __hip_bfloat16* __restrict__ wc, const int* __restrict__ flagp) {
  int f = *flagp;
  int gid = blockIdx.x * NTHREADS + threadIdx.x;
  int d = gid & 127, o = gid >> 7;
  float a = 0.f;
#pragma unroll
  for (int j = 0; j < 64; j++) a = fmaf(ldf(pw, o * 64 + j, f), ldf(opw, j * 128 + d, f), a);
  wc[(size_t)o * 128 + d] = f2bf(a);
}

// ---------------- out_proj+proj MFMA + fused pn stats ----------------
__global__ __launch_bounds__(NTHREADS) void k_outproj_mfma(const __hip_bfloat16* __restrict__ A,
                                                           const __hip_bfloat16* __restrict__ Wcb,
                                                           const void* __restrict__ bias,
                                                           __hip_bfloat16* __restrict__ out,
                                                           float* __restrict__ gacc,
                                                           const int* __restrict__ flagp) {
  __shared__ unsigned short Wl[64 * 136];
  __shared__ float bl[64];
  __shared__ float sred[256], qred[256];
  int f = *flagp;
  int t = threadIdx.x;
  const unsigned short* ws = (const unsigned short*)Wcb;
  for (int i = t; i < 8192; i += NTHREADS) Wl[(i >> 7) * 136 + (i & 127)] = ws[i];
  if (t < 64) bl[t] = ldf(bias, t, f);
  __syncthreads();
  int wv = t >> 6, lane = t & 63;
  int m = lane & 15, quad = lane >> 4;
  long m0 = (long)blockIdx.x * 256 + wv * 64;
  f4_t zero4 = {0.f, 0.f, 0.f, 0.f};
  f4_t acc[4][4];
#pragma unroll
  for (int mt = 0; mt < 4; mt++)
#pragma unroll
    for (int nt = 0; nt < 4; nt++) acc[mt][nt] = zero4;
  const unsigned short* ap = (const unsigned short*)A;
#pragma unroll
  for (int ch = 0; ch < 4; ch++) {
    int kof = ch * 32 + quad * 8;
    bs8_t a0 = *(const bs8_t*)(ap + (m0 + 0 * 16 + m) * 128 + kof);
    bs8_t a1 = *(const bs8_t*)(ap + (m0 + 1 * 16 + m) * 128 + kof);
    bs8_t a2 = *(const bs8_t*)(ap + (m0 + 2 * 16 + m) * 128 + kof);
    bs8_t a3 = *(const bs8_t*)(ap + (m0 + 3 * 16 + m) * 128 + kof);
#pragma unroll
    for (int nt = 0; nt < 4; nt++) {
      bs8_t b = *(const bs8_t*)&Wl[(nt * 16 + m) * 136 + kof];
      acc[0][nt] = __builtin_amdgcn_mfma_f32_16x16x32_bf16(a0, b, acc[0][nt], 0, 0, 0);
      acc[1][nt] = __builtin_amdgcn_mfma_f32_16x16x32_bf16(a1, b, acc[1][nt], 0, 0, 0);
      acc[2][nt] = __builtin_amdgcn_mfma_f32_16x16x32_bf16(a2, b, acc[2][nt], 0, 0, 0);
      acc[3][nt] = __builtin_amdgcn_mfma_f32_16x16x32_bf16(a3, b, acc[3][nt], 0, 0, 0);
    }
  }
  float psum[4], pq[4];
#pragma unroll
  for (int nt = 0; nt < 4; nt++) {
    int co = nt * 16 + m;
    float s = 0.f, q = 0.f;
#pragma unroll
    for (int mt = 0; mt < 4; mt++)
#pragma unroll
      for (int rg = 0; rg < 4; rg++) {
        float v = sane(acc[mt][nt][rg] + bl[co]);
        long row = m0 + mt * 16 + quad * 4 + rg;
        out[row * 64 + co] = f2bf(v);
        s += v;
        q += v * v;
      }
    psum[nt] = s;
    pq[nt] = q;
  }
#pragma unroll
  for (int nt = 0; nt < 4; nt++) {
    psum[nt] += __shfl_xor(psum[nt], 16, 64);
    psum[nt] += __shfl_xor(psum[nt], 32, 64);
    pq[nt]   += __shfl_xor(pq[nt], 16, 64);
    pq[nt]   += __shfl_xor(pq[nt], 32, 64);
  }
  if (quad == 0) {
#pragma unroll
    for (int nt = 0; nt < 4; nt++) {
      sred[wv * 64 + nt * 16 + m] = psum[nt];
      qred[wv * 64 + nt * 16 + m] = pq[nt];
    }
  }
  __syncthreads();
  if (t < 64) {
    atomicAdd(&gacc[t], sred[t] + sred[64 + t] + sred[128 + t] + sred[192 + t]);
    atomicAdd(&gacc[64 + t], qred[t] + qred[64 + t] + qred[128 + t] + qred[192 + t]);
  }
}

// ---------------- final ----------------
__global__ __launch_bounds__(NTHREADS) void k_final(const __hip_bfloat16* __restrict__ s2,
                                                    void* __restrict__ io,
                                                    const float* __restrict__ ss,
                                                    const int* __restrict__ flagp) {
  __shared__ float tile[64 * 65];
  __shared__ float sc[64], sh[64];
  int f = *flagp;
  int t = threadIdx.x;
  if (t < 64) {
    sc[t] = ss[t];
    sh[t] = ss[64 + t];
  }
  int z = blockIdx.x >> 6, n0 = (blockIdx.x & 63) << 6;
  size_t base = ((size_t)z * 4096 + n0) * 64;
  __syncthreads();
#pragma unroll
  for (int jj = 0; jj < 16; jj++) {
    int id = t + jj * NTHREADS;
    int i = id >> 6, c = id & 63;
    float v = sane(bf2f(s2[base + id]));
    tile[i * 65 + c] = sc[c] * v + sh[c];
  }
  __syncthreads();
#pragma unroll
  for (int jj = 0; jj < 16; jj++) {
    int id = t + jj * NTHREADS;
    int c = id >> 6, nl = id & 63;
    size_t off = (size_t)c * 131072 + (size_t)z * 4096 + n0 + nl;
    if (f) {
      float* o = (float*)io;
      o[off] = sane(o[off] + tile[nl * 65 + c]);
    } else {
      __hip_bfloat16* o = (__hip_bfloat16*)io;
      o[off] = f2bf(sane(bf2f(o[off]) + tile[nl * 65 + c]));
    }
  }
}

// ---------------- launch ----------------
extern "C" void kernel_launch(void* const* d_in, const int* in_sizes, int n_in,
                              void* d_out, int out_size, void* d_ws, size_t ws_size,
                              hipStream_t stream) {
  (void)in_sizes; (void)n_in; (void)out_size; (void)ws_size;
  const void* x        = d_in[0];
  const void* c1_w     = d_in[1];
  const void* in1_g    = d_in[2];
  const void* in1_b    = d_in[3];
  const void* c2_w     = d_in[4];
  const void* in2_g    = d_in[5];
  const void* in2_b    = d_in[6];
  const void* dw_w     = d_in[7];
  const void* pw_w     = d_in[8];
  const void* inr_g    = d_in[9];
  const void* inr_b    = d_in[10];
  const void* ln_g     = d_in[11];
  const void* ln_b     = d_in[12];
  const void* in_proj_w= d_in[13];
  const void* conv1d_w = d_in[14];
  const void* conv1d_b = d_in[15];
  const void* x_proj_w = d_in[16];
  const void* dt_proj_w= d_in[17];
  const void* dt_proj_b= d_in[18];
  const void* A_log    = d_in[19];
  const void* D_p      = d_in[20];
  const void* out_proj_w=d_in[21];
  const void* proj_w   = d_in[22];
  const void* proj_b   = d_in[23];
  const void* pn_g     = d_in[24];
  const void* pn_b     = d_in[25];

  char* wb = (char*)d_ws;
  // Byte layout, TOTAL ~= 87.4 MB (< 90.3 MB proven mapped in R7).
  // R0 [0, 33,554,432): P1(9.5M) -> P2(19.5M) -> zg(33.5M) -> s2(16.8M)
  __hip_bfloat16* P1   = (__hip_bfloat16*)wb;
  __hip_bfloat16* P2   = (__hip_bfloat16*)wb;
  __hip_bfloat16* zgb  = (__hip_bfloat16*)wb;
  __hip_bfloat16* s2   = (__hip_bfloat16*)wb;
  // R1 [33,554,432, 67,108,864): c1raw(17.3M) -> c2raw(17.8M) | pre2(16.8M) -> x_in(33.5M)
  // NOTE: x_in spans [33,554,432, 67,108,864) and is LIVE until k_outproj — nothing
  // may alias inside that range while the scan pipeline runs.
  __hip_bfloat16* c1raw = (__hip_bfloat16*)(wb + 33554432);
  __hip_bfloat16* c2raw = (__hip_bfloat16*)(wb + 33554432);
  __hip_bfloat16* pre2  = (__hip_bfloat16*)(wb + 33554432);
  __hip_bfloat16* x_in  = (__hip_bfloat16*)(wb + 33554432);
  // hcl [51,380,224, 68,157,440) — dead after k_x2ln (overlaps x_in tail; x_in written later)
  __hip_bfloat16* hcl   = (__hip_bfloat16*)(wb + 51380224);
  // seq [68,157,440, 84,934,656); BC (f32, 16,777,216 B exactly) aliases it after inproj
  __hip_bfloat16* seq   = (__hip_bfloat16*)(wb + 68157440);
  float*          BCf   = (float*)(wb + 68157440);
  // weights [84,934,656 ...)
  __hip_bfloat16* W1b   = (__hip_bfloat16*)(wb + 84934656);             // 73,728 B
  __hip_bfloat16* W2b   = (__hip_bfloat16*)(wb + 85008384);             // 147,456 B
  __hip_bfloat16* inwb  = (__hip_bfloat16*)(wb + 85155840);             // 32,768 B
  __hip_bfloat16* wcombb= (__hip_bfloat16*)(wb + 85188608);             // 16,384 B
  __hip_bfloat16* pwbb  = (__hip_bfloat16*)(wb + 85204992);             // 8,192 B
  __hip_bfloat16* xpwb  = (__hip_bfloat16*)(wb + 85213184);             // 9,216 B
  float*          fst   = (float*)(wb + 85222400);                      // 4,112 B
  // dtin f32 [85,229,568, 87,326,720) — free tail, outside every live buffer
  float*          dtinf = (float*)(wb + 85229568);

  float* acc_in1 = fst;
  float* acc_in2 = fst + 128;
  float* acc_inr = fst + 256;
  float* acc_pn  = fst + 384;
  float* ss_in1  = fst + 512;
  float* ss_in2  = fst + 640;
  float* ss_inr  = fst + 768;
  float* ss_pn   = fst + 896;
  int*   flagp   = (int*)(fst + 1024);

  hipMemsetAsync(fst, 0, 512 * sizeof(float), stream);

  k_detect<<<1, NTHREADS, 0, stream>>>(x, flagp);
  k_pad1<<<34 * 66, NTHREADS, 0, stream>>>(x, P1, flagp);
  k_prepw<<<144, NTHREADS, 0, stream>>>(c1_w, W1b, 32, flagp);
  k_prepw<<<288, NTHREADS, 0, stream>>>(c2_w, W2b, 64, flagp);
  k_prepcvt<<<64, NTHREADS, 0, stream>>>(in_proj_w, inwb, 16384, flagp);
  k_prepcvt<<<16, NTHREADS, 0, stream>>>(pw_w, pwbb, 4096, flagp);
  k_prepcvt<<<18, NTHREADS, 0, stream>>>(x_proj_w, xpwb, 4608, flagp);
  k_wcomb<<<32, NTHREADS, 0, stream>>>(proj_w, out_proj_w, wcombb, flagp);

  k_gemm_conv<32, 40><<<33 * 32, NTHREADS, 0, stream>>>(P1, W1b, c1raw, acc_in1);
  k_finalize<<<1, 64, 0, stream>>>(acc_in1, in1_g, in1_b, ss_in1, 1.0f / 135168.0f, flagp);
  k_normpad<<<35 * 66, NTHREADS, 0, stream>>>(c1raw, ss_in1, P2);

  k_gemm_conv<64, 88><<<34 * 32, NTHREADS, 0, stream>>>(P2, W2b, c2raw, acc_in2);
  k_finalize<<<1, 64, 0, stream>>>(acc_in2, in2_g, in2_b, ss_in2, 1.0f / 139264.0f, flagp);
  k_hslice_cl<<<2048, NTHREADS, 0, stream>>>(c2raw, ss_in2, hcl, d_out, flagp);

  k_dwpw_mfma<<<2048, NTHREADS, 0, stream>>>(hcl, dw_w, pwbb, pre2, acc_inr, flagp);
  k_finalize<<<1, 64, 0, stream>>>(acc_inr, inr_g, inr_b, ss_inr, 1.0f / 131072.0f, flagp);
  k_x2ln_cl<<<512, NTHREADS, 0, stream>>>(hcl, pre2, ss_inr, ln_g, ln_b, seq, flagp);

  k_inproj_mfma<<<2048, NTHREADS, 0, stream>>>(seq, inwb, x_in, zgb);
  k_conv1d_ip<<<2048, NTHREADS, 0, stream>>>(x_in, conv1d_w, conv1d_b, flagp);
  k_xproj_mfma<<<512, NTHREADS, 0, stream>>>(x_in, xpwb, dtinf, BCf);
  k_scan<<<2048, NTHREADS, 0, stream>>>(dtinf, BCf, x_in, zgb, dt_proj_w, dt_proj_b, A_log, D_p, flagp);
  k_outproj_mfma<<<512, NTHREADS, 0, stream>>>(x_in, wcombb, proj_b, s2, acc_pn, flagp);

  k_finalize<<<1, 64, 0, stream>>>(acc_pn, pn_g, pn_b, ss_pn, 1.0f / 131072.0f, flagp);
  k_final<<<2048, NTHREADS, 0, stream>>>(s2, d_out, ss_pn, flagp);
}

// Round 8
// 515.982 us; speedup vs baseline: 1.3529x; 1.0250x over previous
//
#include <hip/hip_runtime.h>
#include <hip/hip_bf16.h>

// Hybrid decoder block, MFMA everywhere GEMM-shaped, channels-last internals.
// row convention: r = z*4096 + n, n = y*64+x.
#define NTHREADS 256

typedef __attribute__((ext_vector_type(8))) short bs8_t;   // 8 bf16 (4 VGPRs)
typedef __attribute__((ext_vector_type(4))) float f4_t;    // 4 fp32 acc

__device__ __forceinline__ float bf2f(__hip_bfloat16 v) { return __bfloat162float(v); }
__device__ __forceinline__ __hip_bfloat16 f2bf(float v) { return __float2bfloat16(v); }
__device__ __forceinline__ float b2f_lo(unsigned int p) { return __uint_as_float(p << 16); }
__device__ __forceinline__ float b2f_hi(unsigned int p) { return __uint_as_float(p & 0xffff0000u); }
__device__ __forceinline__ float sigm(float x) { return 1.f / (1.f + __expf(-x)); }
__device__ __forceinline__ float leaky(float x) { return x > 0.f ? x : 0.01f * x; }
__device__ __forceinline__ float sane(float x) { return fminf(fmaxf(x, -1e9f), 1e9f); }
__device__ __forceinline__ unsigned packbf(float a, float b) {
  union { __hip_bfloat16 h[2]; unsigned u; } cv;
  cv.h[0] = f2bf(a); cv.h[1] = f2bf(b);
  return cv.u;
}
__device__ __forceinline__ float ldf(const void* p, long i, int f) {
  return f ? ((const float*)p)[i] : bf2f(((const __hip_bfloat16*)p)[i]);
}
// single-instruction 2^x (v_exp_f32); gfx9 trans ops are HW-interlocked.
__device__ __forceinline__ float exp2_fast(float x) {
  float r;
  asm("v_exp_f32 %0, %1" : "=v"(r) : "v"(x));
  return r;
}

// ---------------- dtype detector ----------------
__global__ void k_detect(const void* xp, int* flag) {
  __shared__ int cnt[NTHREADS];
  const __hip_bfloat16* h = (const __hip_bfloat16*)xp;
  int t = threadIdx.x;
  int c = 0;
  for (int j = 0; j < 8; j++) {
    float v = fabsf(bf2f(h[(t * 8 + j) * 2]));
    if (v > 1e-12f && v < 1e12f) c++;
  }
  cnt[t] = c;
  __syncthreads();
  for (int s = 128; s > 0; s >>= 1) {
    if (t < s) cnt[t] += cnt[t + s];
    __syncthreads();
  }
  if (t == 0) *flag = (cnt[0] > 1433) ? 0 : 1;
}

// generic converter: out[i] = bf16(in[i])
__global__ void k_prepcvt(const void* __restrict__ in, __hip_bfloat16* __restrict__ out,
                          int n, const int* __restrict__ flagp) {
  int f = *flagp;
  int gid = blockIdx.x * NTHREADS + threadIdx.x;
  if (gid < n) out[gid] = f2bf(ldf(in, gid, f));
}

// ---------------- pad1: x (ci-first) -> P1[z'(34)][y'(66)][x'(66)][32] bf16 ----------------
__global__ __launch_bounds__(NTHREADS) void k_pad1(const void* __restrict__ x,
                                                   __hip_bfloat16* __restrict__ P1,
                                                   const int* __restrict__ flagp) {
  __shared__ float tile[64 * 33];
  int f = *flagp;
  int zp = blockIdx.x / 66, yp = blockIdx.x % 66;
  long rowbase = ((long)zp * 66 + yp) * 66 * 32;
  int t = threadIdx.x;
  if (zp == 0 || zp == 33 || yp == 0 || yp == 65) {
    for (int i = t; i < 2112; i += NTHREADS) P1[rowbase + i] = f2bf(0.f);
    return;
  }
  int z = zp - 1, y = yp - 1;
#pragma unroll
  for (int j = 0; j < 8; j++) {
    int idx = t + j * NTHREADS;
    int ci = idx >> 6, xx = idx & 63;
    tile[xx * 33 + ci] = ldf(x, (long)(ci * 32 + z) * 4096 + y * 64 + xx, f);
  }
  __syncthreads();
#pragma unroll
  for (int j = 0; j < 8; j++) {
    int idx = t + j * NTHREADS;
    int xx = idx >> 5, ci = idx & 31;
    P1[rowbase + (xx + 1) * 32 + ci] = f2bf(tile[xx * 33 + ci]);
  }
  if (t < 32) P1[rowbase + t] = f2bf(0.f);
  else if (t < 64) P1[rowbase + 65 * 32 + (t - 32)] = f2bf(0.f);
}

// ---------------- weight reorg: cw (co,ci,2,3,3) -> W[s][co][ci] bf16 ----------------
__global__ void k_prepw(const void* __restrict__ cw, __hip_bfloat16* __restrict__ W,
                        int CI, const int* __restrict__ flagp) {
  int f = *flagp;
  int gid = blockIdx.x * NTHREADS + threadIdx.x;
  int s = gid / (64 * CI);
  int rem = gid % (64 * CI);
  int co = rem / CI, ci = rem % CI;
  W[gid] = f2bf(ldf(cw, (long)(co * CI + ci) * 18 + s, f));
}

// ---------------- MFMA implicit-GEMM conv + fused per-channel stats ----------------
// x-split: each block computes a 32-wide x half (xb = 0 or 32) -> 2x blocks.
// W staging vectorized: uint4 (8 ushorts) per load; row byte-strides (CIP*2)
// are multiples of 16 for CIP in {40, 88}.
template <int CI, int CIP>
__global__ __launch_bounds__(NTHREADS) void k_gemm_conv(const __hip_bfloat16* __restrict__ Pb,
                                                        const __hip_bfloat16* __restrict__ Wb,
                                                        __hip_bfloat16* __restrict__ out,
                                                        float* __restrict__ gacc) {
  __shared__ unsigned short Wl[3 * 64 * CIP];
  __shared__ float sred[256], qred[256];
  const unsigned short* P = (const unsigned short*)Pb;
  const unsigned short* W = (const unsigned short*)Wb;
  int t = threadIdx.x;
  int wv = t >> 6, lane = t & 63;
  int m = lane & 15, quad = lane >> 4;
  int zo  = blockIdx.x >> 5;
  int rem = blockIdx.x & 31;
  int y   = ((rem >> 1) << 2) + wv;
  int xb  = (rem & 1) << 5;
  f4_t zero4 = {0.f, 0.f, 0.f, 0.f};
  f4_t acc[2][4];
#pragma unroll
  for (int mt = 0; mt < 2; mt++)
#pragma unroll
    for (int nt = 0; nt < 4; nt++) acc[mt][nt] = zero4;

  const int NV = 3 * 64 * CI / 8;  // uint4 count per stage
  for (int kz = 0; kz < 2; kz++) {
    for (int ky = 0; ky < 3; ky++) {
      __syncthreads();
      int s0 = (kz * 3 + ky) * 3;
      const uint4* wsrc4 = (const uint4*)(W + (long)s0 * 64 * CI);
      for (int i4 = t; i4 < NV; i4 += NTHREADS) {
        int idx = i4 * 8;
        int kx = idx / (64 * CI), rem2 = idx % (64 * CI);
        int co = rem2 / CI, g = (rem2 % CI) >> 3;
        *(uint4*)&Wl[(kx * 64 + co) * CIP + g * 8] = wsrc4[i4];
      }
      __syncthreads();
      int pz = zo + kz, py = y + ky;
      const unsigned short* prow = P + ((long)(pz * 66 + py) * 66) * CI;
#pragma unroll
      for (int kx = 0; kx < 3; kx++) {
#pragma unroll
        for (int ch = 0; ch < CI / 32; ch++) {
          int kof = kx * CI + ch * 32 + quad * 8;
          bs8_t a0 = *(const bs8_t*)(prow + (xb + 0 * 16 + m) * CI + kof);
          bs8_t a1 = *(const bs8_t*)(prow + (xb + 1 * 16 + m) * CI + kof);
#pragma unroll
          for (int nt = 0; nt < 4; nt++) {
            bs8_t b = *(const bs8_t*)&Wl[(kx * 64 + nt * 16 + m) * CIP + ch * 32 + quad * 8];
            acc[0][nt] = __builtin_amdgcn_mfma_f32_16x16x32_bf16(a0, b, acc[0][nt], 0, 0, 0);
            acc[1][nt] = __builtin_amdgcn_mfma_f32_16x16x32_bf16(a1, b, acc[1][nt], 0, 0, 0);
          }
        }
      }
    }
  }
  long obase = ((long)(zo * 64 + y) * 64) * 64;
  float psum[4], pq[4];
#pragma unroll
  for (int nt = 0; nt < 4; nt++) {
    int co = nt * 16 + m;
    float s = 0.f, q = 0.f;
#pragma unroll
    for (int mt = 0; mt < 2; mt++)
#pragma unroll
      for (int rg = 0; rg < 4; rg++) {
        float v = acc[mt][nt][rg];
        int xx = xb + mt * 16 + quad * 4 + rg;
        out[obase + xx * 64 + co] = f2bf(v);
        s += v;
        q += v * v;
      }
    psum[nt] = s;
    pq[nt] = q;
  }
#pragma unroll
  for (int nt = 0; nt < 4; nt++) {
    psum[nt] += __shfl_xor(psum[nt], 16, 64);
    psum[nt] += __shfl_xor(psum[nt], 32, 64);
    pq[nt]   += __shfl_xor(pq[nt], 16, 64);
    pq[nt]   += __shfl_xor(pq[nt], 32, 64);
  }
  if (quad == 0) {
#pragma unroll
    for (int nt = 0; nt < 4; nt++) {
      sred[wv * 64 + nt * 16 + m] = psum[nt];
      qred[wv * 64 + nt * 16 + m] = pq[nt];
    }
  }
  __syncthreads();
  if (t < 64) {
    atomicAdd(&gacc[t], sred[t] + sred[64 + t] + sred[128 + t] + sred[192 + t]);
    atomicAdd(&gacc[64 + t], qred[t] + qred[64 + t] + qred[128 + t] + qred[192 + t]);
  }
}

__global__ void k_finalize(const float* __restrict__ acc, const void* __restrict__ g,
                           const void* __restrict__ b, float* __restrict__ ss, float invN,
                           const int* __restrict__ flagp) {
  int f = *flagp;
  int t = threadIdx.x;  // 64
  float mean = acc[t] * invN;
  float var  = acc[64 + t] * invN - mean * mean;
  float rstd = rsqrtf(fmaxf(var, 0.f) + 1e-5f);
  float sc   = ldf(g, t, f) * rstd;
  ss[t]      = sc;
  ss[64 + t] = ldf(b, t, f) - mean * sc;
}

// ---------------- normpad: c1raw -> norm+leaky -> P2[35][66][66][64] ----------------
__global__ __launch_bounds__(NTHREADS) void k_normpad(const __hip_bfloat16* __restrict__ in,
                                                      const float* __restrict__ ss,
                                                      __hip_bfloat16* __restrict__ P2) {
  int zp = blockIdx.x / 66, yp = blockIdx.x % 66;
  long rowbase = ((long)zp * 66 + yp) * 66 * 64;
  int t = threadIdx.x;
  if (zp == 0 || zp == 34 || yp == 0 || yp == 65) {
    for (int i = t; i < 4224; i += NTHREADS) P2[rowbase + i] = f2bf(0.f);
    return;
  }
  int z = zp - 1, y = yp - 1;
#pragma unroll
  for (int j = 0; j < 16; j++) {
    int idx = t + j * NTHREADS;
    int xx = idx >> 6, co = idx & 63;
    float v = bf2f(in[((long)(z * 64 + y) * 64 + xx) * 64 + co]) * ss[co] + ss[64 + co];
    P2[rowbase + (xx + 1) * 64 + co] = f2bf(leaky(v));
  }
  if (t < 64) P2[rowbase + t] = f2bf(0.f);
  else if (t < 128) P2[rowbase + 65 * 64 + (t - 64)] = f2bf(0.f);
}

// ---------------- hslice: c2raw -> norm+leaky -> hcl + residual d_out[c][r] ----------------
__global__ __launch_bounds__(NTHREADS) void k_hslice_cl(const __hip_bfloat16* __restrict__ in,
                                                        const float* __restrict__ ss,
                                                        __hip_bfloat16* __restrict__ hcl,
                                                        void* __restrict__ resid,
                                                        const int* __restrict__ flagp) {
  __shared__ float tile[64 * 65];
  int f = *flagp;
  int z = blockIdx.x >> 6, y = blockIdx.x & 63;
  long r0 = (long)z * 4096 + y * 64;
  int t = threadIdx.x;
#pragma unroll
  for (int j = 0; j < 16; j++) {
    int idx = t + j * NTHREADS;
    int xx = idx >> 6, co = idx & 63;
    float v = leaky(bf2f(in[(r0 + xx) * 64 + co]) * ss[co] + ss[64 + co]);
    hcl[(r0 + xx) * 64 + co] = f2bf(v);
    tile[xx * 65 + co] = v;
  }
  __syncthreads();
#pragma unroll
  for (int j = 0; j < 16; j++) {
    int idx = t + j * NTHREADS;
    int co = idx >> 6, xx = idx & 63;
    long off = (long)co * 131072 + r0 + xx;
    if (f) ((float*)resid)[off] = tile[xx * 65 + co];
    else   ((__hip_bfloat16*)resid)[off] = f2bf(tile[xx * 65 + co]);
  }
}

// ---------------- dw3x3 + pw1x1 (MFMA pointwise) + inr stats ----------------
__global__ __launch_bounds__(NTHREADS) void k_dwpw_mfma(const __hip_bfloat16* __restrict__ hcl,
                                                        const void* __restrict__ dwb,
                                                        const __hip_bfloat16* __restrict__ pwbb,
                                                        __hip_bfloat16* __restrict__ out,
                                                        float* __restrict__ acc,
                                                        const int* __restrict__ flagp) {
  __shared__ unsigned short hl[3 * 64 * 64];
  __shared__ unsigned short dwt[64 * 72];
  __shared__ unsigned short pwl[64 * 72];
  __shared__ float dwl[576];
  __shared__ float sred[256], qred[256];
  int f = *flagp;
  int t = threadIdx.x;
  int z = blockIdx.x >> 6, y = blockIdx.x & 63;
  for (int i = t; i < 576; i += NTHREADS) dwl[i] = ldf(dwb, i, f);
  {
    const uint4* ps4 = (const uint4*)pwbb;
#pragma unroll
    for (int j = 0; j < 2; j++) {
      int i = t + j * NTHREADS;          // i in [0,512): uint4 index, 8 ushorts
      int row = i >> 3, g = i & 7;
      *(uint4*)&pwl[row * 72 + g * 8] = ps4[i];
    }
  }
  {
    const unsigned short* hsrc = (const unsigned short*)hcl;
    uint4* hl4 = (uint4*)hl;
#pragma unroll
    for (int j = 0; j < 6; j++) {
      int i = t + j * NTHREADS;          // i in [0,1536): uint4 index
      int dy = i / 512, rem = i % 512;   // rem in uint4 units within the row-slab
      int ry = y - 1 + dy;
      uint4 v = make_uint4(0u, 0u, 0u, 0u);
      if ((unsigned)ry < 64u)
        v = *(const uint4*)(hsrc + ((long)z * 4096 + ry * 64) * 64 + rem * 8);
      hl4[i] = v;
    }
  }
  __syncthreads();
  const unsigned* hl32 = (const unsigned*)hl;
  unsigned* dwt32 = (unsigned*)dwt;
#pragma unroll
  for (int j = 0; j < 8; j++) {
    int idx = t + j * NTHREADS;
    int xx = idx >> 5, cp = idx & 31;
    float a0 = 0.f, a1 = 0.f;
#pragma unroll
    for (int dy = 0; dy < 3; dy++)
#pragma unroll
      for (int dx = 0; dx < 3; dx++) {
        int xv = xx - 1 + dx;
        if ((unsigned)xv < 64u) {
          unsigned hv = hl32[(dy * 64 + xv) * 32 + cp];
          a0 = fmaf(b2f_lo(hv), dwl[(cp * 2) * 9 + dy * 3 + dx], a0);
          a1 = fmaf(b2f_hi(hv), dwl[(cp * 2 + 1) * 9 + dy * 3 + dx], a1);
        }
      }
    dwt32[xx * 36 + cp] = packbf(a0, a1);
  }
  __syncthreads();
  int wv = t >> 6, lane = t & 63;
  int m = lane & 15, quad = lane >> 4;
  f4_t zero4 = {0.f, 0.f, 0.f, 0.f};
  f4_t acc4[4];
#pragma unroll
  for (int nt = 0; nt < 4; nt++) acc4[nt] = zero4;
#pragma unroll
  for (int ch = 0; ch < 2; ch++) {
    bs8_t a = *(const bs8_t*)&dwt[(wv * 16 + m) * 72 + ch * 32 + quad * 8];
#pragma unroll
    for (int nt = 0; nt < 4; nt++) {
      bs8_t b = *(const bs8_t*)&pwl[(nt * 16 + m) * 72 + ch * 32 + quad * 8];
      acc4[nt] = __builtin_amdgcn_mfma_f32_16x16x32_bf16(a, b, acc4[nt], 0, 0, 0);
    }
  }
  long obase = ((long)z * 4096 + y * 64) * 64;
  float psum[4], pq[4];
#pragma unroll
  for (int nt = 0; nt < 4; nt++) {
    float s = 0.f, q = 0.f;
#pragma unroll
    for (int rg = 0; rg < 4; rg++) {
      float v = acc4[nt][rg];
      int xx = wv * 16 + quad * 4 + rg;
      out[obase + xx * 64 + nt * 16 + m] = f2bf(v);
      s += v;
      q += v * v;
    }
    psum[nt] = s;
    pq[nt] = q;
  }
#pragma unroll
  for (int nt = 0; nt < 4; nt++) {
    psum[nt] += __shfl_xor(psum[nt], 16, 64);
    psum[nt] += __shfl_xor(psum[nt], 32, 64);
    pq[nt]   += __shfl_xor(pq[nt], 16, 64);
    pq[nt]   += __shfl_xor(pq[nt], 32, 64);
  }
  if (quad == 0) {
#pragma unroll
    for (int nt = 0; nt < 4; nt++) {
      sred[wv * 64 + nt * 16 + m] = psum[nt];
      qred[wv * 64 + nt * 16 + m] = pq[nt];
    }
  }
  __syncthreads();
  if (t < 64) {
    atomicAdd(&acc[t], sred[t] + sred[64 + t] + sred[128 + t] + sred[192 + t]);
    atomicAdd(&acc[64 + t], qred[t] + qred[64 + t] + qred[128 + t] + qred[192 + t]);
  }
}

// ---------------- x2 = h + silu(norm(pre2)); LayerNorm C=64 -> seq bf16 ----------------
__global__ __launch_bounds__(NTHREADS) void k_x2ln_cl(const __hip_bfloat16* __restrict__ hcl,
                                                      const __hip_bfloat16* __restrict__ p2,
                                                      const float* __restrict__ ssr,
                                                      const void* __restrict__ lng,
                                                      const void* __restrict__ lnb,
                                                      __hip_bfloat16* __restrict__ out,
                                                      const int* __restrict__ flagp) {
  __shared__ float sc[64], sh[64], sg[64], sb[64];
  int f = *flagp;
  int t = threadIdx.x;
  if (t < 64) {
    sc[t] = ssr[t];
    sh[t] = ssr[64 + t];
    sg[t] = ldf(lng, t, f);
    sb[t] = ldf(lnb, t, f);
  }
  __syncthreads();
  long r = (long)blockIdx.x * NTHREADS + t;
  const uint4* hp = (const uint4*)(hcl + r * 64);
  const uint4* pp = (const uint4*)(p2 + r * 64);
  float v[64];
  float s1 = 0.f;
#pragma unroll
  for (int q = 0; q < 8; q++) {
    uint4 hu = hp[q], pu = pp[q];
    float hv[8] = {b2f_lo(hu.x), b2f_hi(hu.x), b2f_lo(hu.y), b2f_hi(hu.y),
                   b2f_lo(hu.z), b2f_hi(hu.z), b2f_lo(hu.w), b2f_hi(hu.w)};
    float pv[8] = {b2f_lo(pu.x), b2f_hi(pu.x), b2f_lo(pu.y), b2f_hi(pu.y),
                   b2f_lo(pu.z), b2f_hi(pu.z), b2f_lo(pu.w), b2f_hi(pu.w)};
#pragma unroll
    for (int i = 0; i < 8; i++) {
      int c = q * 8 + i;
      float pn = sc[c] * pv[i] + sh[c];
      float x2 = hv[i] + pn * sigm(pn);
      v[c] = x2;
      s1 += x2;
    }
  }
  float m = s1 * (1.f / 64.f);
  float s2 = 0.f;
#pragma unroll
  for (int c = 0; c < 64; c++) {
    float d = v[c] - m;
    s2 += d * d;
  }
  float rstd = rsqrtf(s2 * (1.f / 64.f) + 1e-5f);
  uint4* o4 = (uint4*)(out + r * 64);
#pragma unroll
  for (int q = 0; q < 8; q++) {
    int c = q * 8;
    uint4 o;
    o.x = packbf((v[c + 0] - m) * rstd * sg[c + 0] + sb[c + 0],
                 (v[c + 1] - m) * rstd * sg[c + 1] + sb[c + 1]);
    o.y = packbf((v[c + 2] - m) * rstd * sg[c + 2] + sb[c + 2],
                 (v[c + 3] - m) * rstd * sg[c + 3] + sb[c + 3]);
    o.z = packbf((v[c + 4] - m) * rstd * sg[c + 4] + sb[c + 4],
                 (v[c + 5] - m) * rstd * sg[c + 5] + sb[c + 5]);
    o.w = packbf((v[c + 6] - m) * rstd * sg[c + 6] + sb[c + 6],
                 (v[c + 7] - m) * rstd * sg[c + 7] + sb[c + 7]);
    o4[q] = o;
  }
}

// ---------------- in_proj MFMA ----------------
__global__ __launch_bounds__(NTHREADS) void k_inproj_mfma(const __hip_bfloat16* __restrict__ seq,
                                                          const __hip_bfloat16* __restrict__ Wbf,
                                                          __hip_bfloat16* __restrict__ x_in,
                                                          __hip_bfloat16* __restrict__ zg) {
  __shared__ unsigned short Wl[256 * 72];
  const uint4* ws4 = (const uint4*)Wbf;
  int t = threadIdx.x;
#pragma unroll
  for (int j = 0; j < 8; j++) {
    int i4 = t + j * NTHREADS;           // i4 in [0,2048): 8 ushorts each
    int row = i4 >> 3, g = i4 & 7;
    *(uint4*)&Wl[row * 72 + g * 8] = ws4[i4];
  }
  __syncthreads();
  int wv = t >> 6, lane = t & 63;
  int m = lane & 15, quad = lane >> 4;
  long m0 = (long)blockIdx.x * 64;
  int n0 = wv * 64;
  f4_t zero4 = {0.f, 0.f, 0.f, 0.f};
  f4_t acc[4][4];
#pragma unroll
  for (int mt = 0; mt < 4; mt++)
#pragma unroll
    for (int nt = 0; nt < 4; nt++) acc[mt][nt] = zero4;
  const unsigned short* sp = (const unsigned short*)seq;
#pragma unroll
  for (int ch = 0; ch < 2; ch++) {
    int kof = ch * 32 + quad * 8;
    bs8_t a0 = *(const bs8_t*)(sp + (m0 + 0 * 16 + m) * 64 + kof);
    bs8_t a1 = *(const bs8_t*)(sp + (m0 + 1 * 16 + m) * 64 + kof);
    bs8_t a2 = *(const bs8_t*)(sp + (m0 + 2 * 16 + m) * 64 + kof);
    bs8_t a3 = *(const bs8_t*)(sp + (m0 + 3 * 16 + m) * 64 + kof);
#pragma unroll
    for (int nt = 0; nt < 4; nt++) {
      bs8_t b = *(const bs8_t*)&Wl[(n0 + nt * 16 + m) * 72 + kof];
      acc[0][nt] = __builtin_amdgcn_mfma_f32_16x16x32_bf16(a0, b, acc[0][nt], 0, 0, 0);
      acc[1][nt] = __builtin_amdgcn_mfma_f32_16x16x32_bf16(a1, b, acc[1][nt], 0, 0, 0);
      acc[2][nt] = __builtin_amdgcn_mfma_f32_16x16x32_bf16(a2, b, acc[2][nt], 0, 0, 0);
      acc[3][nt] = __builtin_amdgcn_mfma_f32_16x16x32_bf16(a3, b, acc[3][nt], 0, 0, 0);
    }
  }
  __hip_bfloat16* obuf = (n0 < 128) ? x_in : zg;
  int cbase = (n0 < 128) ? n0 : (n0 - 128);
#pragma unroll
  for (int mt = 0; mt < 4; mt++)
#pragma unroll
    for (int nt = 0; nt < 4; nt++) {
      int col = cbase + nt * 16 + m;
#pragma unroll
      for (int rg = 0; rg < 4; rg++) {
        long row = m0 + mt * 16 + quad * 4 + rg;
        obuf[row * 128 + col] = f2bf(acc[mt][nt][rg]);
      }
    }
}

// ---------------- causal depthwise conv1d, in place ----------------
__global__ __launch_bounds__(NTHREADS) void k_conv1d_ip(__hip_bfloat16* xio,
                                                        const void* __restrict__ wb,
                                                        const void* __restrict__ bb,
                                                        const int* __restrict__ flagp) {
  int f = *flagp;
  int gid = blockIdx.x * NTHREADS + threadIdx.x;
  int d = gid & 127, nl = gid >> 7;
  float w0 = ldf(wb, d * 4 + 0, f), w1 = ldf(wb, d * 4 + 1, f);
  float w2 = ldf(wb, d * 4 + 2, f), w3 = ldf(wb, d * 4 + 3, f);
  float bias = ldf(bb, d, f);
  const size_t stride = 4096u * 128u;
  size_t off0 = (size_t)nl * 128 + d;
  float xv[32];
#pragma unroll
  for (int z = 0; z < 32; z++) xv[z] = bf2f(xio[off0 + (size_t)z * stride]);
  float h0 = 0.f, h1 = 0.f, h2 = 0.f;
#pragma unroll
  for (int z = 0; z < 32; z++) {
    float cur = xv[z];
    float a = bias;
    a = fmaf(h0, w0, a);
    a = fmaf(h1, w1, a);
    a = fmaf(h2, w2, a);
    a = fmaf(cur, w3, a);
    xv[z] = a * sigm(a);
    h0 = h1; h1 = h2; h2 = cur;
  }
#pragma unroll
  for (int z = 0; z < 32; z++) xio[off0 + (size_t)z * stride] = f2bf(xv[z]);
}

// ---------------- x_proj MFMA: (131072,128) x (36->48 pad,128)^T ----------------
// outputs: dtin[r][4] f32 (cols 0..3) and BC[r][32] f32 (cols 4..35)
__global__ __launch_bounds__(NTHREADS) void k_xproj_mfma(const __hip_bfloat16* __restrict__ A,
                                                         const __hip_bfloat16* __restrict__ Wbf,
                                                         float* __restrict__ dtin,
                                                         float* __restrict__ BC) {
  __shared__ unsigned short Wl[48 * 136];
  const uint4* ws4 = (const uint4*)Wbf;   // (36,128) row-major
  int t = threadIdx.x;
#pragma unroll
  for (int j = 0; j < 3; j++) {
    int i4 = t + j * NTHREADS;           // i4 in [0,768): 48 rows x 16 uint4
    int row = i4 >> 4, g = i4 & 15;
    uint4 v = make_uint4(0u, 0u, 0u, 0u);
    if (row < 36) v = ws4[row * 16 + g];
    *(uint4*)&Wl[row * 136 + g * 8] = v;
  }
  __syncthreads();
  int wv = t >> 6, lane = t & 63;
  int m = lane & 15, quad = lane >> 4;
  long m0 = (long)blockIdx.x * 256 + wv * 64;
  f4_t zero4 = {0.f, 0.f, 0.f, 0.f};
  f4_t acc[4][3];
#pragma unroll
  for (int mt = 0; mt < 4; mt++)
#pragma unroll
    for (int nt = 0; nt < 3; nt++) acc[mt][nt] = zero4;
  const unsigned short* ap = (const unsigned short*)A;
#pragma unroll
  for (int ch = 0; ch < 4; ch++) {
    int kof = ch * 32 + quad * 8;
    bs8_t a0 = *(const bs8_t*)(ap + (m0 + 0 * 16 + m) * 128 + kof);
    bs8_t a1 = *(const bs8_t*)(ap + (m0 + 1 * 16 + m) * 128 + kof);
    bs8_t a2 = *(const bs8_t*)(ap + (m0 + 2 * 16 + m) * 128 + kof);
    bs8_t a3 = *(const bs8_t*)(ap + (m0 + 3 * 16 + m) * 128 + kof);
#pragma unroll
    for (int nt = 0; nt < 3; nt++) {
      bs8_t b = *(const bs8_t*)&Wl[(nt * 16 + m) * 136 + kof];
      acc[0][nt] = __builtin_amdgcn_mfma_f32_16x16x32_bf16(a0, b, acc[0][nt], 0, 0, 0);
      acc[1][nt] = __builtin_amdgcn_mfma_f32_16x16x32_bf16(a1, b, acc[1][nt], 0, 0, 0);
      acc[2][nt] = __builtin_amdgcn_mfma_f32_16x16x32_bf16(a2, b, acc[2][nt], 0, 0, 0);
      acc[3][nt] = __builtin_amdgcn_mfma_f32_16x16x32_bf16(a3, b, acc[3][nt], 0, 0, 0);
    }
  }
#pragma unroll
  for (int mt = 0; mt < 4; mt++)
#pragma unroll
    for (int nt = 0; nt < 3; nt++) {
      int col = nt * 16 + m;
#pragma unroll
      for (int rg = 0; rg < 4; rg++) {
        long row = m0 + mt * 16 + quad * 4 + rg;
        float v = acc[mt][nt][rg];
        if (col < 4) dtin[row * 4 + col] = v;
        else if (col < 36) BC[row * 32 + (col - 4)] = v;
      }
    }
}

// ---------------- selective scan ----------------
// geo fast path: BC/dt rows are WAVE-UNIFORM (n = gid>>7) -> readfirstlane
// routes them to scalar s_load; per-lane u/zv prefetched 1 deep.
__global__ __launch_bounds__(NTHREADS) void k_scan(const float* __restrict__ dtin,
                                                   const float* __restrict__ BC,
                                                   __hip_bfloat16* __restrict__ uy,
                                                   const __hip_bfloat16* __restrict__ zg,
                                                   const void* __restrict__ dtw,
                                                   const void* __restrict__ dtb,
                                                   const void* __restrict__ Alog,
                                                   const void* __restrict__ Dp,
                                                   const int* __restrict__ flagp) {
  int f = *flagp;
  int gid = blockIdx.x * NTHREADS + threadIdx.x;
  int d = gid & 127, n = gid >> 7;
  // A2[s] = -exp(A_log[d][s]) * log2(e): exp(dt*A) == exp2(dt*A2)
  float A2[16];
#pragma unroll
  for (int s = 0; s < 16; s++)
    A2[s] = -__expf(fminf(ldf(Alog, d * 16 + s, f), 60.f)) * 1.44269504088896f;
  float W0 = ldf(dtw, d * 4 + 0, f), W1 = ldf(dtw, d * 4 + 1, f);
  float W2 = ldf(dtw, d * 4 + 2, f), W3 = ldf(dtw, d * 4 + 3, f);
  float bias = ldf(dtb, d, f);
  float Dv = ldf(Dp, d, f);
  float a0 = A2[0];
  int geo = 1;
#pragma unroll
  for (int s = 1; s < 16; s++)
    geo &= (fabsf(A2[s] - (float)(s + 1) * a0) <= 1e-4f * fabsf(A2[s])) ? 1 : 0;
  geo = __all(geo);
  float st[16];
#pragma unroll
  for (int s = 0; s < 16; s++) st[s] = 0.f;
  if (geo) {
    int nu_ = __builtin_amdgcn_readfirstlane(n);   // wave-uniform -> scalar addr
    const float4* bp0 = (const float4*)(BC + (size_t)nu_ * 32);
    const float4* dp0 = (const float4*)(dtin + (size_t)nu_ * 4);
    const __hip_bfloat16* up0 = uy + (size_t)n * 128 + d;
    const __hip_bfloat16* zp0 = zg + (size_t)n * 128 + d;
    __hip_bfloat16* uq = uy + (size_t)n * 128 + d;
    const size_t ustep = 4096u * 128u;
    // prologue: loads for z=0
    float4 b0 = bp0[0], b1 = bp0[1], b2 = bp0[2], b3 = bp0[3];
    float4 c0 = bp0[4], c1 = bp0[5], c2 = bp0[6], c3 = bp0[7];
    float4 dt4 = dp0[0];
    float u  = sane(bf2f(*up0));
    float zv = sane(bf2f(*zp0));
#pragma unroll 2
    for (int z = 0; z < 32; z++) {
      // prefetch z+1 (z=31 re-reads z=31; values unused)
      int zn = (z < 31) ? z + 1 : 31;
      const float4* bpn = bp0 + (size_t)zn * 32768u;
      float4 nb0 = bpn[0], nb1 = bpn[1], nb2 = bpn[2], nb3 = bpn[3];
      float4 nc0 = bpn[4], nc1 = bpn[5], nc2 = bpn[6], nc3 = bpn[7];
      float4 ndt = dp0[(size_t)zn * 4096u];
      float nu  = sane(bf2f(up0[(size_t)zn * ustep]));
      float nzv = sane(bf2f(zp0[(size_t)zn * ustep]));
      // compute current z
      float v = bias;
      v = fmaf(dt4.x, W0, v);
      v = fmaf(dt4.y, W1, v);
      v = fmaf(dt4.z, W2, v);
      v = fmaf(dt4.w, W3, v);
      float dtv = v > 20.f ? v : __logf(1.f + __expf(v));
      dtv = fminf(fmaxf(dtv, 0.f), 60.f);
      float du = dtv * u;
      float e1 = exp2_fast(dtv * a0);
      float e2 = e1 * e1;
      float es[16];
      es[0] = e1; es[1] = e2;
#pragma unroll
      for (int s = 2; s < 16; s++) es[s] = es[s - 2] * e2;
      float B[16] = {b0.x, b0.y, b0.z, b0.w, b1.x, b1.y, b1.z, b1.w,
                     b2.x, b2.y, b2.z, b2.w, b3.x, b3.y, b3.z, b3.w};
      float C[16] = {c0.x, c0.y, c0.z, c0.w, c1.x, c1.y, c1.z, c1.w,
                     c2.x, c2.y, c2.z, c2.w, c3.x, c3.y, c3.z, c3.w};
#pragma unroll
      for (int s = 0; s < 16; s++) st[s] = fmaf(es[s], st[s], du * B[s]);
      float y0 = 0.f, y1 = 0.f, y2 = 0.f, y3 = 0.f;
#pragma unroll
      for (int s = 0; s < 16; s += 4) {
        y0 = fmaf(st[s + 0], C[s + 0], y0);
        y1 = fmaf(st[s + 1], C[s + 1], y1);
        y2 = fmaf(st[s + 2], C[s + 2], y2);
        y3 = fmaf(st[s + 3], C[s + 3], y3);
      }
      float y = (y0 + y1) + (y2 + y3);
      y = sane((y + Dv * u) * (zv * sigm(zv)));
      uq[(size_t)z * ustep] = f2bf(y);
      // rotate pipeline registers (scalar copies on the SALU pipe if uniform)
      b0 = nb0; b1 = nb1; b2 = nb2; b3 = nb3;
      c0 = nc0; c1 = nc1; c2 = nc2; c3 = nc3;
      dt4 = ndt; u = nu; zv = nzv;
    }
  } else {
#pragma unroll
    for (int s = 0; s < 16; s++) asm("" : "+v"(A2[s]));  // pin; forbid remat/AGPR
    for (int z = 0; z < 32; z++) {
      size_t r = (size_t)z * 4096 + n;
      const float4* bp = (const float4*)(BC + r * 32);
      float4 dt4 = *(const float4*)(dtin + r * 4);
      float4 b0 = bp[0], b1 = bp[1], b2 = bp[2], b3 = bp[3];
      float4 c0 = bp[4], c1 = bp[5], c2 = bp[6], c3 = bp[7];
      float u = sane(bf2f(uy[r * 128 + d]));
      float zv = sane(bf2f(zg[r * 128 + d]));
      float v = bias;
      v = fmaf(dt4.x, W0, v);
      v = fmaf(dt4.y, W1, v);
      v = fmaf(dt4.z, W2, v);
      v = fmaf(dt4.w, W3, v);
      float dtv = v > 20.f ? v : __logf(1.f + __expf(v));
      dtv = fminf(fmaxf(dtv, 0.f), 60.f);
      float du = dtv * u;
      float B[16] = {b0.x, b0.y, b0.z, b0.w, b1.x, b1.y, b1.z, b1.w,
                     b2.x, b2.y, b2.z, b2.w, b3.x, b3.y, b3.z, b3.w};
      float C[16] = {c0.x, c0.y, c0.z, c0.w, c1.x, c1.y, c1.z, c1.w,
                     c2.x, c2.y, c2.z, c2.w, c3.x, c3.y, c3.z, c3.w};
      float y = 0.f;
#pragma unroll
      for (int s = 0; s < 16; s++) {
        float e = exp2_fast(dtv * A2[s]);
        st[s] = fmaf(e, st[s], du * B[s]);
        y = fmaf(st[s], C[s], y);
      }
      y = sane((y + Dv * u) * (zv * sigm(zv)));
      uy[r * 128 + d] = f2bf(y);
    }
  }
}

// ---------------- W_comb = proj_w @ out_proj_w -> bf16 [o][d] ----------------
__global__ void k_wcomb(const void* __restrict__ pw, const void* __restrict__ opw,
                        __hip_bfloat16* __restrict__ wc, const int* __restrict__ flagp) {
  int f = *flagp;
  int gid = blockIdx.x * NTHREADS + threadIdx.x;
  int d = gid & 127, o = gid >> 7;
  float a = 0.f;
#pragma unroll
  for (int j = 0; j < 64; j++) a = fmaf(ldf(pw, o * 64 + j, f), ldf(opw, j * 128 + d, f), a);
  wc[(size_t)o * 128 + d] = f2bf(a);
}

// ---------------- out_proj+proj MFMA + fused pn stats ----------------
__global__ __launch_bounds__(NTHREADS) void k_outproj_mfma(const __hip_bfloat16* __restrict__ A,
                                                           const __hip_bfloat16* __restrict__ Wcb,
                                                           const void* __restrict__ bias,
                                                           __hip_bfloat16* __restrict__ out,
                                                           float* __restrict__ gacc,
                                                           const int* __restrict__ flagp) {
  __shared__ unsigned short Wl[64 * 136];
  __shared__ float bl[64];
  __shared__ float sred[256], qred[256];
  int f = *flagp;
  int t = threadIdx.x;
  const uint4* ws4 = (const uint4*)Wcb;
#pragma unroll
  for (int j = 0; j < 4; j++) {
    int i4 = t + j * NTHREADS;           // i4 in [0,1024): 64 rows x 16 uint4
    int row = i4 >> 4, g = i4 & 15;
    *(uint4*)&Wl[row * 136 + g * 8] = ws4[i4];
  }
  if (t < 64) bl[t] = ldf(bias, t, f);
  __syncthreads();
  int wv = t >> 6, lane = t & 63;
  int m = lane & 15, quad = lane >> 4;
  long m0 = (long)blockIdx.x * 256 + wv * 64;
  f4_t zero4 = {0.f, 0.f, 0.f, 0.f};
  f4_t acc[4][4];
#pragma unroll
  for (int mt = 0; mt < 4; mt++)
#pragma unroll
    for (int nt = 0; nt < 4; nt++) acc[mt][nt] = zero4;
  const unsigned short* ap = (const unsigned short*)A;
#pragma unroll
  for (int ch = 0; ch < 4; ch++) {
    int kof = ch * 32 + quad * 8;
    bs8_t a0 = *(const bs8_t*)(ap + (m0 + 0 * 16 + m) * 128 + kof);
    bs8_t a1 = *(const bs8_t*)(ap + (m0 + 1 * 16 + m) * 128 + kof);
    bs8_t a2 = *(const bs8_t*)(ap + (m0 + 2 * 16 + m) * 128 + kof);
    bs8_t a3 = *(const bs8_t*)(ap + (m0 + 3 * 16 + m) * 128 + kof);
#pragma unroll
    for (int nt = 0; nt < 4; nt++) {
      bs8_t b = *(const bs8_t*)&Wl[(nt * 16 + m) * 136 + kof];
      acc[0][nt] = __builtin_amdgcn_mfma_f32_16x16x32_bf16(a0, b, acc[0][nt], 0, 0, 0);
      acc[1][nt] = __builtin_amdgcn_mfma_f32_16x16x32_bf16(a1, b, acc[1][nt], 0, 0, 0);
      acc[2][nt] = __builtin_amdgcn_mfma_f32_16x16x32_bf16(a2, b, acc[2][nt], 0, 0, 0);
      acc[3][nt] = __builtin_amdgcn_mfma_f32_16x16x32_bf16(a3, b, acc[3][nt], 0, 0, 0);
    }
  }
  float psum[4], pq[4];
#pragma unroll
  for (int nt = 0; nt < 4; nt++) {
    int co = nt * 16 + m;
    float s = 0.f, q = 0.f;
#pragma unroll
    for (int mt = 0; mt < 4; mt++)
#pragma unroll
      for (int rg = 0; rg < 4; rg++) {
        float v = sane(acc[mt][nt][rg] + bl[co]);
        long row = m0 + mt * 16 + quad * 4 + rg;
        out[row * 64 + co] = f2bf(v);
        s += v;
        q += v * v;
      }
    psum[nt] = s;
    pq[nt] = q;
  }
#pragma unroll
  for (int nt = 0; nt < 4; nt++) {
    psum[nt] += __shfl_xor(psum[nt], 16, 64);
    psum[nt] += __shfl_xor(psum[nt], 32, 64);
    pq[nt]   += __shfl_xor(pq[nt], 16, 64);
    pq[nt]   += __shfl_xor(pq[nt], 32, 64);
  }
  if (quad == 0) {
#pragma unroll
    for (int nt = 0; nt < 4; nt++) {
      sred[wv * 64 + nt * 16 + m] = psum[nt];
      qred[wv * 64 + nt * 16 + m] = pq[nt];
    }
  }
  __syncthreads();
  if (t < 64) {
    atomicAdd(&gacc[t], sred[t] + sred[64 + t] + sred[128 + t] + sred[192 + t]);
    atomicAdd(&gacc[64 + t], qred[t] + qred[64 + t] + qred[128 + t] + qred[192 + t]);
  }
}

// ---------------- final ----------------
__global__ __launch_bounds__(NTHREADS) void k_final(const __hip_bfloat16* __restrict__ s2,
                                                    void* __restrict__ io,
                                                    const float* __restrict__ ss,
                                                    const int* __restrict__ flagp) {
  __shared__ float tile[64 * 65];
  __shared__ float sc[64], sh[64];
  int f = *flagp;
  int t = threadIdx.x;
  if (t < 64) {
    sc[t] = ss[t];
    sh[t] = ss[64 + t];
  }
  int z = blockIdx.x >> 6, n0 = (blockIdx.x & 63) << 6;
  size_t base = ((size_t)z * 4096 + n0) * 64;
  __syncthreads();
#pragma unroll
  for (int jj = 0; jj < 16; jj++) {
    int id = t + jj * NTHREADS;
    int i = id >> 6, c = id & 63;
    float v = sane(bf2f(s2[base + id]));
    tile[i * 65 + c] = sc[c] * v + sh[c];
  }
  __syncthreads();
#pragma unroll
  for (int jj = 0; jj < 16; jj++) {
    int id = t + jj * NTHREADS;
    int c = id >> 6, nl = id & 63;
    size_t off = (size_t)c * 131072 + (size_t)z * 4096 + n0 + nl;
    if (f) {
      float* o = (float*)io;
      o[off] = sane(o[off] + tile[nl * 65 + c]);
    } else {
      __hip_bfloat16* o = (__hip_bfloat16*)io;
      o[off] = f2bf(sane(bf2f(o[off]) + tile[nl * 65 + c]));
    }
  }
}

// ---------------- launch ----------------
extern "C" void kernel_launch(void* const* d_in, const int* in_sizes, int n_in,
                              void* d_out, int out_size, void* d_ws, size_t ws_size,
                              hipStream_t stream) {
  (void)in_sizes; (void)n_in; (void)out_size; (void)ws_size;
  const void* x        = d_in[0];
  const void* c1_w     = d_in[1];
  const void* in1_g    = d_in[2];
  const void* in1_b    = d_in[3];
  const void* c2_w     = d_in[4];
  const void* in2_g    = d_in[5];
  const void* in2_b    = d_in[6];
  const void* dw_w     = d_in[7];
  const void* pw_w     = d_in[8];
  const void* inr_g    = d_in[9];
  const void* inr_b    = d_in[10];
  const void* ln_g     = d_in[11];
  const void* ln_b     = d_in[12];
  const void* in_proj_w= d_in[13];
  const void* conv1d_w = d_in[14];
  const void* conv1d_b = d_in[15];
  const void* x_proj_w = d_in[16];
  const void* dt_proj_w= d_in[17];
  const void* dt_proj_b= d_in[18];
  const void* A_log    = d_in[19];
  const void* D_p      = d_in[20];
  const void* out_proj_w=d_in[21];
  const void* proj_w   = d_in[22];
  const void* proj_b   = d_in[23];
  const void* pn_g     = d_in[24];
  const void* pn_b     = d_in[25];

  char* wb = (char*)d_ws;
  // Byte layout, TOTAL ~= 87.4 MB (< 90.3 MB proven mapped in R7).
  // R0 [0, 33,554,432): P1(9.5M) -> P2(19.5M) -> zg(33.5M) -> s2(16.8M)
  __hip_bfloat16* P1   = (__hip_bfloat16*)wb;
  __hip_bfloat16* P2   = (__hip_bfloat16*)wb;
  __hip_bfloat16* zgb  = (__hip_bfloat16*)wb;
  __hip_bfloat16* s2   = (__hip_bfloat16*)wb;
  // R1 [33,554,432, 67,108,864): c1raw(17.3M) -> c2raw(17.8M) | pre2(16.8M) -> x_in(33.5M)
  // NOTE: x_in spans [33,554,432, 67,108,864) and is LIVE until k_outproj — nothing
  // may alias inside that range while the scan pipeline runs.
  __hip_bfloat16* c1raw = (__hip_bfloat16*)(wb + 33554432);
  __hip_bfloat16* c2raw = (__hip_bfloat16*)(wb + 33554432);
  __hip_bfloat16* pre2  = (__hip_bfloat16*)(wb + 33554432);
  __hip_bfloat16* x_in  = (__hip_bfloat16*)(wb + 33554432);
  // hcl [51,380,224, 68,157,440) — dead after k_x2ln (overlaps x_in tail; x_in written later)
  __hip_bfloat16* hcl   = (__hip_bfloat16*)(wb + 51380224);
  // seq [68,157,440, 84,934,656); BC (f32, 16,777,216 B exactly) aliases it after inproj
  __hip_bfloat16* seq   = (__hip_bfloat16*)(wb + 68157440);
  float*          BCf   = (float*)(wb + 68157440);
  // weights [84,934,656 ...)
  __hip_bfloat16* W1b   = (__hip_bfloat16*)(wb + 84934656);             // 73,728 B
  __hip_bfloat16* W2b   = (__hip_bfloat16*)(wb + 85008384);             // 147,456 B
  __hip_bfloat16* inwb  = (__hip_bfloat16*)(wb + 85155840);             // 32,768 B
  __hip_bfloat16* wcombb= (__hip_bfloat16*)(wb + 85188608);             // 16,384 B
  __hip_bfloat16* pwbb  = (__hip_bfloat16*)(wb + 85204992);             // 8,192 B
  __hip_bfloat16* xpwb  = (__hip_bfloat16*)(wb + 85213184);             // 9,216 B
  float*          fst   = (float*)(wb + 85222400);                      // 4,112 B
  // dtin f32 [85,229,568, 87,326,720) — free tail, outside every live buffer
  float*          dtinf = (float*)(wb + 85229568);

  float* acc_in1 = fst;
  float* acc_in2 = fst + 128;
  float* acc_inr = fst + 256;
  float* acc_pn  = fst + 384;
  float* ss_in1  = fst + 512;
  float* ss_in2  = fst + 640;
  float* ss_inr  = fst + 768;
  float* ss_pn   = fst + 896;
  int*   flagp   = (int*)(fst + 1024);

  hipMemsetAsync(fst, 0, 512 * sizeof(float), stream);

  k_detect<<<1, NTHREADS, 0, stream>>>(x, flagp);
  k_pad1<<<34 * 66, NTHREADS, 0, stream>>>(x, P1, flagp);
  k_prepw<<<144, NTHREADS, 0, stream>>>(c1_w, W1b, 32, flagp);
  k_prepw<<<288, NTHREADS, 0, stream>>>(c2_w, W2b, 64, flagp);
  k_prepcvt<<<64, NTHREADS, 0, stream>>>(in_proj_w, inwb, 16384, flagp);
  k_prepcvt<<<16, NTHREADS, 0, stream>>>(pw_w, pwbb, 4096, flagp);
  k_prepcvt<<<18, NTHREADS, 0, stream>>>(x_proj_w, xpwb, 4608, flagp);
  k_wcomb<<<32, NTHREADS, 0, stream>>>(proj_w, out_proj_w, wcombb, flagp);

  k_gemm_conv<32, 40><<<33 * 32, NTHREADS, 0, stream>>>(P1, W1b, c1raw, acc_in1);
  k_finalize<<<1, 64, 0, stream>>>(acc_in1, in1_g, in1_b, ss_in1, 1.0f / 135168.0f, flagp);
  k_normpad<<<35 * 66, NTHREADS, 0, stream>>>(c1raw, ss_in1, P2);

  k_gemm_conv<64, 88><<<34 * 32, NTHREADS, 0, stream>>>(P2, W2b, c2raw, acc_in2);
  k_finalize<<<1, 64, 0, stream>>>(acc_in2, in2_g, in2_b, ss_in2, 1.0f / 139264.0f, flagp);
  k_hslice_cl<<<2048, NTHREADS, 0, stream>>>(c2raw, ss_in2, hcl, d_out, flagp);

  k_dwpw_mfma<<<2048, NTHREADS, 0, stream>>>(hcl, dw_w, pwbb, pre2, acc_inr, flagp);
  k_finalize<<<1, 64, 0, stream>>>(acc_inr, inr_g, inr_b, ss_inr, 1.0f / 131072.0f, flagp);
  k_x2ln_cl<<<512, NTHREADS, 0, stream>>>(hcl, pre2, ss_inr, ln_g, ln_b, seq, flagp);

  k_inproj_mfma<<<2048, NTHREADS, 0, stream>>>(seq, inwb, x_in, zgb);
  k_conv1d_ip<<<2048, NTHREADS, 0, stream>>>(x_in, conv1d_w, conv1d_b, flagp);
  k_xproj_mfma<<<512, NTHREADS, 0, stream>>>(x_in, xpwb, dtinf, BCf);
  k_scan<<<2048, NTHREADS, 0, stream>>>(dtinf, BCf, x_in, zgb, dt_proj_w, dt_proj_b, A_log, D_p, flagp);
  k_outproj_mfma<<<512, NTHREADS, 0, stream>>>(x_in, wcombb, proj_b, s2, acc_pn, flagp);

  k_finalize<<<1, 64, 0, stream>>>(acc_pn, pn_g, pn_b, ss_pn, 1.0f / 131072.0f, flagp);
  k_final<<<2048, NTHREADS, 0, stream>>>(s2, d_out, ss_pn, flagp);
}